// Round 6
// baseline (246.342 us; speedup 1.0000x reference)
//
#include <hip/hip_runtime.h>
#include <hip/hip_bf16.h>

#define BATCH 2
#define SEQ 2048
#define DMODEL 1024
#define NH 16
#define HD 64
#define NRF 266
#define NRFP 288   // padded feature dim (multiple of 32), cols [266,288) are zero
#define CHK 128
#define NCH 16
#define NBH 32
#define NROWS 4096  // BATCH*SEQ

constexpr float SCAL = 0.17677669529663687f;   // DMODEL^-0.25
constexpr float SCAL2 = 0.03125f;              // SCAL^2 = DMODEL^-0.5
constexpr float CNORM = 0.06131393094576169f;  // 1/sqrt(NRF)
constexpr float KEPS = 1e-4f;
constexpr float LN_CNORM = -2.7917480361965505f;   // ln(1/sqrt(266))
constexpr float CKEPS = 6.131393094576169e-6f;     // CNORM*KEPS

typedef short bf16x8 __attribute__((ext_vector_type(8)));
typedef float f32x4 __attribute__((ext_vector_type(4)));

__device__ __forceinline__ short f2bs(float v) {
  __hip_bfloat16 h = __float2bfloat16(v);
  return *reinterpret_cast<short*>(&h);
}
__device__ __forceinline__ float bs2f(short s) {
  __hip_bfloat16 h;
  *reinterpret_cast<short*>(&h) = s;
  return __bfloat162float(h);
}
__device__ __forceinline__ void gload_lds16(const void* g, void* l) {
  __builtin_amdgcn_global_load_lds(
      (const __attribute__((address_space(1))) void*)g,
      (__attribute__((address_space(3))) void*)l, 16, 0, 0);
}

// ---------------- f32 -> bf16 convert ----------------
__global__ __launch_bounds__(256) void f32_to_bf16_k(const float* __restrict__ x,
                                                     short* __restrict__ y, int n) {
  int i = (blockIdx.x * 256 + threadIdx.x) * 8;
  if (i >= n) return;
  float4 a = *(const float4*)&x[i];
  float4 b = *(const float4*)&x[i + 4];
  bf16x8 o;
  o[0] = f2bs(a.x); o[1] = f2bs(a.y); o[2] = f2bs(a.z); o[3] = f2bs(a.w);
  o[4] = f2bs(b.x); o[5] = f2bs(b.y); o[6] = f2bs(b.z); o[7] = f2bs(b.w);
  *(bf16x8*)&y[i] = o;
}

// ---------------- rf [266][64] f32 -> rfb [288][64] bf16, SCAL folded, padded ----------------
__global__ __launch_bounds__(256) void rf_pad_bf16(const float* __restrict__ rf,
                                                   short* __restrict__ rfb) {
  int idx = blockIdx.x * 256 + threadIdx.x;  // grid 72*256 = 18432 exact
  rfb[idx] = (idx < NRF * HD) ? f2bs(rf[idx] * SCAL) : (short)0;
}

// ---------------- W[K][N] f32 -> Wt[N][K] bf16 ----------------
__global__ __launch_bounds__(256) void transpose_bf16(const float* __restrict__ W,
                                                      short* __restrict__ Wt) {
  __shared__ float t[32][33];
  int k0 = blockIdx.y << 5, n0 = blockIdx.x << 5;
  int tx = threadIdx.x & 31, ty = threadIdx.x >> 5;  // ty 0..7
#pragma unroll
  for (int rr = 0; rr < 4; ++rr) {
    int r = ty + (rr << 3);
    t[r][tx] = W[(size_t)(k0 + r) * DMODEL + n0 + tx];
  }
  __syncthreads();
#pragma unroll
  for (int rr = 0; rr < 4; ++rr) {
    int r = ty + (rr << 3);
    Wt[(size_t)(n0 + r) * DMODEL + k0 + tx] = f2bs(t[tx][r]);
  }
}

// ---------------- MFMA GEMM: C[M x 1024] = A(bf16 [M][1024]) @ Bt(bf16 [1024][1024])^T + bias
// BM=128 BN=128 BK=64, 4 waves (2x2), each wave 64x64 out; m97-style structure.
template <bool OUTBF>
__global__ __launch_bounds__(256) void gemm_bt(const short* __restrict__ A,
                                               const short* __restrict__ Bt,
                                               const float* __restrict__ bias,
                                               void* __restrict__ C) {
  __shared__ short As[128 * 64];
  __shared__ short Bs[128 * 64];
  int tid = threadIdx.x;
  int bm = blockIdx.y << 7, bn = blockIdx.x << 7;
  int lane = tid & 63, wid = tid >> 6;
  int wr = wid >> 1, wc = wid & 1;  // wave rows: wr*64..+63, cols: wc*64..+63
  int cl = lane & 15, rq = lane >> 4;
  f32x4 acc[4][4];
#pragma unroll
  for (int m = 0; m < 4; ++m)
#pragma unroll
    for (int n = 0; n < 4; ++n) acc[m][n] = f32x4{0.f, 0.f, 0.f, 0.f};

  for (int k0 = 0; k0 < DMODEL; k0 += 64) {
    __syncthreads();
#pragma unroll
    for (int i = 0; i < 4; ++i) {  // A tile: 128x64 bf16 = 16KB
      int e = tid * 8 + i * 2048;
      int row = e >> 6;
      int k = (e & 63) ^ ((row & 7) << 3);
      gload_lds16(A + (size_t)(bm + row) * DMODEL + k0 + k,
                  &As[wid * 512 + i * 2048]);
    }
#pragma unroll
    for (int i = 0; i < 4; ++i) {  // B tile: 128x64 bf16 = 16KB
      int e = tid * 8 + i * 2048;
      int row = e >> 6;
      int k = (e & 63) ^ ((row & 7) << 3);
      gload_lds16(Bt + (size_t)(bn + row) * DMODEL + k0 + k,
                  &Bs[wid * 512 + i * 2048]);
    }
    __syncthreads();
#pragma unroll
    for (int ks = 0; ks < 2; ++ks) {
      int kb = ks * 32 + (rq << 3);
      bf16x8 af[4], bfv[4];
#pragma unroll
      for (int mf = 0; mf < 4; ++mf) {
        int row = wr * 64 + mf * 16 + cl;
        af[mf] = *(const bf16x8*)&As[row * 64 + (kb ^ ((row & 7) << 3))];
      }
#pragma unroll
      for (int nf = 0; nf < 4; ++nf) {
        int row = wc * 64 + nf * 16 + cl;
        bfv[nf] = *(const bf16x8*)&Bs[row * 64 + (kb ^ ((row & 7) << 3))];
      }
#pragma unroll
      for (int mf = 0; mf < 4; ++mf)
#pragma unroll
        for (int nf = 0; nf < 4; ++nf)
          acc[mf][nf] = __builtin_amdgcn_mfma_f32_16x16x32_bf16(af[mf], bfv[nf],
                                                                acc[mf][nf], 0, 0, 0);
    }
  }
  int rbase = bm + wr * 64 + (rq << 2);
  int cbase = bn + wc * 64 + cl;
#pragma unroll
  for (int nf = 0; nf < 4; ++nf) {
    int col = cbase + nf * 16;
    float bv = bias[col];
#pragma unroll
    for (int mf = 0; mf < 4; ++mf)
#pragma unroll
      for (int r = 0; r < 4; ++r) {
        int row = rbase + mf * 16 + r;
        float v = acc[mf][nf][r] + bv;
        if (OUTBF)
          ((short*)C)[(size_t)row * DMODEL + col] = f2bs(v);
        else
          ((float*)C)[(size_t)row * DMODEL + col] = v;
      }
  }
}

// ---------------- h_k per (b,h,l) + per-block max (bf16 K input) ----------------
__global__ __launch_bounds__(256) void hk_kernel(const short* __restrict__ Kb,
                                                 float* __restrict__ hkbuf,
                                                 float* __restrict__ pmax) {
  int n = blockIdx.x;
  int tid = threadIdx.x;
  short4 kv = *(const short4*)(Kb + (size_t)n * DMODEL + tid * 4);
  float x0 = bs2f(kv.x), x1 = bs2f(kv.y), x2 = bs2f(kv.z), x3 = bs2f(kv.w);
  float ss = x0 * x0 + x1 * x1 + x2 * x2 + x3 * x3;
#pragma unroll
  for (int off = 8; off >= 1; off >>= 1) ss += __shfl_xor(ss, off, 16);
  float hkv = -0.5f * SCAL2 * ss;
  int h = tid >> 4;
  if ((tid & 15) == 0) {
    int b = n >> 11, l = n & (SEQ - 1);
    hkbuf[((size_t)(b * NH + h)) * SEQ + l] = hkv;
  }
  __shared__ float red[256];
  red[tid] = hkv;
  __syncthreads();
  for (int s = 128; s > 0; s >>= 1) {
    if (tid < s) red[tid] = fmaxf(red[tid], red[tid + s]);
    __syncthreads();
  }
  if (tid == 0) pmax[n] = red[0];
}

__global__ __launch_bounds__(256) void maxreduce_kernel(const float* __restrict__ pmax,
                                                        float* __restrict__ kstab) {
  int tid = threadIdx.x;
  float m = -3.0e38f;
  for (int i = tid; i < NROWS; i += 256) m = fmaxf(m, pmax[i]);
  __shared__ float red[256];
  red[tid] = m;
  __syncthreads();
  for (int s = 128; s > 0; s >>= 1) {
    if (tid < s) red[tid] = fmaxf(red[tid], red[tid + s]);
    __syncthreads();
  }
  if (tid == 0) *kstab = red[0];
}

// ---------------- feature map via MFMA (fast-exp epilogue) ----------------
__global__ __launch_bounds__(256, 1) void featmap_mfma(
    const short* __restrict__ Qproj, const short* __restrict__ Kproj,
    const short* __restrict__ rfb, const float* __restrict__ hkbuf,
    const float* __restrict__ kstab, short* __restrict__ Qp, short* __restrict__ Kp) {
  __shared__ short smem[26624];  // A:8192 | B:18432 ; epilogue reuses as P[128][152]
  __shared__ float hks[128];
  short* As = smem;
  short* Bs = smem + 8192;
  int isK = blockIdx.z;
  const short* X = isK ? Kproj : Qproj;
  short* O = isK ? Kp : Qp;
  int bh = blockIdx.y, b = bh >> 4, h = bh & 15;
  int l0 = blockIdx.x << 7;
  int tid = threadIdx.x, lane = tid & 63, wid = tid >> 6;
  int cl = lane & 15, rq = lane >> 4;

#pragma unroll
  for (int i = 0; i < 4; ++i) {
    int e = tid * 8 + i * 2048;
    int row = e >> 6;
    int k = (e & 63) ^ ((row & 7) << 3);
    gload_lds16(X + ((size_t)b * SEQ + l0 + row) * DMODEL + h * HD + k,
                &As[wid * 512 + i * 2048]);
  }
#pragma unroll
  for (int i = 0; i < 9; ++i) {
    int e = tid * 8 + i * 2048;
    int row = e >> 6;
    int k = (e & 63) ^ ((row & 7) << 3);
    gload_lds16(rfb + row * HD + k, &Bs[wid * 512 + i * 2048]);
  }
  if (isK) {
    float ksv = *kstab;
    if (tid < 128)
      hks[tid] = hkbuf[(size_t)bh * SEQ + l0 + tid] - ksv + LN_CNORM;
  }
  __syncthreads();

  int i0 = wid * 32;
  f32x4 acc[2][18];
#pragma unroll
  for (int m = 0; m < 2; ++m)
#pragma unroll
    for (int n = 0; n < 18; ++n) acc[m][n] = f32x4{0.f, 0.f, 0.f, 0.f};
#pragma unroll
  for (int ks = 0; ks < 2; ++ks) {
    int kb = ks * 32 + (rq << 3);
    int swz = (cl & 7) << 3;
    bf16x8 af[2];
#pragma unroll
    for (int mf = 0; mf < 2; ++mf) {
      int row = i0 + mf * 16 + cl;
      af[mf] = *(const bf16x8*)&As[row * 64 + (kb ^ swz)];
    }
#pragma unroll
    for (int nf = 0; nf < 18; ++nf) {
      int brow = nf * 16 + cl;
      bf16x8 bv = *(const bf16x8*)&Bs[brow * 64 + (kb ^ swz)];
#pragma unroll
      for (int mf = 0; mf < 2; ++mf)
        acc[mf][nf] = __builtin_amdgcn_mfma_f32_16x16x32_bf16(af[mf], bv,
                                                              acc[mf][nf], 0, 0, 0);
    }
  }

  short* Ps = smem;  // [128][152]
#pragma unroll
  for (int hf = 0; hf < 2; ++hf) {
    __syncthreads();
#pragma unroll
    for (int mf = 0; mf < 2; ++mf)
#pragma unroll
      for (int r = 0; r < 4; ++r) {
        int rl = i0 + mf * 16 + (rq << 2) + r;
        float addk = isK ? hks[rl] : LN_CNORM;  // ln(CNORM) folded into exp
#pragma unroll
        for (int nf2 = 0; nf2 < 9; ++nf2) {
          int m = hf * 144 + nf2 * 16 + cl;
          float v = acc[mf][hf * 9 + nf2][r] + addk;
          float o = (m < NRF) ? (__expf(v) + CKEPS) : 0.f;
          Ps[rl * 152 + nf2 * 16 + cl] = f2bs(o);
        }
      }
    __syncthreads();
#pragma unroll
    for (int it = 0; it < 9; ++it) {
      int idx = tid + it * 256;
      int row = idx / 18, ch = idx - row * 18;
      bf16x8 val = *(const bf16x8*)&Ps[row * 152 + ch * 8];
      *(bf16x8*)&O[((size_t)bh * SEQ + l0 + row) * NRFP + hf * 144 + ch * 8] = val;
    }
  }
}

// ---------------- per-chunk sums via MFMA: Sc[m][d] = sum_i K'[i][m] V[i][d] ----------------
__global__ __launch_bounds__(256) void chunksum_mfma(
    const short* __restrict__ Kp, const short* __restrict__ Vb,
    short* __restrict__ Schunk, float* __restrict__ ksum) {
  constexpr int ST = 70;
  __shared__ short KT[NRFP * ST];  // [m][i_loc]
  __shared__ short VT[HD * ST];    // [d][i_loc]
  int c = blockIdx.x, bh = blockIdx.y;
  int b = bh >> 4, h = bh & 15;
  int tid = threadIdx.x, lane = tid & 63, wv = tid >> 6;
  int cl = lane & 15, rq = lane >> 4;
  int irow = tid >> 2;  // 0..63
  int mq = tid & 3;
  size_t rowb = (size_t)bh * SEQ + (size_t)c * CHK;

  f32x4 acc[18];
#pragma unroll
  for (int m = 0; m < 18; ++m) acc[m] = f32x4{0.f, 0.f, 0.f, 0.f};
  float k1 = 0.f, k2 = 0.f;

  for (int hf = 0; hf < 2; ++hf) {
    __syncthreads();
    const short* Krow = Kp + (rowb + hf * 64 + irow) * NRFP;
#pragma unroll
    for (int cg = 0; cg < 9; ++cg) {
      int m0 = cg * 32 + mq * 8;
      bf16x8 v = *(const bf16x8*)(Krow + m0);
#pragma unroll
      for (int e = 0; e < 8; ++e) KT[(m0 + e) * ST + irow] = v[e];
    }
    const short* Vrow =
        Vb + ((size_t)b * SEQ + (size_t)c * CHK + hf * 64 + irow) * DMODEL + h * HD;
    {
      int d0 = mq * 16;
      bf16x8 v0 = *(const bf16x8*)(Vrow + d0);
      bf16x8 v1 = *(const bf16x8*)(Vrow + d0 + 8);
#pragma unroll
      for (int e = 0; e < 8; ++e) VT[(d0 + e) * ST + irow] = v0[e];
#pragma unroll
      for (int e = 0; e < 8; ++e) VT[(d0 + 8 + e) * ST + irow] = v1[e];
    }
    __syncthreads();
#pragma unroll
    for (int ks = 0; ks < 2; ++ks) {
      int kb = ks * 32 + rq * 8;
      bf16x8 bv = *(const bf16x8*)&VT[(wv * 16 + cl) * ST + kb];
#pragma unroll
      for (int mf = 0; mf < 18; ++mf) {
        bf16x8 av = *(const bf16x8*)&KT[(mf * 16 + cl) * ST + kb];
        acc[mf] = __builtin_amdgcn_mfma_f32_16x16x32_bf16(av, bv, acc[mf], 0, 0, 0);
      }
    }
    {
      const short* r1 = &KT[tid * ST];
#pragma unroll
      for (int g = 0; g < 8; ++g) {
        bf16x8 v = *(const bf16x8*)(r1 + g * 8);
#pragma unroll
        for (int e = 0; e < 8; ++e) k1 += bs2f(v[e]);
      }
      if (tid < 10) {
        const short* r2 = &KT[(256 + tid) * ST];
#pragma unroll
        for (int g = 0; g < 8; ++g) {
          bf16x8 v = *(const bf16x8*)(r2 + g * 8);
#pragma unroll
          for (int e = 0; e < 8; ++e) k2 += bs2f(v[e]);
        }
      }
    }
  }
  size_t sbase = ((size_t)bh * NCH + c) * (size_t)(NRFP * HD);
  size_t kbase = ((size_t)bh * NCH + c) * (size_t)NRF;
#pragma unroll
  for (int mf = 0; mf < 18; ++mf)
#pragma unroll
    for (int r = 0; r < 4; ++r) {
      int m = mf * 16 + rq * 4 + r;
      Schunk[sbase + (size_t)m * HD + wv * 16 + cl] = f2bs(acc[mf][r]);
    }
  if (tid < NRF) ksum[kbase + tid] = k1;
  if (tid < 10) ksum[kbase + 256 + tid] = k2;
}

// ---------------- exclusive prefix over chunks ----------------
__global__ __launch_bounds__(256) void prefix_S_bf(const short* __restrict__ Sc,
                                                   short* __restrict__ Sp) {
  int e = blockIdx.x * 256 + threadIdx.x;
  int bh = blockIdx.y;
  size_t base = (size_t)bh * NCH * (NRFP * HD) + e;
  float a = 0.f;
#pragma unroll
  for (int c = 0; c < NCH; ++c) {
    size_t idx = base + (size_t)c * (NRFP * HD);
    float v = bs2f(Sc[idx]);
    Sp[idx] = f2bs(a);
    a += v;
  }
}

__global__ void prefix_k_kernel(float* __restrict__ ksum) {
  int tid = blockIdx.x * 256 + threadIdx.x;
  if (tid >= NBH * NRF) return;
  int bh = tid / NRF;
  int m = tid - bh * NRF;
  size_t base = (size_t)bh * NCH * NRF + m;
  float a = 0.f;
#pragma unroll
  for (int c = 0; c < NCH; ++c) {
    size_t idx = base + (size_t)c * NRF;
    float v = ksum[idx];
    ksum[idx] = a;
    a += v;
  }
}

// ---------------- inter-chunk via MFMA ----------------
__global__ __launch_bounds__(256) void inter_mfma(
    const short* __restrict__ Qp, const short* __restrict__ Sp,
    const float* __restrict__ ksum, float* __restrict__ numA,
    float* __restrict__ denA) {
  int c = blockIdx.x, bh = blockIdx.y;
  __shared__ short Bs[64 * 296];
  __shared__ float ks[272];
  int tid = threadIdx.x, lane = tid & 63, wid = tid >> 6;
  const short* Spb = Sp + ((size_t)bh * NCH + c) * (size_t)(NRFP * HD);
  for (int idx = tid; idx < NRFP * HD; idx += 256) {
    int m = idx >> 6, d = idx & 63;
    Bs[d * 296 + m] = Spb[idx];
  }
  const float* ksb = ksum + ((size_t)bh * NCH + c) * (size_t)NRF;
  for (int idx = tid; idx < NRF; idx += 256) ks[idx] = ksb[idx];
  __syncthreads();
  int row0 = wid * 32;
  const short* Arow = Qp + ((size_t)bh * SEQ + (size_t)c * CHK + row0) * NRFP;
  f32x4 acc[2][4];
#pragma unroll
  for (int m = 0; m < 2; ++m)
#pragma unroll
    for (int n = 0; n < 4; ++n) acc[m][n] = f32x4{0.f, 0.f, 0.f, 0.f};
#pragma unroll
  for (int k9 = 0; k9 < 9; ++k9) {
    int kb = k9 * 32 + ((lane >> 4) << 3);
    bf16x8 af[2], bfv[4];
#pragma unroll
    for (int mf = 0; mf < 2; ++mf)
      af[mf] = *(const bf16x8*)(Arow + (size_t)(mf * 16 + (lane & 15)) * NRFP + kb);
#pragma unroll
    for (int nf = 0; nf < 4; ++nf)
      bfv[nf] = *(const bf16x8*)&Bs[(nf * 16 + (lane & 15)) * 296 + kb];
#pragma unroll
    for (int mf = 0; mf < 2; ++mf)
#pragma unroll
      for (int nf = 0; nf < 4; ++nf)
        acc[mf][nf] = __builtin_amdgcn_mfma_f32_16x16x32_bf16(af[mf], bfv[nf],
                                                              acc[mf][nf], 0, 0, 0);
  }
  size_t nb = ((size_t)bh * SEQ + (size_t)c * CHK + row0) * HD;
#pragma unroll
  for (int mf = 0; mf < 2; ++mf)
#pragma unroll
    for (int nf = 0; nf < 4; ++nf)
#pragma unroll
      for (int r = 0; r < 4; ++r) {
        int row = mf * 16 + ((lane >> 4) << 2) + r;
        int col = nf * 16 + (lane & 15);
        numA[nb + (size_t)row * HD + col] = acc[mf][nf][r];
      }
  int r = tid >> 1, half = tid & 1;
  const short* qr = Qp + ((size_t)bh * SEQ + (size_t)c * CHK + r) * NRFP;
  float s = 0.f;
  int m0 = half * 133;
  for (int m = m0; m < m0 + 133; ++m) s += bs2f(qr[m]) * ks[m];
  s += __shfl_xor(s, 1);
  if (!half) denA[(size_t)bh * SEQ + (size_t)c * CHK + r] = s;
}

// ---------------- intra-chunk via MFMA ----------------
__global__ __launch_bounds__(256) void intra_mfma(
    const short* __restrict__ Qp, const short* __restrict__ Kp,
    const short* __restrict__ Vb, const float* __restrict__ numA,
    const float* __restrict__ denA, short* __restrict__ ctxb) {
  constexpr int PST = 136;
  __shared__ short Pl[4 * 32 * PST];
  __shared__ short Vt[64 * PST];
  __shared__ float den_s[128];
  int c = blockIdx.x, bh = blockIdx.y;
  int b = bh >> 4, h = bh & 15;
  int tid = threadIdx.x, lane = tid & 63, wid = tid >> 6;
  int cl = lane & 15, rq = lane >> 4;
  size_t rowb = (size_t)bh * SEQ + (size_t)c * CHK;

  {
    int jj = tid >> 3, d0 = (tid & 7) << 3;
#pragma unroll
    for (int jt = 0; jt < 4; ++jt) {
      int j = jj + jt * 32;
      bf16x8 v = *(const bf16x8*)(Vb + ((size_t)b * SEQ + (size_t)c * CHK + j) * DMODEL +
                                  h * HD + d0);
#pragma unroll
      for (int e = 0; e < 8; ++e) Vt[(d0 + e) * PST + j] = v[e];
    }
  }

  int i0 = wid * 32;
  const short* Arow = Qp + (rowb + i0) * NRFP;
  const short* Krow = Kp + rowb * NRFP;
  f32x4 acc[2][8];
#pragma unroll
  for (int m = 0; m < 2; ++m)
#pragma unroll
    for (int n = 0; n < 8; ++n) acc[m][n] = f32x4{0.f, 0.f, 0.f, 0.f};
#pragma unroll
  for (int k9 = 0; k9 < 9; ++k9) {
    int kb = k9 * 32 + ((lane >> 4) << 3);
    bf16x8 af[2];
#pragma unroll
    for (int mf = 0; mf < 2; ++mf)
      af[mf] = *(const bf16x8*)(Arow + (size_t)(mf * 16 + cl) * NRFP + kb);
#pragma unroll
    for (int nf = 0; nf < 8; ++nf) {
      bf16x8 bv = *(const bf16x8*)(Krow + (size_t)(nf * 16 + cl) * NRFP + kb);
#pragma unroll
      for (int mf = 0; mf < 2; ++mf)
        acc[mf][nf] = __builtin_amdgcn_mfma_f32_16x16x32_bf16(af[mf], bv,
                                                              acc[mf][nf], 0, 0, 0);
    }
  }
  float dsum[2][4];
#pragma unroll
  for (int mf = 0; mf < 2; ++mf)
#pragma unroll
    for (int r = 0; r < 4; ++r) dsum[mf][r] = 0.f;
#pragma unroll
  for (int mf = 0; mf < 2; ++mf)
#pragma unroll
    for (int r = 0; r < 4; ++r) {
      int rl = mf * 16 + (rq << 2) + r;
      int row = i0 + rl;
#pragma unroll
      for (int nf = 0; nf < 8; ++nf) {
        int col = nf * 16 + cl;
        float v = (col > row) ? 0.f : acc[mf][nf][r];
        dsum[mf][r] += v;
        Pl[wid * 32 * PST + rl * PST + col] = f2bs(v);
      }
    }
#pragma unroll
  for (int mf = 0; mf < 2; ++mf)
#pragma unroll
    for (int r = 0; r < 4; ++r) {
      float s = dsum[mf][r];
      s += __shfl_xor(s, 1);
      s += __shfl_xor(s, 2);
      s += __shfl_xor(s, 4);
      s += __shfl_xor(s, 8);
      if (cl == 0) den_s[i0 + mf * 16 + (rq << 2) + r] = s;
    }
  __syncthreads();

  f32x4 pacc[2][4];
#pragma unroll
  for (int m = 0; m < 2; ++m)
#pragma unroll
    for (int n = 0; n < 4; ++n) pacc[m][n] = f32x4{0.f, 0.f, 0.f, 0.f};
#pragma unroll
  for (int kk = 0; kk < 4; ++kk) {
    int kb = kk * 32 + ((lane >> 4) << 3);
    bf16x8 paf[2];
#pragma unroll
    for (int mf = 0; mf < 2; ++mf)
      paf[mf] = *(const bf16x8*)&Pl[wid * 32 * PST + (mf * 16 + cl) * PST + kb];
#pragma unroll
    for (int nf = 0; nf < 4; ++nf) {
      bf16x8 bv = *(const bf16x8*)&Vt[(nf * 16 + cl) * PST + kb];
#pragma unroll
      for (int mf = 0; mf < 2; ++mf)
        pacc[mf][nf] = __builtin_amdgcn_mfma_f32_16x16x32_bf16(paf[mf], bv,
                                                               pacc[mf][nf], 0, 0, 0);
    }
  }
#pragma unroll
  for (int mf = 0; mf < 2; ++mf)
#pragma unroll
    for (int r = 0; r < 4; ++r) {
      int row = i0 + mf * 16 + (rq << 2) + r;
      size_t grow = rowb + row;
      float inv = 1.0f / (denA[grow] + den_s[row]);
      size_t ob = ((size_t)b * SEQ + (size_t)c * CHK + row) * DMODEL + h * HD;
#pragma unroll
      for (int nf = 0; nf < 4; ++nf) {
        int d = nf * 16 + cl;
        float v = (numA[grow * HD + d] + pacc[mf][nf][r]) * inv;
        ctxb[ob + d] = f2bs(v);
      }
    }
}

// ---------------- launch ----------------
extern "C" void kernel_launch(void* const* d_in, const int* in_sizes, int n_in,
                              void* d_out, int out_size, void* d_ws, size_t ws_size,
                              hipStream_t stream) {
  (void)in_sizes; (void)n_in; (void)out_size;
  const float* query = (const float*)d_in[0];
  const float* key_  = (const float*)d_in[1];
  const float* value = (const float*)d_in[2];
  const float* Wq = (const float*)d_in[3];
  const float* bq = (const float*)d_in[4];
  const float* Wk = (const float*)d_in[5];
  const float* bk = (const float*)d_in[6];
  const float* Wv = (const float*)d_in[7];
  const float* bv = (const float*)d_in[8];
  const float* Wo = (const float*)d_in[9];
  const float* bo = (const float*)d_in[10];
  const float* rf = (const float*)d_in[11];

  constexpr size_t SZ_INBF = (size_t)NROWS * DMODEL * 2;
  constexpr size_t SZ_QP   = (size_t)NBH * SEQ * NRFP * 2;
  constexpr size_t SZ_WT   = (size_t)DMODEL * DMODEL * 2;
  constexpr size_t SZ_SCH  = (size_t)NBH * NCH * NRFP * HD * 2;
  constexpr size_t SZ_KS   = (size_t)NBH * NCH * NRF * 4;
  constexpr size_t SZ_HK   = (size_t)NBH * SEQ * 4;
  constexpr size_t SZ_NUMA = (size_t)NBH * SEQ * HD * 4;
  constexpr size_t SZ_RFB  = (size_t)NRFP * HD * 2;

  constexpr size_t O_QP   = 0;
  constexpr size_t O_KP   = O_QP + SZ_QP;
  constexpr size_t O_WT   = O_KP + SZ_QP;
  constexpr size_t O_QPR  = O_WT + 4 * SZ_WT;
  constexpr size_t O_KPR  = O_QPR + SZ_INBF;
  constexpr size_t O_VPR  = O_KPR + SZ_INBF;
  constexpr size_t O_SCH  = O_VPR + SZ_INBF;
  constexpr size_t O_SPR  = O_SCH + SZ_SCH;
  constexpr size_t O_KSUM = O_SPR + SZ_SCH;
  constexpr size_t O_HK   = O_KSUM + SZ_KS;
  constexpr size_t O_PMAX = O_HK + SZ_HK;
  constexpr size_t O_KST  = O_PMAX + (size_t)NROWS * 4;
  constexpr size_t O_NUMA = O_KST + 256;
  constexpr size_t O_DENA = O_NUMA + SZ_NUMA;
  constexpr size_t O_CTXB = O_DENA + SZ_HK;
  constexpr size_t O_RFB  = O_CTXB + SZ_INBF;
  constexpr size_t O_END  = O_RFB + SZ_RFB;
  if (ws_size < O_END) return;

  char* w = (char*)d_ws;
  short* Qbf = (short*)(w + O_QP);
  short* Kbf = (short*)(w + O_QP + SZ_INBF);
  short* Vbf = (short*)(w + O_QP + 2 * SZ_INBF);
  short* Qp  = (short*)(w + O_QP);
  short* Kp  = (short*)(w + O_KP);
  short* WtQ = (short*)(w + O_WT);
  short* WtK = (short*)(w + O_WT + SZ_WT);
  short* WtV = (short*)(w + O_WT + 2 * SZ_WT);
  short* WtO = (short*)(w + O_WT + 3 * SZ_WT);
  short* Qpr = (short*)(w + O_QPR);
  short* Kpr = (short*)(w + O_KPR);
  short* Vpr = (short*)(w + O_VPR);
  short* Sch = (short*)(w + O_SCH);
  short* Spr = (short*)(w + O_SPR);
  float* ksum = (float*)(w + O_KSUM);
  float* hkbuf = (float*)(w + O_HK);
  float* pmax = (float*)(w + O_PMAX);
  float* kstab = (float*)(w + O_KST);
  float* numA = (float*)(w + O_NUMA);
  float* denA = (float*)(w + O_DENA);
  short* ctxb = (short*)(w + O_CTXB);
  short* rfb  = (short*)(w + O_RFB);

  constexpr int NEL = NROWS * DMODEL;
  f32_to_bf16_k<<<NEL / (256 * 8), 256, 0, stream>>>(query, Qbf, NEL);
  f32_to_bf16_k<<<NEL / (256 * 8), 256, 0, stream>>>(key_, Kbf, NEL);
  f32_to_bf16_k<<<NEL / (256 * 8), 256, 0, stream>>>(value, Vbf, NEL);
  transpose_bf16<<<dim3(32, 32), 256, 0, stream>>>(Wq, WtQ);
  transpose_bf16<<<dim3(32, 32), 256, 0, stream>>>(Wk, WtK);
  transpose_bf16<<<dim3(32, 32), 256, 0, stream>>>(Wv, WtV);
  transpose_bf16<<<dim3(32, 32), 256, 0, stream>>>(Wo, WtO);
  rf_pad_bf16<<<(NRFP * HD) / 256, 256, 0, stream>>>(rf, rfb);
  gemm_bt<true><<<dim3(8, 32), 256, 0, stream>>>(Qbf, WtQ, bq, Qpr);
  gemm_bt<true><<<dim3(8, 32), 256, 0, stream>>>(Kbf, WtK, bk, Kpr);
  gemm_bt<true><<<dim3(8, 32), 256, 0, stream>>>(Vbf, WtV, bv, Vpr);
  hk_kernel<<<NROWS, 256, 0, stream>>>(Kpr, hkbuf, pmax);
  maxreduce_kernel<<<1, 256, 0, stream>>>(pmax, kstab);
  featmap_mfma<<<dim3(SEQ / 128, NBH, 2), 256, 0, stream>>>(Qpr, Kpr, rfb, hkbuf,
                                                            kstab, Qp, Kp);
  chunksum_mfma<<<dim3(NCH, NBH), 256, 0, stream>>>(Kp, Vpr, Sch, ksum);
  prefix_S_bf<<<dim3(NRFP * HD / 256, NBH), 256, 0, stream>>>(Sch, Spr);
  prefix_k_kernel<<<(NBH * NRF + 255) / 256, 256, 0, stream>>>(ksum);
  inter_mfma<<<dim3(NCH, NBH), 256, 0, stream>>>(Qp, Spr, ksum, numA, denA);
  intra_mfma<<<dim3(NCH, NBH), 256, 0, stream>>>(Qp, Kp, Vpr, numA, denA, ctxb);
  gemm_bt<false><<<dim3(8, 32), 256, 0, stream>>>(ctxb, WtO, bo, d_out);
}

// Round 7
// 244.364 us; speedup vs baseline: 1.0081x; 1.0081x over previous
//
#include <hip/hip_runtime.h>
#include <hip/hip_bf16.h>

#define BATCH 2
#define SEQ 2048
#define DMODEL 1024
#define NH 16
#define HD 64
#define NRF 266
#define NRFP 288   // padded feature dim (multiple of 32), cols [266,288) are zero
#define CHK 128
#define NCH 16
#define NBH 32
#define NROWS 4096  // BATCH*SEQ

constexpr float SCAL = 0.17677669529663687f;   // DMODEL^-0.25
constexpr float SCAL2 = 0.03125f;              // SCAL^2 = DMODEL^-0.5
constexpr float CNORM = 0.06131393094576169f;  // 1/sqrt(NRF)
constexpr float LN_CNORM = -2.7917480361965505f;   // ln(1/sqrt(266))
constexpr float CKEPS = 6.131393094576169e-6f;     // CNORM*KEPS

typedef short bf16x8 __attribute__((ext_vector_type(8)));
typedef float f32x4 __attribute__((ext_vector_type(4)));

__device__ __forceinline__ short f2bs(float v) {
  __hip_bfloat16 h = __float2bfloat16(v);
  return *reinterpret_cast<short*>(&h);
}
__device__ __forceinline__ float bs2f(short s) {
  __hip_bfloat16 h;
  *reinterpret_cast<short*>(&h) = s;
  return __bfloat162float(h);
}
__device__ __forceinline__ void gload_lds16(const void* g, void* l) {
  __builtin_amdgcn_global_load_lds(
      (const __attribute__((address_space(1))) void*)g,
      (__attribute__((address_space(3))) void*)l, 16, 0, 0);
}
// monotone float<->uint order encoding (for atomicMax over floats)
__device__ __forceinline__ unsigned f2ord(float f) {
  unsigned u = __float_as_uint(f);
  return (u & 0x80000000u) ? ~u : (u | 0x80000000u);
}
__device__ __forceinline__ float ord2f(unsigned e) {
  return (e & 0x80000000u) ? __uint_as_float(e & 0x7fffffffu)
                           : __uint_as_float(~e);
}

// ---------------- fused f32 -> bf16 convert for q,k,v ----------------
__global__ __launch_bounds__(256) void cvt3_kernel(const float* __restrict__ q,
                                                   const float* __restrict__ k,
                                                   const float* __restrict__ v,
                                                   short* __restrict__ out) {
  int z = blockIdx.y;
  const float* x = (z == 0) ? q : (z == 1) ? k : v;
  short* y = out + (size_t)z * NROWS * DMODEL;
  int i = (blockIdx.x * 256 + threadIdx.x) * 8;
  float4 a = *(const float4*)&x[i];
  float4 b = *(const float4*)&x[i + 4];
  bf16x8 o;
  o[0] = f2bs(a.x); o[1] = f2bs(a.y); o[2] = f2bs(a.z); o[3] = f2bs(a.w);
  o[4] = f2bs(b.x); o[5] = f2bs(b.y); o[6] = f2bs(b.z); o[7] = f2bs(b.w);
  *(bf16x8*)&y[i] = o;
}

// ---------------- rf pad + SCAL fold; also zero the kstab atomic slot ----------------
__global__ __launch_bounds__(256) void rf_pad_bf16(const float* __restrict__ rf,
                                                   short* __restrict__ rfb,
                                                   unsigned* __restrict__ kord) {
  int idx = blockIdx.x * 256 + threadIdx.x;  // grid 72*256 = 18432 exact
  rfb[idx] = (idx < NRF * HD) ? f2bs(rf[idx] * SCAL) : (short)0;
  if (idx == 0) *kord = 0u;  // smallest ordered value; runs before hk_kernel
}

// ---------------- fused W transposes: W[K][N] f32 -> Wt[N][K] bf16, 4 weights ----------------
__global__ __launch_bounds__(256) void transpose4_bf16(
    const float* __restrict__ Wq, const float* __restrict__ Wk,
    const float* __restrict__ Wv, const float* __restrict__ Wo,
    short* __restrict__ WtBase) {
  __shared__ float t[32][33];
  int z = blockIdx.z;
  const float* W = (z == 0) ? Wq : (z == 1) ? Wk : (z == 2) ? Wv : Wo;
  short* Wt = WtBase + (size_t)z * DMODEL * DMODEL;
  int k0 = blockIdx.y << 5, n0 = blockIdx.x << 5;
  int tx = threadIdx.x & 31, ty = threadIdx.x >> 5;  // ty 0..7
#pragma unroll
  for (int rr = 0; rr < 4; ++rr) {
    int r = ty + (rr << 3);
    t[r][tx] = W[(size_t)(k0 + r) * DMODEL + n0 + tx];
  }
  __syncthreads();
#pragma unroll
  for (int rr = 0; rr < 4; ++rr) {
    int r = ty + (rr << 3);
    Wt[(size_t)(n0 + r) * DMODEL + k0 + tx] = f2bs(t[tx][r]);
  }
}

// ---------------- MFMA GEMM core: 128x64 tile, BK=64, 4 waves (2x2) ----------------
template <bool OUTBF>
__device__ __forceinline__ void gemm_core(const short* __restrict__ A,
                                          const short* __restrict__ Bt,
                                          const float* __restrict__ bias,
                                          void* __restrict__ C, int bm, int bn) {
  __shared__ short As[128 * 64];
  __shared__ short Bs[64 * 64];
  int tid = threadIdx.x;
  int lane = tid & 63, wid = tid >> 6;
  int wr = wid >> 1, wc = wid & 1;
  f32x4 acc[4][2];
#pragma unroll
  for (int m = 0; m < 4; ++m)
#pragma unroll
    for (int n = 0; n < 2; ++n) acc[m][n] = f32x4{0.f, 0.f, 0.f, 0.f};

  for (int k0 = 0; k0 < DMODEL; k0 += 64) {
    __syncthreads();
#pragma unroll
    for (int i = 0; i < 4; ++i) {
      int e = tid * 8 + i * 2048;
      int row = e >> 6;
      int k = (e & 63) ^ ((row & 7) << 3);
      gload_lds16(A + (size_t)(bm + row) * DMODEL + k0 + k,
                  &As[wid * 512 + i * 2048]);
    }
#pragma unroll
    for (int i = 0; i < 2; ++i) {
      int e = tid * 8 + i * 2048;
      int row = e >> 6;
      int k = (e & 63) ^ ((row & 7) << 3);
      gload_lds16(Bt + (size_t)(bn + row) * DMODEL + k0 + k,
                  &Bs[wid * 512 + i * 2048]);
    }
    __syncthreads();
#pragma unroll
    for (int ks = 0; ks < 2; ++ks) {
      int kb = ks * 32 + ((lane >> 4) << 3);
      bf16x8 af[4], bfv[2];
#pragma unroll
      for (int mf = 0; mf < 4; ++mf) {
        int row = wr * 64 + mf * 16 + (lane & 15);
        af[mf] = *(const bf16x8*)&As[row * 64 + (kb ^ ((row & 7) << 3))];
      }
#pragma unroll
      for (int nf = 0; nf < 2; ++nf) {
        int row = wc * 32 + nf * 16 + (lane & 15);
        bfv[nf] = *(const bf16x8*)&Bs[row * 64 + (kb ^ ((row & 7) << 3))];
      }
#pragma unroll
      for (int mf = 0; mf < 4; ++mf)
#pragma unroll
        for (int nf = 0; nf < 2; ++nf)
          acc[mf][nf] = __builtin_amdgcn_mfma_f32_16x16x32_bf16(af[mf], bfv[nf],
                                                                acc[mf][nf], 0, 0, 0);
    }
  }
  int rbase = bm + wr * 64 + ((lane >> 4) << 2);
  int cbase = bn + wc * 32 + (lane & 15);
#pragma unroll
  for (int nf = 0; nf < 2; ++nf) {
    int col = cbase + nf * 16;
    float bv = bias[col];
#pragma unroll
    for (int mf = 0; mf < 4; ++mf)
#pragma unroll
      for (int r = 0; r < 4; ++r) {
        int row = rbase + mf * 16 + r;
        float v = acc[mf][nf][r] + bv;
        if (OUTBF)
          ((short*)C)[(size_t)row * DMODEL + col] = f2bs(v);
        else
          ((float*)C)[(size_t)row * DMODEL + col] = v;
      }
  }
}

// fused QKV projection: grid (16, 32, 3)
__global__ __launch_bounds__(256) void gemm_qkv3(
    const short* __restrict__ Abase, const short* __restrict__ WtBase,
    const float* __restrict__ bq, const float* __restrict__ bk,
    const float* __restrict__ bv, short* __restrict__ OutBase) {
  int z = blockIdx.z;
  const short* A = Abase + (size_t)z * NROWS * DMODEL;
  const short* Bt = WtBase + (size_t)z * DMODEL * DMODEL;
  const float* bias = (z == 0) ? bq : (z == 1) ? bk : bv;
  short* C = OutBase + (size_t)z * NROWS * DMODEL;
  gemm_core<true>(A, Bt, bias, C, blockIdx.y << 7, blockIdx.x << 6);
}

// output projection: grid (16, 32)
__global__ __launch_bounds__(256) void gemm_out(const short* __restrict__ A,
                                                const short* __restrict__ Bt,
                                                const float* __restrict__ bias,
                                                float* __restrict__ C) {
  gemm_core<false>(A, Bt, bias, C, blockIdx.y << 7, blockIdx.x << 6);
}

// ---------------- h_k per (b,h,l) + global max via ordered atomic ----------------
__global__ __launch_bounds__(256) void hk_kernel(const short* __restrict__ Kb,
                                                 float* __restrict__ hkbuf,
                                                 unsigned* __restrict__ kord) {
  int n = blockIdx.x;
  int tid = threadIdx.x;
  short4 kv = *(const short4*)(Kb + (size_t)n * DMODEL + tid * 4);
  float x0 = bs2f(kv.x), x1 = bs2f(kv.y), x2 = bs2f(kv.z), x3 = bs2f(kv.w);
  float ss = x0 * x0 + x1 * x1 + x2 * x2 + x3 * x3;
#pragma unroll
  for (int off = 8; off >= 1; off >>= 1) ss += __shfl_xor(ss, off, 16);
  float hkv = -0.5f * SCAL2 * ss;
  int h = tid >> 4;
  if ((tid & 15) == 0) {
    int b = n >> 11, l = n & (SEQ - 1);
    hkbuf[((size_t)(b * NH + h)) * SEQ + l] = hkv;
  }
  __shared__ float red[256];
  red[tid] = hkv;
  __syncthreads();
  for (int s = 128; s > 0; s >>= 1) {
    if (tid < s) red[tid] = fmaxf(red[tid], red[tid + s]);
    __syncthreads();
  }
  if (tid == 0) atomicMax(kord, f2ord(red[0]));
}

// ---------------- feature map via MFMA (fast-exp epilogue) ----------------
__global__ __launch_bounds__(256, 1) void featmap_mfma(
    const short* __restrict__ Qproj, const short* __restrict__ Kproj,
    const short* __restrict__ rfb, const float* __restrict__ hkbuf,
    const unsigned* __restrict__ kord, short* __restrict__ Qp,
    short* __restrict__ Kp) {
  __shared__ short smem[26624];  // A:8192 | B:18432 ; epilogue reuses as P[128][152]
  __shared__ float hks[128];
  short* As = smem;
  short* Bs = smem + 8192;
  int isK = blockIdx.z;
  const short* X = isK ? Kproj : Qproj;
  short* O = isK ? Kp : Qp;
  int bh = blockIdx.y, b = bh >> 4, h = bh & 15;
  int l0 = blockIdx.x << 7;
  int tid = threadIdx.x, lane = tid & 63, wid = tid >> 6;
  int cl = lane & 15, rq = lane >> 4;

#pragma unroll
  for (int i = 0; i < 4; ++i) {
    int e = tid * 8 + i * 2048;
    int row = e >> 6;
    int k = (e & 63) ^ ((row & 7) << 3);
    gload_lds16(X + ((size_t)b * SEQ + l0 + row) * DMODEL + h * HD + k,
                &As[wid * 512 + i * 2048]);
  }
#pragma unroll
  for (int i = 0; i < 9; ++i) {
    int e = tid * 8 + i * 2048;
    int row = e >> 6;
    int k = (e & 63) ^ ((row & 7) << 3);
    gload_lds16(rfb + row * HD + k, &Bs[wid * 512 + i * 2048]);
  }
  if (isK) {
    float ksv = ord2f(*kord);
    if (tid < 128)
      hks[tid] = hkbuf[(size_t)bh * SEQ + l0 + tid] - ksv + LN_CNORM;
  }
  __syncthreads();

  int i0 = wid * 32;
  f32x4 acc[2][18];
#pragma unroll
  for (int m = 0; m < 2; ++m)
#pragma unroll
    for (int n = 0; n < 18; ++n) acc[m][n] = f32x4{0.f, 0.f, 0.f, 0.f};
#pragma unroll
  for (int ks = 0; ks < 2; ++ks) {
    int kb = ks * 32 + (rq << 3);
    int swz = (cl & 7) << 3;
    bf16x8 af[2];
#pragma unroll
    for (int mf = 0; mf < 2; ++mf) {
      int row = i0 + mf * 16 + cl;
      af[mf] = *(const bf16x8*)&As[row * 64 + (kb ^ swz)];
    }
#pragma unroll
    for (int nf = 0; nf < 18; ++nf) {
      int brow = nf * 16 + cl;
      bf16x8 bv = *(const bf16x8*)&Bs[brow * 64 + (kb ^ swz)];
#pragma unroll
      for (int mf = 0; mf < 2; ++mf)
        acc[mf][nf] = __builtin_amdgcn_mfma_f32_16x16x32_bf16(af[mf], bv,
                                                              acc[mf][nf], 0, 0, 0);
    }
  }

  short* Ps = smem;  // [128][152]
#pragma unroll
  for (int hf = 0; hf < 2; ++hf) {
    __syncthreads();
#pragma unroll
    for (int mf = 0; mf < 2; ++mf)
#pragma unroll
      for (int r = 0; r < 4; ++r) {
        int rl = i0 + mf * 16 + (rq << 2) + r;
        float addk = isK ? hks[rl] : LN_CNORM;
#pragma unroll
        for (int nf2 = 0; nf2 < 9; ++nf2) {
          int m = hf * 144 + nf2 * 16 + cl;
          float v = acc[mf][hf * 9 + nf2][r] + addk;
          float o = (m < NRF) ? (__expf(v) + CKEPS) : 0.f;
          Ps[rl * 152 + nf2 * 16 + cl] = f2bs(o);
        }
      }
    __syncthreads();
#pragma unroll
    for (int it = 0; it < 9; ++it) {
      int idx = tid + it * 256;
      int row = idx / 18, ch = idx - row * 18;
      bf16x8 val = *(const bf16x8*)&Ps[row * 152 + ch * 8];
      *(bf16x8*)&O[((size_t)bh * SEQ + l0 + row) * NRFP + hf * 144 + ch * 8] = val;
    }
  }
}

// ---------------- per-chunk sums via MFMA ----------------
__global__ __launch_bounds__(256) void chunksum_mfma(
    const short* __restrict__ Kp, const short* __restrict__ Vb,
    short* __restrict__ Schunk, float* __restrict__ ksum) {
  constexpr int ST = 70;
  __shared__ short KT[NRFP * ST];  // [m][i_loc]
  __shared__ short VT[HD * ST];    // [d][i_loc]
  int c = blockIdx.x, bh = blockIdx.y;
  int b = bh >> 4, h = bh & 15;
  int tid = threadIdx.x, lane = tid & 63, wv = tid >> 6;
  int cl = lane & 15, rq = lane >> 4;
  int irow = tid >> 2;  // 0..63
  int mq = tid & 3;
  size_t rowb = (size_t)bh * SEQ + (size_t)c * CHK;

  f32x4 acc[18];
#pragma unroll
  for (int m = 0; m < 18; ++m) acc[m] = f32x4{0.f, 0.f, 0.f, 0.f};
  float k1 = 0.f, k2 = 0.f;

  for (int hf = 0; hf < 2; ++hf) {
    __syncthreads();
    const short* Krow = Kp + (rowb + hf * 64 + irow) * NRFP;
#pragma unroll
    for (int cg = 0; cg < 9; ++cg) {
      int m0 = cg * 32 + mq * 8;
      bf16x8 v = *(const bf16x8*)(Krow + m0);
#pragma unroll
      for (int e = 0; e < 8; ++e) KT[(m0 + e) * ST + irow] = v[e];
    }
    const short* Vrow =
        Vb + ((size_t)b * SEQ + (size_t)c * CHK + hf * 64 + irow) * DMODEL + h * HD;
    {
      int d0 = mq * 16;
      bf16x8 v0 = *(const bf16x8*)(Vrow + d0);
      bf16x8 v1 = *(const bf16x8*)(Vrow + d0 + 8);
#pragma unroll
      for (int e = 0; e < 8; ++e) VT[(d0 + e) * ST + irow] = v0[e];
#pragma unroll
      for (int e = 0; e < 8; ++e) VT[(d0 + 8 + e) * ST + irow] = v1[e];
    }
    __syncthreads();
#pragma unroll
    for (int ks = 0; ks < 2; ++ks) {
      int kb = ks * 32 + rq * 8;
      bf16x8 bv = *(const bf16x8*)&VT[(wv * 16 + cl) * ST + kb];
#pragma unroll
      for (int mf = 0; mf < 18; ++mf) {
        bf16x8 av = *(const bf16x8*)&KT[(mf * 16 + cl) * ST + kb];
        acc[mf] = __builtin_amdgcn_mfma_f32_16x16x32_bf16(av, bv, acc[mf], 0, 0, 0);
      }
    }
    {
      const short* r1 = &KT[tid * ST];
#pragma unroll
      for (int g = 0; g < 8; ++g) {
        bf16x8 v = *(const bf16x8*)(r1 + g * 8);
#pragma unroll
        for (int e = 0; e < 8; ++e) k1 += bs2f(v[e]);
      }
      if (tid < 10) {
        const short* r2 = &KT[(256 + tid) * ST];
#pragma unroll
        for (int g = 0; g < 8; ++g) {
          bf16x8 v = *(const bf16x8*)(r2 + g * 8);
#pragma unroll
          for (int e = 0; e < 8; ++e) k2 += bs2f(v[e]);
        }
      }
    }
  }
  size_t sbase = ((size_t)bh * NCH + c) * (size_t)(NRFP * HD);
  size_t kbase = ((size_t)bh * NCH + c) * (size_t)NRF;
#pragma unroll
  for (int mf = 0; mf < 18; ++mf)
#pragma unroll
    for (int r = 0; r < 4; ++r) {
      int m = mf * 16 + rq * 4 + r;
      Schunk[sbase + (size_t)m * HD + wv * 16 + cl] = f2bs(acc[mf][r]);
    }
  if (tid < NRF) ksum[kbase + tid] = k1;
  if (tid < 10) ksum[kbase + 256 + tid] = k2;
}

// ---------------- fused exclusive prefixes: S (x<72) and ksum (x==72) ----------------
__global__ __launch_bounds__(256) void prefix_all(const short* __restrict__ Sc,
                                                  short* __restrict__ Sp,
                                                  float* __restrict__ ksum) {
  int bh = blockIdx.y;
  if (blockIdx.x == 72) {
    for (int m = threadIdx.x; m < NRF; m += 256) {
      size_t base = (size_t)bh * NCH * NRF + m;
      float a = 0.f;
#pragma unroll
      for (int c = 0; c < NCH; ++c) {
        size_t idx = base + (size_t)c * NRF;
        float v = ksum[idx];
        ksum[idx] = a;
        a += v;
      }
    }
    return;
  }
  int e = blockIdx.x * 256 + threadIdx.x;
  size_t base = (size_t)bh * NCH * (NRFP * HD) + e;
  float a = 0.f;
#pragma unroll
  for (int c = 0; c < NCH; ++c) {
    size_t idx = base + (size_t)c * (NRFP * HD);
    float v = bs2f(Sc[idx]);
    Sp[idx] = f2bs(a);
    a += v;
  }
}

// ---------------- inter-chunk via MFMA ----------------
__global__ __launch_bounds__(256) void inter_mfma(
    const short* __restrict__ Qp, const short* __restrict__ Sp,
    const float* __restrict__ ksum, float* __restrict__ numA,
    float* __restrict__ denA) {
  int c = blockIdx.x, bh = blockIdx.y;
  __shared__ short Bs[64 * 296];
  __shared__ float ks[272];
  int tid = threadIdx.x, lane = tid & 63, wid = tid >> 6;
  const short* Spb = Sp + ((size_t)bh * NCH + c) * (size_t)(NRFP * HD);
  for (int idx = tid; idx < NRFP * HD; idx += 256) {
    int m = idx >> 6, d = idx & 63;
    Bs[d * 296 + m] = Spb[idx];
  }
  const float* ksb = ksum + ((size_t)bh * NCH + c) * (size_t)NRF;
  for (int idx = tid; idx < NRF; idx += 256) ks[idx] = ksb[idx];
  __syncthreads();
  int row0 = wid * 32;
  const short* Arow = Qp + ((size_t)bh * SEQ + (size_t)c * CHK + row0) * NRFP;
  f32x4 acc[2][4];
#pragma unroll
  for (int m = 0; m < 2; ++m)
#pragma unroll
    for (int n = 0; n < 4; ++n) acc[m][n] = f32x4{0.f, 0.f, 0.f, 0.f};
#pragma unroll
  for (int k9 = 0; k9 < 9; ++k9) {
    int kb = k9 * 32 + ((lane >> 4) << 3);
    bf16x8 af[2], bfv[4];
#pragma unroll
    for (int mf = 0; mf < 2; ++mf)
      af[mf] = *(const bf16x8*)(Arow + (size_t)(mf * 16 + (lane & 15)) * NRFP + kb);
#pragma unroll
    for (int nf = 0; nf < 4; ++nf)
      bfv[nf] = *(const bf16x8*)&Bs[(nf * 16 + (lane & 15)) * 296 + kb];
#pragma unroll
    for (int mf = 0; mf < 2; ++mf)
#pragma unroll
      for (int nf = 0; nf < 4; ++nf)
        acc[mf][nf] = __builtin_amdgcn_mfma_f32_16x16x32_bf16(af[mf], bfv[nf],
                                                              acc[mf][nf], 0, 0, 0);
  }
  size_t nb = ((size_t)bh * SEQ + (size_t)c * CHK + row0) * HD;
#pragma unroll
  for (int mf = 0; mf < 2; ++mf)
#pragma unroll
    for (int nf = 0; nf < 4; ++nf)
#pragma unroll
      for (int r = 0; r < 4; ++r) {
        int row = mf * 16 + ((lane >> 4) << 2) + r;
        int col = nf * 16 + (lane & 15);
        numA[nb + (size_t)row * HD + col] = acc[mf][nf][r];
      }
  int r = tid >> 1, half = tid & 1;
  const short* qr = Qp + ((size_t)bh * SEQ + (size_t)c * CHK + r) * NRFP;
  float s = 0.f;
  int m0 = half * 133;
  for (int m = m0; m < m0 + 133; ++m) s += bs2f(qr[m]) * ks[m];
  s += __shfl_xor(s, 1);
  if (!half) denA[(size_t)bh * SEQ + (size_t)c * CHK + r] = s;
}

// ---------------- intra-chunk via MFMA ----------------
__global__ __launch_bounds__(256) void intra_mfma(
    const short* __restrict__ Qp, const short* __restrict__ Kp,
    const short* __restrict__ Vb, const float* __restrict__ numA,
    const float* __restrict__ denA, short* __restrict__ ctxb) {
  constexpr int PST = 136;
  __shared__ short Pl[4 * 32 * PST];
  __shared__ short Vt[64 * PST];
  __shared__ float den_s[128];
  int c = blockIdx.x, bh = blockIdx.y;
  int b = bh >> 4, h = bh & 15;
  int tid = threadIdx.x, lane = tid & 63, wid = tid >> 6;
  int cl = lane & 15, rq = lane >> 4;
  size_t rowb = (size_t)bh * SEQ + (size_t)c * CHK;

  {
    int jj = tid >> 3, d0 = (tid & 7) << 3;
#pragma unroll
    for (int jt = 0; jt < 4; ++jt) {
      int j = jj + jt * 32;
      bf16x8 v = *(const bf16x8*)(Vb + ((size_t)b * SEQ + (size_t)c * CHK + j) * DMODEL +
                                  h * HD + d0);
#pragma unroll
      for (int e = 0; e < 8; ++e) Vt[(d0 + e) * PST + j] = v[e];
    }
  }

  int i0 = wid * 32;
  const short* Arow = Qp + (rowb + i0) * NRFP;
  const short* Krow = Kp + rowb * NRFP;
  f32x4 acc[2][8];
#pragma unroll
  for (int m = 0; m < 2; ++m)
#pragma unroll
    for (int n = 0; n < 8; ++n) acc[m][n] = f32x4{0.f, 0.f, 0.f, 0.f};
#pragma unroll
  for (int k9 = 0; k9 < 9; ++k9) {
    int kb = k9 * 32 + ((lane >> 4) << 3);
    bf16x8 af[2];
#pragma unroll
    for (int mf = 0; mf < 2; ++mf)
      af[mf] = *(const bf16x8*)(Arow + (size_t)(mf * 16 + cl) * NRFP + kb);
#pragma unroll
    for (int nf = 0; nf < 8; ++nf) {
      bf16x8 bv = *(const bf16x8*)(Krow + (size_t)(nf * 16 + cl) * NRFP + kb);
#pragma unroll
      for (int mf = 0; mf < 2; ++mf)
        acc[mf][nf] = __builtin_amdgcn_mfma_f32_16x16x32_bf16(af[mf], bv,
                                                              acc[mf][nf], 0, 0, 0);
    }
  }
  float dsum[2][4];
#pragma unroll
  for (int mf = 0; mf < 2; ++mf)
#pragma unroll
    for (int r = 0; r < 4; ++r) dsum[mf][r] = 0.f;
#pragma unroll
  for (int mf = 0; mf < 2; ++mf)
#pragma unroll
    for (int r = 0; r < 4; ++r) {
      int rl = mf * 16 + (rq << 2) + r;
      int row = i0 + rl;
#pragma unroll
      for (int nf = 0; nf < 8; ++nf) {
        int col = nf * 16 + cl;
        float v = (col > row) ? 0.f : acc[mf][nf][r];
        dsum[mf][r] += v;
        Pl[wid * 32 * PST + rl * PST + col] = f2bs(v);
      }
    }
#pragma unroll
  for (int mf = 0; mf < 2; ++mf)
#pragma unroll
    for (int r = 0; r < 4; ++r) {
      float s = dsum[mf][r];
      s += __shfl_xor(s, 1);
      s += __shfl_xor(s, 2);
      s += __shfl_xor(s, 4);
      s += __shfl_xor(s, 8);
      if (cl == 0) den_s[i0 + mf * 16 + (rq << 2) + r] = s;
    }
  __syncthreads();

  f32x4 pacc[2][4];
#pragma unroll
  for (int m = 0; m < 2; ++m)
#pragma unroll
    for (int n = 0; n < 4; ++n) pacc[m][n] = f32x4{0.f, 0.f, 0.f, 0.f};
#pragma unroll
  for (int kk = 0; kk < 4; ++kk) {
    int kb = kk * 32 + ((lane >> 4) << 3);
    bf16x8 paf[2];
#pragma unroll
    for (int mf = 0; mf < 2; ++mf)
      paf[mf] = *(const bf16x8*)&Pl[wid * 32 * PST + (mf * 16 + cl) * PST + kb];
#pragma unroll
    for (int nf = 0; nf < 4; ++nf) {
      bf16x8 bv = *(const bf16x8*)&Vt[(nf * 16 + cl) * PST + kb];
#pragma unroll
      for (int mf = 0; mf < 2; ++mf)
        pacc[mf][nf] = __builtin_amdgcn_mfma_f32_16x16x32_bf16(paf[mf], bv,
                                                               pacc[mf][nf], 0, 0, 0);
    }
  }
#pragma unroll
  for (int mf = 0; mf < 2; ++mf)
#pragma unroll
    for (int r = 0; r < 4; ++r) {
      int row = i0 + mf * 16 + (rq << 2) + r;
      size_t grow = rowb + row;
      float inv = 1.0f / (denA[grow] + den_s[row]);
      size_t ob = ((size_t)b * SEQ + (size_t)c * CHK + row) * DMODEL + h * HD;
#pragma unroll
      for (int nf = 0; nf < 4; ++nf) {
        int d = nf * 16 + cl;
        float v = (numA[grow * HD + d] + pacc[mf][nf][r]) * inv;
        ctxb[ob + d] = f2bs(v);
      }
    }
}

// ---------------- launch ----------------
extern "C" void kernel_launch(void* const* d_in, const int* in_sizes, int n_in,
                              void* d_out, int out_size, void* d_ws, size_t ws_size,
                              hipStream_t stream) {
  (void)in_sizes; (void)n_in; (void)out_size;
  const float* query = (const float*)d_in[0];
  const float* key_  = (const float*)d_in[1];
  const float* value = (const float*)d_in[2];
  const float* Wq = (const float*)d_in[3];
  const float* bq = (const float*)d_in[4];
  const float* Wk = (const float*)d_in[5];
  const float* bk = (const float*)d_in[6];
  const float* Wv = (const float*)d_in[7];
  const float* bv = (const float*)d_in[8];
  const float* Wo = (const float*)d_in[9];
  const float* bo = (const float*)d_in[10];
  const float* rf = (const float*)d_in[11];

  constexpr size_t SZ_INBF = (size_t)NROWS * DMODEL * 2;
  constexpr size_t SZ_QP   = (size_t)NBH * SEQ * NRFP * 2;
  constexpr size_t SZ_WT   = (size_t)DMODEL * DMODEL * 2;
  constexpr size_t SZ_SCH  = (size_t)NBH * NCH * NRFP * HD * 2;
  constexpr size_t SZ_KS   = (size_t)NBH * NCH * NRF * 4;
  constexpr size_t SZ_HK   = (size_t)NBH * SEQ * 4;
  constexpr size_t SZ_NUMA = (size_t)NBH * SEQ * HD * 4;
  constexpr size_t SZ_RFB  = (size_t)NRFP * HD * 2;

  constexpr size_t O_QP   = 0;
  constexpr size_t O_KP   = O_QP + SZ_QP;
  constexpr size_t O_WT   = O_KP + SZ_QP;
  constexpr size_t O_QPR  = O_WT + 4 * SZ_WT;   // QKV proj outputs, contiguous x3
  constexpr size_t O_SCH  = O_QPR + 3 * SZ_INBF;
  constexpr size_t O_SPR  = O_SCH + SZ_SCH;
  constexpr size_t O_KSUM = O_SPR + SZ_SCH;
  constexpr size_t O_HK   = O_KSUM + SZ_KS;
  constexpr size_t O_KST  = O_HK + SZ_HK;
  constexpr size_t O_NUMA = O_KST + 256;
  constexpr size_t O_DENA = O_NUMA + SZ_NUMA;
  constexpr size_t O_CTXB = O_DENA + SZ_HK;
  constexpr size_t O_RFB  = O_CTXB + SZ_INBF;
  constexpr size_t O_END  = O_RFB + SZ_RFB;
  if (ws_size < O_END) return;

  char* w = (char*)d_ws;
  short* Qbf  = (short*)(w + O_QP);   // 3x input bf16, contiguous (dead after QKV gemm)
  short* Qp   = (short*)(w + O_QP);
  short* Kp   = (short*)(w + O_KP);
  short* WtB  = (short*)(w + O_WT);
  short* QprB = (short*)(w + O_QPR);  // Qpr,Kpr,Vpr contiguous
  short* Kpr  = (short*)(w + O_QPR + SZ_INBF);
  short* Vpr  = (short*)(w + O_QPR + 2 * SZ_INBF);
  short* Sch  = (short*)(w + O_SCH);
  short* Spr  = (short*)(w + O_SPR);
  float* ksum = (float*)(w + O_KSUM);
  float* hkbuf = (float*)(w + O_HK);
  unsigned* kord = (unsigned*)(w + O_KST);
  float* numA = (float*)(w + O_NUMA);
  float* denA = (float*)(w + O_DENA);
  short* ctxb = (short*)(w + O_CTXB);
  short* rfb  = (short*)(w + O_RFB);

  constexpr int NEL = NROWS * DMODEL;
  cvt3_kernel<<<dim3(NEL / 2048, 3), 256, 0, stream>>>(query, key_, value, Qbf);
  transpose4_bf16<<<dim3(32, 32, 4), 256, 0, stream>>>(Wq, Wk, Wv, Wo, WtB);
  rf_pad_bf16<<<(NRFP * HD) / 256, 256, 0, stream>>>(rf, rfb, kord);
  gemm_qkv3<<<dim3(16, 32, 3), 256, 0, stream>>>(Qbf, WtB, bq, bk, bv, QprB);
  hk_kernel<<<NROWS, 256, 0, stream>>>(Kpr, hkbuf, kord);
  featmap_mfma<<<dim3(SEQ / 128, NBH, 2), 256, 0, stream>>>(QprB, Kpr, rfb, hkbuf,
                                                            kord, Qp, Kp);
  chunksum_mfma<<<dim3(NCH, NBH), 256, 0, stream>>>(Kp, Vpr, Sch, ksum);
  prefix_all<<<dim3(73, NBH), 256, 0, stream>>>(Sch, Spr, ksum);
  inter_mfma<<<dim3(NCH, NBH), 256, 0, stream>>>(Qp, Spr, ksum, numA, denA);
  intra_mfma<<<dim3(NCH, NBH), 256, 0, stream>>>(Qp, Kp, Vpr, numA, denA, ctxb);
  gemm_out<<<dim3(16, 32), 256, 0, stream>>>(ctxb, WtB + 3 * (size_t)DMODEL * DMODEL,
                                             bo, (float*)d_out);
}

// Round 8
// 199.853 us; speedup vs baseline: 1.2326x; 1.2227x over previous
//
#include <hip/hip_runtime.h>
#include <hip/hip_bf16.h>

#define BATCH 2
#define SEQ 2048
#define DMODEL 1024
#define NH 16
#define HD 64
#define NRF 266
#define NRFP 288   // padded feature dim (multiple of 32), cols [266,288) are zero
#define CHK 128
#define NCH 16
#define NBH 32
#define NROWS 4096  // BATCH*SEQ

constexpr float SCAL = 0.17677669529663687f;   // DMODEL^-0.25
constexpr float SCAL2 = 0.03125f;              // SCAL^2 = DMODEL^-0.5
constexpr float CNORM = 0.06131393094576169f;  // 1/sqrt(NRF)
constexpr float LN_CNORM = -2.7917480361965505f;   // ln(1/sqrt(266))
constexpr float CKEPS = 6.131393094576169e-6f;     // CNORM*KEPS

typedef short bf16x8 __attribute__((ext_vector_type(8)));
typedef float f32x4 __attribute__((ext_vector_type(4)));

__device__ __forceinline__ short f2bs(float v) {
  __hip_bfloat16 h = __float2bfloat16(v);
  return *reinterpret_cast<short*>(&h);
}
__device__ __forceinline__ float bs2f(short s) {
  __hip_bfloat16 h;
  *reinterpret_cast<short*>(&h) = s;
  return __bfloat162float(h);
}
__device__ __forceinline__ void gload_lds16(const void* g, void* l) {
  __builtin_amdgcn_global_load_lds(
      (const __attribute__((address_space(1))) void*)g,
      (__attribute__((address_space(3))) void*)l, 16, 0, 0);
}
// monotone float<->uint order encoding (for atomicMax over floats; values here < 0)
__device__ __forceinline__ unsigned f2ord(float f) {
  unsigned u = __float_as_uint(f);
  return (u & 0x80000000u) ? ~u : (u | 0x80000000u);
}
__device__ __forceinline__ float ord2f(unsigned e) {
  return (e & 0x80000000u) ? __uint_as_float(e & 0x7fffffffu)
                           : __uint_as_float(~e);
}

// ---------------- fused f32 -> bf16 convert for q,k,v ----------------
__global__ __launch_bounds__(256) void cvt3_kernel(const float* __restrict__ q,
                                                   const float* __restrict__ k,
                                                   const float* __restrict__ v,
                                                   short* __restrict__ out) {
  int z = blockIdx.y;
  const float* x = (z == 0) ? q : (z == 1) ? k : v;
  short* y = out + (size_t)z * NROWS * DMODEL;
  int i = (blockIdx.x * 256 + threadIdx.x) * 8;
  float4 a = *(const float4*)&x[i];
  float4 b = *(const float4*)&x[i + 4];
  bf16x8 o;
  o[0] = f2bs(a.x); o[1] = f2bs(a.y); o[2] = f2bs(a.z); o[3] = f2bs(a.w);
  o[4] = f2bs(b.x); o[5] = f2bs(b.y); o[6] = f2bs(b.z); o[7] = f2bs(b.w);
  *(bf16x8*)&y[i] = o;
}

// ---------------- rf pad + SCAL fold; also zero the kstab atomic slot ----------------
__global__ __launch_bounds__(256) void rf_pad_bf16(const float* __restrict__ rf,
                                                   short* __restrict__ rfb,
                                                   unsigned* __restrict__ kord) {
  int idx = blockIdx.x * 256 + threadIdx.x;  // grid 72*256 = 18432 exact
  rfb[idx] = (idx < NRF * HD) ? f2bs(rf[idx] * SCAL) : (short)0;
  if (idx == 0) *kord = 0u;  // smallest ordered value; runs before hk_kernel
}

// ---------------- fused W transposes: W[K][N] f32 -> Wt[N][K] bf16, 4 weights ----------------
__global__ __launch_bounds__(256) void transpose4_bf16(
    const float* __restrict__ Wq, const float* __restrict__ Wk,
    const float* __restrict__ Wv, const float* __restrict__ Wo,
    short* __restrict__ WtBase) {
  __shared__ float t[32][33];
  int z = blockIdx.z;
  const float* W = (z == 0) ? Wq : (z == 1) ? Wk : (z == 2) ? Wv : Wo;
  short* Wt = WtBase + (size_t)z * DMODEL * DMODEL;
  int k0 = blockIdx.y << 5, n0 = blockIdx.x << 5;
  int tx = threadIdx.x & 31, ty = threadIdx.x >> 5;  // ty 0..7
#pragma unroll
  for (int rr = 0; rr < 4; ++rr) {
    int r = ty + (rr << 3);
    t[r][tx] = W[(size_t)(k0 + r) * DMODEL + n0 + tx];
  }
  __syncthreads();
#pragma unroll
  for (int rr = 0; rr < 4; ++rr) {
    int r = ty + (rr << 3);
    Wt[(size_t)(n0 + r) * DMODEL + k0 + tx] = f2bs(t[tx][r]);
  }
}

// ---------------- MFMA GEMM core: 128x64 tile, BK=64, 4 waves (2x2) ----------------
template <bool OUTBF>
__device__ __forceinline__ void gemm_core(const short* __restrict__ A,
                                          const short* __restrict__ Bt,
                                          const float* __restrict__ bias,
                                          void* __restrict__ C, int bm, int bn) {
  __shared__ short As[128 * 64];
  __shared__ short Bs[64 * 64];
  int tid = threadIdx.x;
  int lane = tid & 63, wid = tid >> 6;
  int wr = wid >> 1, wc = wid & 1;
  f32x4 acc[4][2];
#pragma unroll
  for (int m = 0; m < 4; ++m)
#pragma unroll
    for (int n = 0; n < 2; ++n) acc[m][n] = f32x4{0.f, 0.f, 0.f, 0.f};

  for (int k0 = 0; k0 < DMODEL; k0 += 64) {
    __syncthreads();
#pragma unroll
    for (int i = 0; i < 4; ++i) {
      int e = tid * 8 + i * 2048;
      int row = e >> 6;
      int k = (e & 63) ^ ((row & 7) << 3);
      gload_lds16(A + (size_t)(bm + row) * DMODEL + k0 + k,
                  &As[wid * 512 + i * 2048]);
    }
#pragma unroll
    for (int i = 0; i < 2; ++i) {
      int e = tid * 8 + i * 2048;
      int row = e >> 6;
      int k = (e & 63) ^ ((row & 7) << 3);
      gload_lds16(Bt + (size_t)(bn + row) * DMODEL + k0 + k,
                  &Bs[wid * 512 + i * 2048]);
    }
    __syncthreads();
#pragma unroll
    for (int ks = 0; ks < 2; ++ks) {
      int kb = ks * 32 + ((lane >> 4) << 3);
      bf16x8 af[4], bfv[2];
#pragma unroll
      for (int mf = 0; mf < 4; ++mf) {
        int row = wr * 64 + mf * 16 + (lane & 15);
        af[mf] = *(const bf16x8*)&As[row * 64 + (kb ^ ((row & 7) << 3))];
      }
#pragma unroll
      for (int nf = 0; nf < 2; ++nf) {
        int row = wc * 32 + nf * 16 + (lane & 15);
        bfv[nf] = *(const bf16x8*)&Bs[row * 64 + (kb ^ ((row & 7) << 3))];
      }
#pragma unroll
      for (int mf = 0; mf < 4; ++mf)
#pragma unroll
        for (int nf = 0; nf < 2; ++nf)
          acc[mf][nf] = __builtin_amdgcn_mfma_f32_16x16x32_bf16(af[mf], bfv[nf],
                                                                acc[mf][nf], 0, 0, 0);
    }
  }
  int rbase = bm + wr * 64 + ((lane >> 4) << 2);
  int cbase = bn + wc * 32 + (lane & 15);
#pragma unroll
  for (int nf = 0; nf < 2; ++nf) {
    int col = cbase + nf * 16;
    float bv = bias[col];
#pragma unroll
    for (int mf = 0; mf < 4; ++mf)
#pragma unroll
      for (int r = 0; r < 4; ++r) {
        int row = rbase + mf * 16 + r;
        float v = acc[mf][nf][r] + bv;
        if (OUTBF)
          ((short*)C)[(size_t)row * DMODEL + col] = f2bs(v);
        else
          ((float*)C)[(size_t)row * DMODEL + col] = v;
      }
  }
}

// fused QKV projection: grid (16, 32, 3)
__global__ __launch_bounds__(256) void gemm_qkv3(
    const short* __restrict__ Abase, const short* __restrict__ WtBase,
    const float* __restrict__ bq, const float* __restrict__ bk,
    const float* __restrict__ bv, short* __restrict__ OutBase) {
  int z = blockIdx.z;
  const short* A = Abase + (size_t)z * NROWS * DMODEL;
  const short* Bt = WtBase + (size_t)z * DMODEL * DMODEL;
  const float* bias = (z == 0) ? bq : (z == 1) ? bk : bv;
  short* C = OutBase + (size_t)z * NROWS * DMODEL;
  gemm_core<true>(A, Bt, bias, C, blockIdx.y << 7, blockIdx.x << 6);
}

// output projection: grid (16, 32)
__global__ __launch_bounds__(256) void gemm_out(const short* __restrict__ A,
                                                const short* __restrict__ Bt,
                                                const float* __restrict__ bias,
                                                float* __restrict__ C) {
  gemm_core<false>(A, Bt, bias, C, blockIdx.y << 7, blockIdx.x << 6);
}

// ---------------- h_k: 256 blocks x 256 thr; thread = one (row,head); 1 atomic/block ----------------
__global__ __launch_bounds__(256) void hk_kernel(const short* __restrict__ Kb,
                                                 float* __restrict__ hkbuf,
                                                 unsigned* __restrict__ kord) {
  int tid = threadIdx.x;
  int rloc = tid >> 4, h = tid & 15;       // 16 rows/block, 16 heads
  int n = blockIdx.x * 16 + rloc;          // global row
  const short* p = Kb + (size_t)n * DMODEL + h * HD;
  float ss = 0.f;
#pragma unroll
  for (int g = 0; g < 8; ++g) {
    bf16x8 v = *(const bf16x8*)(p + g * 8);
#pragma unroll
    for (int e = 0; e < 8; ++e) {
      float x = bs2f(v[e]);
      ss += x * x;
    }
  }
  float hkv = -0.5f * SCAL2 * ss;
  int b = n >> 11, l = n & (SEQ - 1);
  hkbuf[((size_t)(b * NH + h)) * SEQ + l] = hkv;
  __shared__ float red[256];
  red[tid] = hkv;
  __syncthreads();
  for (int s = 128; s > 0; s >>= 1) {
    if (tid < s) red[tid] = fmaxf(red[tid], red[tid + s]);
    __syncthreads();
  }
  if (tid == 0) atomicMax(kord, f2ord(red[0]));
}

// ---------------- feature map via MFMA (fast-exp epilogue) ----------------
__global__ __launch_bounds__(256, 1) void featmap_mfma(
    const short* __restrict__ Qproj, const short* __restrict__ Kproj,
    const short* __restrict__ rfb, const float* __restrict__ hkbuf,
    const unsigned* __restrict__ kord, short* __restrict__ Qp,
    short* __restrict__ Kp) {
  __shared__ short smem[26624];  // A:8192 | B:18432 ; epilogue reuses as P[128][152]
  __shared__ float hks[128];
  short* As = smem;
  short* Bs = smem + 8192;
  int isK = blockIdx.z;
  const short* X = isK ? Kproj : Qproj;
  short* O = isK ? Kp : Qp;
  int bh = blockIdx.y, b = bh >> 4, h = bh & 15;
  int l0 = blockIdx.x << 7;
  int tid = threadIdx.x, lane = tid & 63, wid = tid >> 6;
  int cl = lane & 15, rq = lane >> 4;

#pragma unroll
  for (int i = 0; i < 4; ++i) {
    int e = tid * 8 + i * 2048;
    int row = e >> 6;
    int k = (e & 63) ^ ((row & 7) << 3);
    gload_lds16(X + ((size_t)b * SEQ + l0 + row) * DMODEL + h * HD + k,
                &As[wid * 512 + i * 2048]);
  }
#pragma unroll
  for (int i = 0; i < 9; ++i) {
    int e = tid * 8 + i * 2048;
    int row = e >> 6;
    int k = (e & 63) ^ ((row & 7) << 3);
    gload_lds16(rfb + row * HD + k, &Bs[wid * 512 + i * 2048]);
  }
  if (isK) {
    float ksv = ord2f(*kord);
    if (tid < 128)
      hks[tid] = hkbuf[(size_t)bh * SEQ + l0 + tid] - ksv + LN_CNORM;
  }
  __syncthreads();

  int i0 = wid * 32;
  f32x4 acc[2][18];
#pragma unroll
  for (int m = 0; m < 2; ++m)
#pragma unroll
    for (int n = 0; n < 18; ++n) acc[m][n] = f32x4{0.f, 0.f, 0.f, 0.f};
#pragma unroll
  for (int ks = 0; ks < 2; ++ks) {
    int kb = ks * 32 + (rq << 3);
    int swz = (cl & 7) << 3;
    bf16x8 af[2];
#pragma unroll
    for (int mf = 0; mf < 2; ++mf) {
      int row = i0 + mf * 16 + cl;
      af[mf] = *(const bf16x8*)&As[row * 64 + (kb ^ swz)];
    }
#pragma unroll
    for (int nf = 0; nf < 18; ++nf) {
      int brow = nf * 16 + cl;
      bf16x8 bv = *(const bf16x8*)&Bs[brow * 64 + (kb ^ swz)];
#pragma unroll
      for (int mf = 0; mf < 2; ++mf)
        acc[mf][nf] = __builtin_amdgcn_mfma_f32_16x16x32_bf16(af[mf], bv,
                                                              acc[mf][nf], 0, 0, 0);
    }
  }

  short* Ps = smem;  // [128][152]
#pragma unroll
  for (int hf = 0; hf < 2; ++hf) {
    __syncthreads();
#pragma unroll
    for (int mf = 0; mf < 2; ++mf)
#pragma unroll
      for (int r = 0; r < 4; ++r) {
        int rl = i0 + mf * 16 + (rq << 2) + r;
        float addk = isK ? hks[rl] : LN_CNORM;
#pragma unroll
        for (int nf2 = 0; nf2 < 9; ++nf2) {
          int m = hf * 144 + nf2 * 16 + cl;
          float v = acc[mf][hf * 9 + nf2][r] + addk;
          float o = (m < NRF) ? (__expf(v) + CKEPS) : 0.f;
          Ps[rl * 152 + nf2 * 16 + cl] = f2bs(o);
        }
      }
    __syncthreads();
#pragma unroll
    for (int it = 0; it < 9; ++it) {
      int idx = tid + it * 256;
      int row = idx / 18, ch = idx - row * 18;
      bf16x8 val = *(const bf16x8*)&Ps[row * 152 + ch * 8];
      *(bf16x8*)&O[((size_t)bh * SEQ + l0 + row) * NRFP + hf * 144 + ch * 8] = val;
    }
  }
}

// ---------------- per-chunk sums via MFMA ----------------
__global__ __launch_bounds__(256) void chunksum_mfma(
    const short* __restrict__ Kp, const short* __restrict__ Vb,
    short* __restrict__ Schunk, float* __restrict__ ksum) {
  constexpr int ST = 70;
  __shared__ short KT[NRFP * ST];  // [m][i_loc]
  __shared__ short VT[HD * ST];    // [d][i_loc]
  int c = blockIdx.x, bh = blockIdx.y;
  int b = bh >> 4, h = bh & 15;
  int tid = threadIdx.x, lane = tid & 63, wv = tid >> 6;
  int cl = lane & 15, rq = lane >> 4;
  int irow = tid >> 2;  // 0..63
  int mq = tid & 3;
  size_t rowb = (size_t)bh * SEQ + (size_t)c * CHK;

  f32x4 acc[18];
#pragma unroll
  for (int m = 0; m < 18; ++m) acc[m] = f32x4{0.f, 0.f, 0.f, 0.f};
  float k1 = 0.f, k2 = 0.f;

  for (int hf = 0; hf < 2; ++hf) {
    __syncthreads();
    const short* Krow = Kp + (rowb + hf * 64 + irow) * NRFP;
#pragma unroll
    for (int cg = 0; cg < 9; ++cg) {
      int m0 = cg * 32 + mq * 8;
      bf16x8 v = *(const bf16x8*)(Krow + m0);
#pragma unroll
      for (int e = 0; e < 8; ++e) KT[(m0 + e) * ST + irow] = v[e];
    }
    const short* Vrow =
        Vb + ((size_t)b * SEQ + (size_t)c * CHK + hf * 64 + irow) * DMODEL + h * HD;
    {
      int d0 = mq * 16;
      bf16x8 v0 = *(const bf16x8*)(Vrow + d0);
      bf16x8 v1 = *(const bf16x8*)(Vrow + d0 + 8);
#pragma unroll
      for (int e = 0; e < 8; ++e) VT[(d0 + e) * ST + irow] = v0[e];
#pragma unroll
      for (int e = 0; e < 8; ++e) VT[(d0 + 8 + e) * ST + irow] = v1[e];
    }
    __syncthreads();
#pragma unroll
    for (int ks = 0; ks < 2; ++ks) {
      int kb = ks * 32 + rq * 8;
      bf16x8 bv = *(const bf16x8*)&VT[(wv * 16 + cl) * ST + kb];
#pragma unroll
      for (int mf = 0; mf < 18; ++mf) {
        bf16x8 av = *(const bf16x8*)&KT[(mf * 16 + cl) * ST + kb];
        acc[mf] = __builtin_amdgcn_mfma_f32_16x16x32_bf16(av, bv, acc[mf], 0, 0, 0);
      }
    }
    {
      const short* r1 = &KT[tid * ST];
#pragma unroll
      for (int g = 0; g < 8; ++g) {
        bf16x8 v = *(const bf16x8*)(r1 + g * 8);
#pragma unroll
        for (int e = 0; e < 8; ++e) k1 += bs2f(v[e]);
      }
      if (tid < 10) {
        const short* r2 = &KT[(256 + tid) * ST];
#pragma unroll
        for (int g = 0; g < 8; ++g) {
          bf16x8 v = *(const bf16x8*)(r2 + g * 8);
#pragma unroll
          for (int e = 0; e < 8; ++e) k2 += bs2f(v[e]);
        }
      }
    }
  }
  size_t sbase = ((size_t)bh * NCH + c) * (size_t)(NRFP * HD);
  size_t kbase = ((size_t)bh * NCH + c) * (size_t)NRF;
#pragma unroll
  for (int mf = 0; mf < 18; ++mf)
#pragma unroll
    for (int r = 0; r < 4; ++r) {
      int m = mf * 16 + rq * 4 + r;
      Schunk[sbase + (size_t)m * HD + wv * 16 + cl] = f2bs(acc[mf][r]);
    }
  if (tid < NRF) ksum[kbase + tid] = k1;
  if (tid < 10) ksum[kbase + 256 + tid] = k2;
}

// ---------------- fused exclusive prefixes: S (x<72) and ksum (x==72) ----------------
__global__ __launch_bounds__(256) void prefix_all(const short* __restrict__ Sc,
                                                  short* __restrict__ Sp,
                                                  float* __restrict__ ksum) {
  int bh = blockIdx.y;
  if (blockIdx.x == 72) {
    for (int m = threadIdx.x; m < NRF; m += 256) {
      size_t base = (size_t)bh * NCH * NRF + m;
      float a = 0.f;
#pragma unroll
      for (int c = 0; c < NCH; ++c) {
        size_t idx = base + (size_t)c * NRF;
        float v = ksum[idx];
        ksum[idx] = a;
        a += v;
      }
    }
    return;
  }
  int e = blockIdx.x * 256 + threadIdx.x;
  size_t base = (size_t)bh * NCH * (NRFP * HD) + e;
  float a = 0.f;
#pragma unroll
  for (int c = 0; c < NCH; ++c) {
    size_t idx = base + (size_t)c * (NRFP * HD);
    float v = bs2f(Sc[idx]);
    Sp[idx] = f2bs(a);
    a += v;
  }
}

// ---------------- inter-chunk via MFMA ----------------
__global__ __launch_bounds__(256) void inter_mfma(
    const short* __restrict__ Qp, const short* __restrict__ Sp,
    const float* __restrict__ ksum, float* __restrict__ numA,
    float* __restrict__ denA) {
  int c = blockIdx.x, bh = blockIdx.y;
  __shared__ short Bs[64 * 296];
  __shared__ float ks[272];
  int tid = threadIdx.x, lane = tid & 63, wid = tid >> 6;
  const short* Spb = Sp + ((size_t)bh * NCH + c) * (size_t)(NRFP * HD);
  for (int idx = tid; idx < NRFP * HD; idx += 256) {
    int m = idx >> 6, d = idx & 63;
    Bs[d * 296 + m] = Spb[idx];
  }
  const float* ksb = ksum + ((size_t)bh * NCH + c) * (size_t)NRF;
  for (int idx = tid; idx < NRF; idx += 256) ks[idx] = ksb[idx];
  __syncthreads();
  int row0 = wid * 32;
  const short* Arow = Qp + ((size_t)bh * SEQ + (size_t)c * CHK + row0) * NRFP;
  f32x4 acc[2][4];
#pragma unroll
  for (int m = 0; m < 2; ++m)
#pragma unroll
    for (int n = 0; n < 4; ++n) acc[m][n] = f32x4{0.f, 0.f, 0.f, 0.f};
#pragma unroll
  for (int k9 = 0; k9 < 9; ++k9) {
    int kb = k9 * 32 + ((lane >> 4) << 3);
    bf16x8 af[2], bfv[4];
#pragma unroll
    for (int mf = 0; mf < 2; ++mf)
      af[mf] = *(const bf16x8*)(Arow + (size_t)(mf * 16 + (lane & 15)) * NRFP + kb);
#pragma unroll
    for (int nf = 0; nf < 4; ++nf)
      bfv[nf] = *(const bf16x8*)&Bs[(nf * 16 + (lane & 15)) * 296 + kb];
#pragma unroll
    for (int mf = 0; mf < 2; ++mf)
#pragma unroll
      for (int nf = 0; nf < 4; ++nf)
        acc[mf][nf] = __builtin_amdgcn_mfma_f32_16x16x32_bf16(af[mf], bfv[nf],
                                                              acc[mf][nf], 0, 0, 0);
  }
  size_t nb = ((size_t)bh * SEQ + (size_t)c * CHK + row0) * HD;
#pragma unroll
  for (int mf = 0; mf < 2; ++mf)
#pragma unroll
    for (int nf = 0; nf < 4; ++nf)
#pragma unroll
      for (int r = 0; r < 4; ++r) {
        int row = mf * 16 + ((lane >> 4) << 2) + r;
        int col = nf * 16 + (lane & 15);
        numA[nb + (size_t)row * HD + col] = acc[mf][nf][r];
      }
  int r = tid >> 1, half = tid & 1;
  const short* qr = Qp + ((size_t)bh * SEQ + (size_t)c * CHK + r) * NRFP;
  float s = 0.f;
  int m0 = half * 133;
  for (int m = m0; m < m0 + 133; ++m) s += bs2f(qr[m]) * ks[m];
  s += __shfl_xor(s, 1);
  if (!half) denA[(size_t)bh * SEQ + (size_t)c * CHK + r] = s;
}

// ---------------- intra-chunk via MFMA ----------------
__global__ __launch_bounds__(256) void intra_mfma(
    const short* __restrict__ Qp, const short* __restrict__ Kp,
    const short* __restrict__ Vb, const float* __restrict__ numA,
    const float* __restrict__ denA, short* __restrict__ ctxb) {
  constexpr int PST = 136;
  __shared__ short Pl[4 * 32 * PST];
  __shared__ short Vt[64 * PST];
  __shared__ float den_s[128];
  int c = blockIdx.x, bh = blockIdx.y;
  int b = bh >> 4, h = bh & 15;
  int tid = threadIdx.x, lane = tid & 63, wid = tid >> 6;
  int cl = lane & 15, rq = lane >> 4;
  size_t rowb = (size_t)bh * SEQ + (size_t)c * CHK;

  {
    int jj = tid >> 3, d0 = (tid & 7) << 3;
#pragma unroll
    for (int jt = 0; jt < 4; ++jt) {
      int j = jj + jt * 32;
      bf16x8 v = *(const bf16x8*)(Vb + ((size_t)b * SEQ + (size_t)c * CHK + j) * DMODEL +
                                  h * HD + d0);
#pragma unroll
      for (int e = 0; e < 8; ++e) Vt[(d0 + e) * PST + j] = v[e];
    }
  }

  int i0 = wid * 32;
  const short* Arow = Qp + (rowb + i0) * NRFP;
  const short* Krow = Kp + rowb * NRFP;
  f32x4 acc[2][8];
#pragma unroll
  for (int m = 0; m < 2; ++m)
#pragma unroll
    for (int n = 0; n < 8; ++n) acc[m][n] = f32x4{0.f, 0.f, 0.f, 0.f};
#pragma unroll
  for (int k9 = 0; k9 < 9; ++k9) {
    int kb = k9 * 32 + ((lane >> 4) << 3);
    bf16x8 af[2];
#pragma unroll
    for (int mf = 0; mf < 2; ++mf)
      af[mf] = *(const bf16x8*)(Arow + (size_t)(mf * 16 + cl) * NRFP + kb);
#pragma unroll
    for (int nf = 0; nf < 8; ++nf) {
      bf16x8 bv = *(const bf16x8*)(Krow + (size_t)(nf * 16 + cl) * NRFP + kb);
#pragma unroll
      for (int mf = 0; mf < 2; ++mf)
        acc[mf][nf] = __builtin_amdgcn_mfma_f32_16x16x32_bf16(af[mf], bv,
                                                              acc[mf][nf], 0, 0, 0);
    }
  }
  float dsum[2][4];
#pragma unroll
  for (int mf = 0; mf < 2; ++mf)
#pragma unroll
    for (int r = 0; r < 4; ++r) dsum[mf][r] = 0.f;
#pragma unroll
  for (int mf = 0; mf < 2; ++mf)
#pragma unroll
    for (int r = 0; r < 4; ++r) {
      int rl = mf * 16 + (rq << 2) + r;
      int row = i0 + rl;
#pragma unroll
      for (int nf = 0; nf < 8; ++nf) {
        int col = nf * 16 + cl;
        float v = (col > row) ? 0.f : acc[mf][nf][r];
        dsum[mf][r] += v;
        Pl[wid * 32 * PST + rl * PST + col] = f2bs(v);
      }
    }
#pragma unroll
  for (int mf = 0; mf < 2; ++mf)
#pragma unroll
    for (int r = 0; r < 4; ++r) {
      float s = dsum[mf][r];
      s += __shfl_xor(s, 1);
      s += __shfl_xor(s, 2);
      s += __shfl_xor(s, 4);
      s += __shfl_xor(s, 8);
      if (cl == 0) den_s[i0 + mf * 16 + (rq << 2) + r] = s;
    }
  __syncthreads();

  f32x4 pacc[2][4];
#pragma unroll
  for (int m = 0; m < 2; ++m)
#pragma unroll
    for (int n = 0; n < 4; ++n) pacc[m][n] = f32x4{0.f, 0.f, 0.f, 0.f};
#pragma unroll
  for (int kk = 0; kk < 4; ++kk) {
    int kb = kk * 32 + ((lane >> 4) << 3);
    bf16x8 paf[2];
#pragma unroll
    for (int mf = 0; mf < 2; ++mf)
      paf[mf] = *(const bf16x8*)&Pl[wid * 32 * PST + (mf * 16 + cl) * PST + kb];
#pragma unroll
    for (int nf = 0; nf < 4; ++nf) {
      bf16x8 bv = *(const bf16x8*)&Vt[(nf * 16 + cl) * PST + kb];
#pragma unroll
      for (int mf = 0; mf < 2; ++mf)
        pacc[mf][nf] = __builtin_amdgcn_mfma_f32_16x16x32_bf16(paf[mf], bv,
                                                               pacc[mf][nf], 0, 0, 0);
    }
  }
#pragma unroll
  for (int mf = 0; mf < 2; ++mf)
#pragma unroll
    for (int r = 0; r < 4; ++r) {
      int row = i0 + mf * 16 + (rq << 2) + r;
      size_t grow = rowb + row;
      float inv = 1.0f / (denA[grow] + den_s[row]);
      size_t ob = ((size_t)b * SEQ + (size_t)c * CHK + row) * DMODEL + h * HD;
#pragma unroll
      for (int nf = 0; nf < 4; ++nf) {
        int d = nf * 16 + cl;
        float v = (numA[grow * HD + d] + pacc[mf][nf][r]) * inv;
        ctxb[ob + d] = f2bs(v);
      }
    }
}

// ---------------- launch ----------------
extern "C" void kernel_launch(void* const* d_in, const int* in_sizes, int n_in,
                              void* d_out, int out_size, void* d_ws, size_t ws_size,
                              hipStream_t stream) {
  (void)in_sizes; (void)n_in; (void)out_size;
  const float* query = (const float*)d_in[0];
  const float* key_  = (const float*)d_in[1];
  const float* value = (const float*)d_in[2];
  const float* Wq = (const float*)d_in[3];
  const float* bq = (const float*)d_in[4];
  const float* Wk = (const float*)d_in[5];
  const float* bk = (const float*)d_in[6];
  const float* Wv = (const float*)d_in[7];
  const float* bv = (const float*)d_in[8];
  const float* Wo = (const float*)d_in[9];
  const float* bo = (const float*)d_in[10];
  const float* rf = (const float*)d_in[11];

  constexpr size_t SZ_INBF = (size_t)NROWS * DMODEL * 2;
  constexpr size_t SZ_QP   = (size_t)NBH * SEQ * NRFP * 2;
  constexpr size_t SZ_WT   = (size_t)DMODEL * DMODEL * 2;
  constexpr size_t SZ_SCH  = (size_t)NBH * NCH * NRFP * HD * 2;
  constexpr size_t SZ_KS   = (size_t)NBH * NCH * NRF * 4;
  constexpr size_t SZ_HK   = (size_t)NBH * SEQ * 4;
  constexpr size_t SZ_NUMA = (size_t)NBH * SEQ * HD * 4;
  constexpr size_t SZ_RFB  = (size_t)NRFP * HD * 2;

  constexpr size_t O_QP   = 0;
  constexpr size_t O_KP   = O_QP + SZ_QP;
  constexpr size_t O_WT   = O_KP + SZ_QP;
  constexpr size_t O_QPR  = O_WT + 4 * SZ_WT;   // QKV proj outputs, contiguous x3
  constexpr size_t O_SCH  = O_QPR + 3 * SZ_INBF;
  constexpr size_t O_SPR  = O_SCH + SZ_SCH;
  constexpr size_t O_KSUM = O_SPR + SZ_SCH;
  constexpr size_t O_HK   = O_KSUM + SZ_KS;
  constexpr size_t O_KST  = O_HK + SZ_HK;
  constexpr size_t O_NUMA = O_KST + 256;
  constexpr size_t O_DENA = O_NUMA + SZ_NUMA;
  constexpr size_t O_CTXB = O_DENA + SZ_HK;
  constexpr size_t O_RFB  = O_CTXB + SZ_INBF;
  constexpr size_t O_END  = O_RFB + SZ_RFB;
  if (ws_size < O_END) return;

  char* w = (char*)d_ws;
  short* Qbf  = (short*)(w + O_QP);   // 3x input bf16, contiguous (dead after QKV gemm)
  short* Qp   = (short*)(w + O_QP);
  short* Kp   = (short*)(w + O_KP);
  short* WtB  = (short*)(w + O_WT);
  short* QprB = (short*)(w + O_QPR);  // Qpr,Kpr,Vpr contiguous
  short* Kpr  = (short*)(w + O_QPR + SZ_INBF);
  short* Vpr  = (short*)(w + O_QPR + 2 * SZ_INBF);
  short* Sch  = (short*)(w + O_SCH);
  short* Spr  = (short*)(w + O_SPR);
  float* ksum = (float*)(w + O_KSUM);
  float* hkbuf = (float*)(w + O_HK);
  unsigned* kord = (unsigned*)(w + O_KST);
  float* numA = (float*)(w + O_NUMA);
  float* denA = (float*)(w + O_DENA);
  short* ctxb = (short*)(w + O_CTXB);
  short* rfb  = (short*)(w + O_RFB);

  constexpr int NEL = NROWS * DMODEL;
  cvt3_kernel<<<dim3(NEL / 2048, 3), 256, 0, stream>>>(query, key_, value, Qbf);
  transpose4_bf16<<<dim3(32, 32, 4), 256, 0, stream>>>(Wq, Wk, Wv, Wo, WtB);
  rf_pad_bf16<<<(NRFP * HD) / 256, 256, 0, stream>>>(rf, rfb, kord);
  gemm_qkv3<<<dim3(16, 32, 3), 256, 0, stream>>>(Qbf, WtB, bq, bk, bv, QprB);
  hk_kernel<<<256, 256, 0, stream>>>(Kpr, hkbuf, kord);
  featmap_mfma<<<dim3(SEQ / 128, NBH, 2), 256, 0, stream>>>(QprB, Kpr, rfb, hkbuf,
                                                            kord, Qp, Kp);
  chunksum_mfma<<<dim3(NCH, NBH), 256, 0, stream>>>(Kp, Vpr, Sch, ksum);
  prefix_all<<<dim3(73, NBH), 256, 0, stream>>>(Sch, Spr, ksum);
  inter_mfma<<<dim3(NCH, NBH), 256, 0, stream>>>(Qp, Spr, ksum, numA, denA);
  intra_mfma<<<dim3(NCH, NBH), 256, 0, stream>>>(Qp, Kp, Vpr, numA, denA, ctxb);
  gemm_out<<<dim3(16, 32), 256, 0, stream>>>(ctxb, WtB + 3 * (size_t)DMODEL * DMODEL,
                                             bo, (float*)d_out);
}

// Round 9
// 195.337 us; speedup vs baseline: 1.2611x; 1.0231x over previous
//
#include <hip/hip_runtime.h>
#include <hip/hip_bf16.h>

#define BATCH 2
#define SEQ 2048
#define DMODEL 1024
#define NH 16
#define HD 64
#define NRF 266
#define NRFP 288   // padded feature dim (multiple of 32), cols [266,288) are zero
#define CHK 128
#define NCH 16
#define NBH 32
#define NROWS 4096  // BATCH*SEQ

constexpr float SCAL = 0.17677669529663687f;   // DMODEL^-0.25
constexpr float SCAL2 = 0.03125f;              // SCAL^2 = DMODEL^-0.5
constexpr float LN_CNORM = -2.7917480361965505f;   // ln(1/sqrt(266))
constexpr float CKEPS = 6.131393094576169e-6f;     // CNORM*KEPS

typedef short bf16x8 __attribute__((ext_vector_type(8)));
typedef float f32x4 __attribute__((ext_vector_type(4)));

__device__ __forceinline__ short f2bs(float v) {
  __hip_bfloat16 h = __float2bfloat16(v);
  return *reinterpret_cast<short*>(&h);
}
__device__ __forceinline__ float bs2f(short s) {
  __hip_bfloat16 h;
  *reinterpret_cast<short*>(&h) = s;
  return __bfloat162float(h);
}
__device__ __forceinline__ void gload_lds16(const void* g, void* l) {
  __builtin_amdgcn_global_load_lds(
      (const __attribute__((address_space(1))) void*)g,
      (__attribute__((address_space(3))) void*)l, 16, 0, 0);
}
// monotone float<->uint order encoding (for atomicMax over floats)
__device__ __forceinline__ unsigned f2ord(float f) {
  unsigned u = __float_as_uint(f);
  return (u & 0x80000000u) ? ~u : (u | 0x80000000u);
}
__device__ __forceinline__ float ord2f(unsigned e) {
  return (e & 0x80000000u) ? __uint_as_float(e & 0x7fffffffu)
                           : __uint_as_float(~e);
}

// ---------------- fused f32 -> bf16 convert for q,k,v ----------------
__global__ __launch_bounds__(256) void cvt3_kernel(const float* __restrict__ q,
                                                   const float* __restrict__ k,
                                                   const float* __restrict__ v,
                                                   short* __restrict__ out) {
  int z = blockIdx.y;
  const float* x = (z == 0) ? q : (z == 1) ? k : v;
  short* y = out + (size_t)z * NROWS * DMODEL;
  int i = (blockIdx.x * 256 + threadIdx.x) * 8;
  float4 a = *(const float4*)&x[i];
  float4 b = *(const float4*)&x[i + 4];
  bf16x8 o;
  o[0] = f2bs(a.x); o[1] = f2bs(a.y); o[2] = f2bs(a.z); o[3] = f2bs(a.w);
  o[4] = f2bs(b.x); o[5] = f2bs(b.y); o[6] = f2bs(b.z); o[7] = f2bs(b.w);
  *(bf16x8*)&y[i] = o;
}

// ---------------- rf pad + SCAL fold; also zero the kstab atomic slot ----------------
__global__ __launch_bounds__(256) void rf_pad_bf16(const float* __restrict__ rf,
                                                   short* __restrict__ rfb,
                                                   unsigned* __restrict__ kord) {
  int idx = blockIdx.x * 256 + threadIdx.x;  // grid 72*256 = 18432 exact
  rfb[idx] = (idx < NRF * HD) ? f2bs(rf[idx] * SCAL) : (short)0;
  if (idx == 0) *kord = 0u;
}

// ---------------- fused W transposes: W[K][N] f32 -> Wt[N][K] bf16, 4 weights ----------------
__global__ __launch_bounds__(256) void transpose4_bf16(
    const float* __restrict__ Wq, const float* __restrict__ Wk,
    const float* __restrict__ Wv, const float* __restrict__ Wo,
    short* __restrict__ WtBase) {
  __shared__ float t[32][33];
  int z = blockIdx.z;
  const float* W = (z == 0) ? Wq : (z == 1) ? Wk : (z == 2) ? Wv : Wo;
  short* Wt = WtBase + (size_t)z * DMODEL * DMODEL;
  int k0 = blockIdx.y << 5, n0 = blockIdx.x << 5;
  int tx = threadIdx.x & 31, ty = threadIdx.x >> 5;
#pragma unroll
  for (int rr = 0; rr < 4; ++rr) {
    int r = ty + (rr << 3);
    t[r][tx] = W[(size_t)(k0 + r) * DMODEL + n0 + tx];
  }
  __syncthreads();
#pragma unroll
  for (int rr = 0; rr < 4; ++rr) {
    int r = ty + (rr << 3);
    Wt[(size_t)(n0 + r) * DMODEL + k0 + tx] = f2bs(t[tx][r]);
  }
}

// ---------------- MFMA GEMM core 128x128, BK=64, 4 waves (2x2, 64x64 each) ----------------
template <bool OUTBF>
__device__ __forceinline__ void gemm_core128(const short* __restrict__ A,
                                             const short* __restrict__ Bt,
                                             const float* __restrict__ bias,
                                             void* __restrict__ C, int bm, int bn) {
  __shared__ short As[128 * 64];
  __shared__ short Bs[128 * 64];
  int tid = threadIdx.x;
  int lane = tid & 63, wid = tid >> 6;
  int wr = wid >> 1, wc = wid & 1;
  int cl = lane & 15, rq = lane >> 4;
  f32x4 acc[4][4];
#pragma unroll
  for (int m = 0; m < 4; ++m)
#pragma unroll
    for (int n = 0; n < 4; ++n) acc[m][n] = f32x4{0.f, 0.f, 0.f, 0.f};

  for (int k0 = 0; k0 < DMODEL; k0 += 64) {
    __syncthreads();
#pragma unroll
    for (int i = 0; i < 4; ++i) {
      int e = tid * 8 + i * 2048;
      int row = e >> 6;
      int k = (e & 63) ^ ((row & 7) << 3);
      gload_lds16(A + (size_t)(bm + row) * DMODEL + k0 + k,
                  &As[wid * 512 + i * 2048]);
    }
#pragma unroll
    for (int i = 0; i < 4; ++i) {
      int e = tid * 8 + i * 2048;
      int row = e >> 6;
      int k = (e & 63) ^ ((row & 7) << 3);
      gload_lds16(Bt + (size_t)(bn + row) * DMODEL + k0 + k,
                  &Bs[wid * 512 + i * 2048]);
    }
    __syncthreads();
#pragma unroll
    for (int ks = 0; ks < 2; ++ks) {
      int kb = ks * 32 + (rq << 3);
      bf16x8 af[4], bfv[4];
#pragma unroll
      for (int mf = 0; mf < 4; ++mf) {
        int row = wr * 64 + mf * 16 + cl;
        af[mf] = *(const bf16x8*)&As[row * 64 + (kb ^ ((row & 7) << 3))];
      }
#pragma unroll
      for (int nf = 0; nf < 4; ++nf) {
        int row = wc * 64 + nf * 16 + cl;
        bfv[nf] = *(const bf16x8*)&Bs[row * 64 + (kb ^ ((row & 7) << 3))];
      }
#pragma unroll
      for (int mf = 0; mf < 4; ++mf)
#pragma unroll
        for (int nf = 0; nf < 4; ++nf)
          acc[mf][nf] = __builtin_amdgcn_mfma_f32_16x16x32_bf16(af[mf], bfv[nf],
                                                                acc[mf][nf], 0, 0, 0);
    }
  }
  int rbase = bm + wr * 64 + (rq << 2);
  int cbase = bn + wc * 64 + cl;
#pragma unroll
  for (int nf = 0; nf < 4; ++nf) {
    int col = cbase + nf * 16;
    float bv = bias[col];
#pragma unroll
    for (int mf = 0; mf < 4; ++mf)
#pragma unroll
      for (int r = 0; r < 4; ++r) {
        int row = rbase + mf * 16 + r;
        float v = acc[mf][nf][r] + bv;
        if (OUTBF)
          ((short*)C)[(size_t)row * DMODEL + col] = f2bs(v);
        else
          ((float*)C)[(size_t)row * DMODEL + col] = v;
      }
  }
}

// ---------------- MFMA GEMM core 128x64, BK=64, 4 waves (2x2) ----------------
template <bool OUTBF>
__device__ __forceinline__ void gemm_core64(const short* __restrict__ A,
                                            const short* __restrict__ Bt,
                                            const float* __restrict__ bias,
                                            void* __restrict__ C, int bm, int bn) {
  __shared__ short As[128 * 64];
  __shared__ short Bs[64 * 64];
  int tid = threadIdx.x;
  int lane = tid & 63, wid = tid >> 6;
  int wr = wid >> 1, wc = wid & 1;
  f32x4 acc[4][2];
#pragma unroll
  for (int m = 0; m < 4; ++m)
#pragma unroll
    for (int n = 0; n < 2; ++n) acc[m][n] = f32x4{0.f, 0.f, 0.f, 0.f};

  for (int k0 = 0; k0 < DMODEL; k0 += 64) {
    __syncthreads();
#pragma unroll
    for (int i = 0; i < 4; ++i) {
      int e = tid * 8 + i * 2048;
      int row = e >> 6;
      int k = (e & 63) ^ ((row & 7) << 3);
      gload_lds16(A + (size_t)(bm + row) * DMODEL + k0 + k,
                  &As[wid * 512 + i * 2048]);
    }
#pragma unroll
    for (int i = 0; i < 2; ++i) {
      int e = tid * 8 + i * 2048;
      int row = e >> 6;
      int k = (e & 63) ^ ((row & 7) << 3);
      gload_lds16(Bt + (size_t)(bn + row) * DMODEL + k0 + k,
                  &Bs[wid * 512 + i * 2048]);
    }
    __syncthreads();
#pragma unroll
    for (int ks = 0; ks < 2; ++ks) {
      int kb = ks * 32 + ((lane >> 4) << 3);
      bf16x8 af[4], bfv[2];
#pragma unroll
      for (int mf = 0; mf < 4; ++mf) {
        int row = wr * 64 + mf * 16 + (lane & 15);
        af[mf] = *(const bf16x8*)&As[row * 64 + (kb ^ ((row & 7) << 3))];
      }
#pragma unroll
      for (int nf = 0; nf < 2; ++nf) {
        int row = wc * 32 + nf * 16 + (lane & 15);
        bfv[nf] = *(const bf16x8*)&Bs[row * 64 + (kb ^ ((row & 7) << 3))];
      }
#pragma unroll
      for (int mf = 0; mf < 4; ++mf)
#pragma unroll
        for (int nf = 0; nf < 2; ++nf)
          acc[mf][nf] = __builtin_amdgcn_mfma_f32_16x16x32_bf16(af[mf], bfv[nf],
                                                                acc[mf][nf], 0, 0, 0);
    }
  }
  int rbase = bm + wr * 64 + ((lane >> 4) << 2);
  int cbase = bn + wc * 32 + (lane & 15);
#pragma unroll
  for (int nf = 0; nf < 2; ++nf) {
    int col = cbase + nf * 16;
    float bv = bias[col];
#pragma unroll
    for (int mf = 0; mf < 4; ++mf)
#pragma unroll
      for (int r = 0; r < 4; ++r) {
        int row = rbase + mf * 16 + r;
        float v = acc[mf][nf][r] + bv;
        if (OUTBF)
          ((short*)C)[(size_t)row * DMODEL + col] = f2bs(v);
        else
          ((float*)C)[(size_t)row * DMODEL + col] = v;
      }
  }
}

// fused QKV projection: grid (8, 32, 3), 128x128 tile, XCD-swizzled
__global__ __launch_bounds__(256) void gemm_qkv3(
    const short* __restrict__ Abase, const short* __restrict__ WtBase,
    const float* __restrict__ bq, const float* __restrict__ bk,
    const float* __restrict__ bv, short* __restrict__ OutBase) {
  int z = blockIdx.z;
  const short* A = Abase + (size_t)z * NROWS * DMODEL;
  const short* Bt = WtBase + (size_t)z * DMODEL * DMODEL;
  const float* bias = (z == 0) ? bq : (z == 1) ? bk : bv;
  short* C = OutBase + (size_t)z * NROWS * DMODEL;
  // XCD swizzle: nwg=256 per z; XCD i gets contiguous swz chunk -> 4 A-panels
  int bid = blockIdx.x + (blockIdx.y << 3);
  int swz = ((bid & 7) << 5) + (bid >> 3);
  int bn = (swz & 7) << 7;
  int bm = (swz >> 3) << 7;
  gemm_core128<true>(A, Bt, bias, C, bm, bn);
}

// output projection: grid (16, 32), 128x64 tile, XCD-swizzled
__global__ __launch_bounds__(256) void gemm_out(const short* __restrict__ A,
                                                const short* __restrict__ Bt,
                                                const float* __restrict__ bias,
                                                float* __restrict__ C) {
  int bid = blockIdx.x + (blockIdx.y << 4);  // nwg=512
  int swz = ((bid & 7) << 6) + (bid >> 3);
  int bn = (swz & 15) << 6;
  int bm = (swz >> 4) << 7;
  gemm_core64<false>(A, Bt, bias, C, bm, bn);
}

// ---------------- h_k: 256 blocks x 256 thr; thread = one (row,head); 1 atomic/block ----------------
__global__ __launch_bounds__(256) void hk_kernel(const short* __restrict__ Kb,
                                                 float* __restrict__ hkbuf,
                                                 unsigned* __restrict__ kord) {
  int tid = threadIdx.x;
  int rloc = tid >> 4, h = tid & 15;
  int n = blockIdx.x * 16 + rloc;
  const short* p = Kb + (size_t)n * DMODEL + h * HD;
  float ss = 0.f;
#pragma unroll
  for (int g = 0; g < 8; ++g) {
    bf16x8 v = *(const bf16x8*)(p + g * 8);
#pragma unroll
    for (int e = 0; e < 8; ++e) {
      float x = bs2f(v[e]);
      ss += x * x;
    }
  }
  float hkv = -0.5f * SCAL2 * ss;
  int b = n >> 11, l = n & (SEQ - 1);
  hkbuf[((size_t)(b * NH + h)) * SEQ + l] = hkv;
  __shared__ float red[256];
  red[tid] = hkv;
  __syncthreads();
  for (int s = 128; s > 0; s >>= 1) {
    if (tid < s) red[tid] = fmaxf(red[tid], red[tid + s]);
    __syncthreads();
  }
  if (tid == 0) atomicMax(kord, f2ord(red[0]));
}

// ---------------- feature map via MFMA (fast-exp epilogue) ----------------
__global__ __launch_bounds__(256, 1) void featmap_mfma(
    const short* __restrict__ Qproj, const short* __restrict__ Kproj,
    const short* __restrict__ rfb, const float* __restrict__ hkbuf,
    const unsigned* __restrict__ kord, short* __restrict__ Qp,
    short* __restrict__ Kp) {
  __shared__ short smem[26624];  // A:8192 | B:18432 ; epilogue reuses as P[128][152]
  __shared__ float hks[128];
  short* As = smem;
  short* Bs = smem + 8192;
  int isK = blockIdx.z;
  const short* X = isK ? Kproj : Qproj;
  short* O = isK ? Kp : Qp;
  int bh = blockIdx.y, b = bh >> 4, h = bh & 15;
  int l0 = blockIdx.x << 7;
  int tid = threadIdx.x, lane = tid & 63, wid = tid >> 6;
  int cl = lane & 15, rq = lane >> 4;

#pragma unroll
  for (int i = 0; i < 4; ++i) {
    int e = tid * 8 + i * 2048;
    int row = e >> 6;
    int k = (e & 63) ^ ((row & 7) << 3);
    gload_lds16(X + ((size_t)b * SEQ + l0 + row) * DMODEL + h * HD + k,
                &As[wid * 512 + i * 2048]);
  }
#pragma unroll
  for (int i = 0; i < 9; ++i) {
    int e = tid * 8 + i * 2048;
    int row = e >> 6;
    int k = (e & 63) ^ ((row & 7) << 3);
    gload_lds16(rfb + row * HD + k, &Bs[wid * 512 + i * 2048]);
  }
  if (isK) {
    float ksv = ord2f(*kord);
    if (tid < 128)
      hks[tid] = hkbuf[(size_t)bh * SEQ + l0 + tid] - ksv + LN_CNORM;
  }
  __syncthreads();

  int i0 = wid * 32;
  f32x4 acc[2][18];
#pragma unroll
  for (int m = 0; m < 2; ++m)
#pragma unroll
    for (int n = 0; n < 18; ++n) acc[m][n] = f32x4{0.f, 0.f, 0.f, 0.f};
#pragma unroll
  for (int ks = 0; ks < 2; ++ks) {
    int kb = ks * 32 + (rq << 3);
    int swz = (cl & 7) << 3;
    bf16x8 af[2];
#pragma unroll
    for (int mf = 0; mf < 2; ++mf) {
      int row = i0 + mf * 16 + cl;
      af[mf] = *(const bf16x8*)&As[row * 64 + (kb ^ swz)];
    }
#pragma unroll
    for (int nf = 0; nf < 18; ++nf) {
      int brow = nf * 16 + cl;
      bf16x8 bv = *(const bf16x8*)&Bs[brow * 64 + (kb ^ swz)];
#pragma unroll
      for (int mf = 0; mf < 2; ++mf)
        acc[mf][nf] = __builtin_amdgcn_mfma_f32_16x16x32_bf16(af[mf], bv,
                                                              acc[mf][nf], 0, 0, 0);
    }
  }

  short* Ps = smem;  // [128][152]
#pragma unroll
  for (int hf = 0; hf < 2; ++hf) {
    __syncthreads();
#pragma unroll
    for (int mf = 0; mf < 2; ++mf)
#pragma unroll
      for (int r = 0; r < 4; ++r) {
        int rl = i0 + mf * 16 + (rq << 2) + r;
        float addk = isK ? hks[rl] : LN_CNORM;
#pragma unroll
        for (int nf2 = 0; nf2 < 9; ++nf2) {
          int m = hf * 144 + nf2 * 16 + cl;
          float v = acc[mf][hf * 9 + nf2][r] + addk;
          float o = (m < NRF) ? (__expf(v) + CKEPS) : 0.f;
          Ps[rl * 152 + nf2 * 16 + cl] = f2bs(o);
        }
      }
    __syncthreads();
#pragma unroll
    for (int it = 0; it < 9; ++it) {
      int idx = tid + it * 256;
      int row = idx / 18, ch = idx - row * 18;
      bf16x8 val = *(const bf16x8*)&Ps[row * 152 + ch * 8];
      *(bf16x8*)&O[((size_t)bh * SEQ + l0 + row) * NRFP + hf * 144 + ch * 8] = val;
    }
  }
}

// ---------------- per-chunk sums via MFMA ----------------
__global__ __launch_bounds__(256) void chunksum_mfma(
    const short* __restrict__ Kp, const short* __restrict__ Vb,
    short* __restrict__ Schunk, float* __restrict__ ksum) {
  constexpr int ST = 70;
  __shared__ short KT[NRFP * ST];  // [m][i_loc]
  __shared__ short VT[HD * ST];    // [d][i_loc]
  int c = blockIdx.x, bh = blockIdx.y;
  int b = bh >> 4, h = bh & 15;
  int tid = threadIdx.x, lane = tid & 63, wv = tid >> 6;
  int cl = lane & 15, rq = lane >> 4;
  int irow = tid >> 2;
  int mq = tid & 3;
  size_t rowb = (size_t)bh * SEQ + (size_t)c * CHK;

  f32x4 acc[18];
#pragma unroll
  for (int m = 0; m < 18; ++m) acc[m] = f32x4{0.f, 0.f, 0.f, 0.f};
  float k1 = 0.f, k2 = 0.f;

  for (int hf = 0; hf < 2; ++hf) {
    __syncthreads();
    const short* Krow = Kp + (rowb + hf * 64 + irow) * NRFP;
#pragma unroll
    for (int cg = 0; cg < 9; ++cg) {
      int m0 = cg * 32 + mq * 8;
      bf16x8 v = *(const bf16x8*)(Krow + m0);
#pragma unroll
      for (int e = 0; e < 8; ++e) KT[(m0 + e) * ST + irow] = v[e];
    }
    const short* Vrow =
        Vb + ((size_t)b * SEQ + (size_t)c * CHK + hf * 64 + irow) * DMODEL + h * HD;
    {
      int d0 = mq * 16;
      bf16x8 v0 = *(const bf16x8*)(Vrow + d0);
      bf16x8 v1 = *(const bf16x8*)(Vrow + d0 + 8);
#pragma unroll
      for (int e = 0; e < 8; ++e) VT[(d0 + e) * ST + irow] = v0[e];
#pragma unroll
      for (int e = 0; e < 8; ++e) VT[(d0 + 8 + e) * ST + irow] = v1[e];
    }
    __syncthreads();
#pragma unroll
    for (int ks = 0; ks < 2; ++ks) {
      int kb = ks * 32 + rq * 8;
      bf16x8 bv = *(const bf16x8*)&VT[(wv * 16 + cl) * ST + kb];
#pragma unroll
      for (int mf = 0; mf < 18; ++mf) {
        bf16x8 av = *(const bf16x8*)&KT[(mf * 16 + cl) * ST + kb];
        acc[mf] = __builtin_amdgcn_mfma_f32_16x16x32_bf16(av, bv, acc[mf], 0, 0, 0);
      }
    }
    {
      const short* r1 = &KT[tid * ST];
#pragma unroll
      for (int g = 0; g < 8; ++g) {
        bf16x8 v = *(const bf16x8*)(r1 + g * 8);
#pragma unroll
        for (int e = 0; e < 8; ++e) k1 += bs2f(v[e]);
      }
      if (tid < 10) {
        const short* r2 = &KT[(256 + tid) * ST];
#pragma unroll
        for (int g = 0; g < 8; ++g) {
          bf16x8 v = *(const bf16x8*)(r2 + g * 8);
#pragma unroll
          for (int e = 0; e < 8; ++e) k2 += bs2f(v[e]);
        }
      }
    }
  }
  size_t sbase = ((size_t)bh * NCH + c) * (size_t)(NRFP * HD);
  size_t kbase = ((size_t)bh * NCH + c) * (size_t)NRF;
#pragma unroll
  for (int mf = 0; mf < 18; ++mf)
#pragma unroll
    for (int r = 0; r < 4; ++r) {
      int m = mf * 16 + rq * 4 + r;
      Schunk[sbase + (size_t)m * HD + wv * 16 + cl] = f2bs(acc[mf][r]);
    }
  if (tid < NRF) ksum[kbase + tid] = k1;
  if (tid < 10) ksum[kbase + 256 + tid] = k2;
}

// ---------------- fused exclusive prefixes: S (x<72) and ksum (x==72) ----------------
__global__ __launch_bounds__(256) void prefix_all(const short* __restrict__ Sc,
                                                  short* __restrict__ Sp,
                                                  float* __restrict__ ksum) {
  int bh = blockIdx.y;
  if (blockIdx.x == 72) {
    for (int m = threadIdx.x; m < NRF; m += 256) {
      size_t base = (size_t)bh * NCH * NRF + m;
      float a = 0.f;
#pragma unroll
      for (int c = 0; c < NCH; ++c) {
        size_t idx = base + (size_t)c * NRF;
        float v = ksum[idx];
        ksum[idx] = a;
        a += v;
      }
    }
    return;
  }
  int e = blockIdx.x * 256 + threadIdx.x;
  size_t base = (size_t)bh * NCH * (NRFP * HD) + e;
  float a = 0.f;
#pragma unroll
  for (int c = 0; c < NCH; ++c) {
    size_t idx = base + (size_t)c * (NRFP * HD);
    float v = bs2f(Sc[idx]);
    Sp[idx] = f2bs(a);
    a += v;
  }
}

// ---------------- inter-chunk via MFMA ----------------
__global__ __launch_bounds__(256) void inter_mfma(
    const short* __restrict__ Qp, const short* __restrict__ Sp,
    const float* __restrict__ ksum, float* __restrict__ numA,
    float* __restrict__ denA) {
  int c = blockIdx.x, bh = blockIdx.y;
  __shared__ short Bs[64 * 296];
  __shared__ float ks[272];
  int tid = threadIdx.x, lane = tid & 63, wid = tid >> 6;
  const short* Spb = Sp + ((size_t)bh * NCH + c) * (size_t)(NRFP * HD);
  for (int idx = tid; idx < NRFP * HD; idx += 256) {
    int m = idx >> 6, d = idx & 63;
    Bs[d * 296 + m] = Spb[idx];
  }
  const float* ksb = ksum + ((size_t)bh * NCH + c) * (size_t)NRF;
  for (int idx = tid; idx < NRF; idx += 256) ks[idx] = ksb[idx];
  __syncthreads();
  int row0 = wid * 32;
  const short* Arow = Qp + ((size_t)bh * SEQ + (size_t)c * CHK + row0) * NRFP;
  f32x4 acc[2][4];
#pragma unroll
  for (int m = 0; m < 2; ++m)
#pragma unroll
    for (int n = 0; n < 4; ++n) acc[m][n] = f32x4{0.f, 0.f, 0.f, 0.f};
#pragma unroll
  for (int k9 = 0; k9 < 9; ++k9) {
    int kb = k9 * 32 + ((lane >> 4) << 3);
    bf16x8 af[2], bfv[4];
#pragma unroll
    for (int mf = 0; mf < 2; ++mf)
      af[mf] = *(const bf16x8*)(Arow + (size_t)(mf * 16 + (lane & 15)) * NRFP + kb);
#pragma unroll
    for (int nf = 0; nf < 4; ++nf)
      bfv[nf] = *(const bf16x8*)&Bs[(nf * 16 + (lane & 15)) * 296 + kb];
#pragma unroll
    for (int mf = 0; mf < 2; ++mf)
#pragma unroll
      for (int nf = 0; nf < 4; ++nf)
        acc[mf][nf] = __builtin_amdgcn_mfma_f32_16x16x32_bf16(af[mf], bfv[nf],
                                                              acc[mf][nf], 0, 0, 0);
  }
  size_t nb = ((size_t)bh * SEQ + (size_t)c * CHK + row0) * HD;
#pragma unroll
  for (int mf = 0; mf < 2; ++mf)
#pragma unroll
    for (int nf = 0; nf < 4; ++nf)
#pragma unroll
      for (int r = 0; r < 4; ++r) {
        int row = mf * 16 + ((lane >> 4) << 2) + r;
        int col = nf * 16 + (lane & 15);
        numA[nb + (size_t)row * HD + col] = acc[mf][nf][r];
      }
  int r = tid >> 1, half = tid & 1;
  const short* qr = Qp + ((size_t)bh * SEQ + (size_t)c * CHK + r) * NRFP;
  float s = 0.f;
  int m0 = half * 133;
  for (int m = m0; m < m0 + 133; ++m) s += bs2f(qr[m]) * ks[m];
  s += __shfl_xor(s, 1);
  if (!half) denA[(size_t)bh * SEQ + (size_t)c * CHK + r] = s;
}

// ---------------- intra-chunk via MFMA ----------------
__global__ __launch_bounds__(256) void intra_mfma(
    const short* __restrict__ Qp, const short* __restrict__ Kp,
    const short* __restrict__ Vb, const float* __restrict__ numA,
    const float* __restrict__ denA, short* __restrict__ ctxb) {
  constexpr int PST = 136;
  __shared__ short Pl[4 * 32 * PST];
  __shared__ short Vt[64 * PST];
  __shared__ float den_s[128];
  int c = blockIdx.x, bh = blockIdx.y;
  int b = bh >> 4, h = bh & 15;
  int tid = threadIdx.x, lane = tid & 63, wid = tid >> 6;
  int cl = lane & 15, rq = lane >> 4;
  size_t rowb = (size_t)bh * SEQ + (size_t)c * CHK;

  {
    int jj = tid >> 3, d0 = (tid & 7) << 3;
#pragma unroll
    for (int jt = 0; jt < 4; ++jt) {
      int j = jj + jt * 32;
      bf16x8 v = *(const bf16x8*)(Vb + ((size_t)b * SEQ + (size_t)c * CHK + j) * DMODEL +
                                  h * HD + d0);
#pragma unroll
      for (int e = 0; e < 8; ++e) Vt[(d0 + e) * PST + j] = v[e];
    }
  }

  int i0 = wid * 32;
  const short* Arow = Qp + (rowb + i0) * NRFP;
  const short* Krow = Kp + rowb * NRFP;
  f32x4 acc[2][8];
#pragma unroll
  for (int m = 0; m < 2; ++m)
#pragma unroll
    for (int n = 0; n < 8; ++n) acc[m][n] = f32x4{0.f, 0.f, 0.f, 0.f};
#pragma unroll
  for (int k9 = 0; k9 < 9; ++k9) {
    int kb = k9 * 32 + ((lane >> 4) << 3);
    bf16x8 af[2];
#pragma unroll
    for (int mf = 0; mf < 2; ++mf)
      af[mf] = *(const bf16x8*)(Arow + (size_t)(mf * 16 + cl) * NRFP + kb);
#pragma unroll
    for (int nf = 0; nf < 8; ++nf) {
      bf16x8 bv = *(const bf16x8*)(Krow + (size_t)(nf * 16 + cl) * NRFP + kb);
#pragma unroll
      for (int mf = 0; mf < 2; ++mf)
        acc[mf][nf] = __builtin_amdgcn_mfma_f32_16x16x32_bf16(af[mf], bv,
                                                              acc[mf][nf], 0, 0, 0);
    }
  }
  float dsum[2][4];
#pragma unroll
  for (int mf = 0; mf < 2; ++mf)
#pragma unroll
    for (int r = 0; r < 4; ++r) dsum[mf][r] = 0.f;
#pragma unroll
  for (int mf = 0; mf < 2; ++mf)
#pragma unroll
    for (int r = 0; r < 4; ++r) {
      int rl = mf * 16 + (rq << 2) + r;
      int row = i0 + rl;
#pragma unroll
      for (int nf = 0; nf < 8; ++nf) {
        int col = nf * 16 + cl;
        float v = (col > row) ? 0.f : acc[mf][nf][r];
        dsum[mf][r] += v;
        Pl[wid * 32 * PST + rl * PST + col] = f2bs(v);
      }
    }
#pragma unroll
  for (int mf = 0; mf < 2; ++mf)
#pragma unroll
    for (int r = 0; r < 4; ++r) {
      float s = dsum[mf][r];
      s += __shfl_xor(s, 1);
      s += __shfl_xor(s, 2);
      s += __shfl_xor(s, 4);
      s += __shfl_xor(s, 8);
      if (cl == 0) den_s[i0 + mf * 16 + (rq << 2) + r] = s;
    }
  __syncthreads();

  f32x4 pacc[2][4];
#pragma unroll
  for (int m = 0; m < 2; ++m)
#pragma unroll
    for (int n = 0; n < 4; ++n) pacc[m][n] = f32x4{0.f, 0.f, 0.f, 0.f};
#pragma unroll
  for (int kk = 0; kk < 4; ++kk) {
    int kb = kk * 32 + ((lane >> 4) << 3);
    bf16x8 paf[2];
#pragma unroll
    for (int mf = 0; mf < 2; ++mf)
      paf[mf] = *(const bf16x8*)&Pl[wid * 32 * PST + (mf * 16 + cl) * PST + kb];
#pragma unroll
    for (int nf = 0; nf < 4; ++nf) {
      bf16x8 bv = *(const bf16x8*)&Vt[(nf * 16 + cl) * PST + kb];
#pragma unroll
      for (int mf = 0; mf < 2; ++mf)
        pacc[mf][nf] = __builtin_amdgcn_mfma_f32_16x16x32_bf16(paf[mf], bv,
                                                               pacc[mf][nf], 0, 0, 0);
    }
  }
#pragma unroll
  for (int mf = 0; mf < 2; ++mf)
#pragma unroll
    for (int r = 0; r < 4; ++r) {
      int row = i0 + mf * 16 + (rq << 2) + r;
      size_t grow = rowb + row;
      float inv = 1.0f / (denA[grow] + den_s[row]);
      size_t ob = ((size_t)b * SEQ + (size_t)c * CHK + row) * DMODEL + h * HD;
#pragma unroll
      for (int nf = 0; nf < 4; ++nf) {
        int d = nf * 16 + cl;
        float v = (numA[grow * HD + d] + pacc[mf][nf][r]) * inv;
        ctxb[ob + d] = f2bs(v);
      }
    }
}

// ---------------- launch ----------------
extern "C" void kernel_launch(void* const* d_in, const int* in_sizes, int n_in,
                              void* d_out, int out_size, void* d_ws, size_t ws_size,
                              hipStream_t stream) {
  (void)in_sizes; (void)n_in; (void)out_size;
  const float* query = (const float*)d_in[0];
  const float* key_  = (const float*)d_in[1];
  const float* value = (const float*)d_in[2];
  const float* Wq = (const float*)d_in[3];
  const float* bq = (const float*)d_in[4];
  const float* Wk = (const float*)d_in[5];
  const float* bk = (const float*)d_in[6];
  const float* Wv = (const float*)d_in[7];
  const float* bv = (const float*)d_in[8];
  const float* Wo = (const float*)d_in[9];
  const float* bo = (const float*)d_in[10];
  const float* rf = (const float*)d_in[11];

  constexpr size_t SZ_INBF = (size_t)NROWS * DMODEL * 2;
  constexpr size_t SZ_QP   = (size_t)NBH * SEQ * NRFP * 2;
  constexpr size_t SZ_WT   = (size_t)DMODEL * DMODEL * 2;
  constexpr size_t SZ_SCH  = (size_t)NBH * NCH * NRFP * HD * 2;
  constexpr size_t SZ_KS   = (size_t)NBH * NCH * NRF * 4;
  constexpr size_t SZ_HK   = (size_t)NBH * SEQ * 4;
  constexpr size_t SZ_NUMA = (size_t)NBH * SEQ * HD * 4;
  constexpr size_t SZ_RFB  = (size_t)NRFP * HD * 2;

  constexpr size_t O_QP   = 0;
  constexpr size_t O_KP   = O_QP + SZ_QP;
  constexpr size_t O_WT   = O_KP + SZ_QP;
  constexpr size_t O_QPR  = O_WT + 4 * SZ_WT;
  constexpr size_t O_SCH  = O_QPR + 3 * SZ_INBF;
  constexpr size_t O_SPR  = O_SCH + SZ_SCH;
  constexpr size_t O_KSUM = O_SPR + SZ_SCH;
  constexpr size_t O_HK   = O_KSUM + SZ_KS;
  constexpr size_t O_KST  = O_HK + SZ_HK;
  constexpr size_t O_NUMA = O_KST + 256;
  constexpr size_t O_DENA = O_NUMA + SZ_NUMA;
  constexpr size_t O_CTXB = O_DENA + SZ_HK;
  constexpr size_t O_RFB  = O_CTXB + SZ_INBF;
  constexpr size_t O_END  = O_RFB + SZ_RFB;
  if (ws_size < O_END) return;

  char* w = (char*)d_ws;
  short* Qbf  = (short*)(w + O_QP);
  short* Qp   = (short*)(w + O_QP);
  short* Kp   = (short*)(w + O_KP);
  short* WtB  = (short*)(w + O_WT);
  short* QprB = (short*)(w + O_QPR);
  short* Kpr  = (short*)(w + O_QPR + SZ_INBF);
  short* Vpr  = (short*)(w + O_QPR + 2 * SZ_INBF);
  short* Sch  = (short*)(w + O_SCH);
  short* Spr  = (short*)(w + O_SPR);
  float* ksum = (float*)(w + O_KSUM);
  float* hkbuf = (float*)(w + O_HK);
  unsigned* kord = (unsigned*)(w + O_KST);
  float* numA = (float*)(w + O_NUMA);
  float* denA = (float*)(w + O_DENA);
  short* ctxb = (short*)(w + O_CTXB);
  short* rfb  = (short*)(w + O_RFB);

  constexpr int NEL = NROWS * DMODEL;
  cvt3_kernel<<<dim3(NEL / 2048, 3), 256, 0, stream>>>(query, key_, value, Qbf);
  transpose4_bf16<<<dim3(32, 32, 4), 256, 0, stream>>>(Wq, Wk, Wv, Wo, WtB);
  rf_pad_bf16<<<(NRFP * HD) / 256, 256, 0, stream>>>(rf, rfb, kord);
  gemm_qkv3<<<dim3(8, 32, 3), 256, 0, stream>>>(Qbf, WtB, bq, bk, bv, QprB);
  hk_kernel<<<256, 256, 0, stream>>>(Kpr, hkbuf, kord);
  featmap_mfma<<<dim3(SEQ / 128, NBH, 2), 256, 0, stream>>>(QprB, Kpr, rfb, hkbuf,
                                                            kord, Qp, Kp);
  chunksum_mfma<<<dim3(NCH, NBH), 256, 0, stream>>>(Kp, Vpr, Sch, ksum);
  prefix_all<<<dim3(73, NBH), 256, 0, stream>>>(Sch, Spr, ksum);
  inter_mfma<<<dim3(NCH, NBH), 256, 0, stream>>>(Qp, Spr, ksum, numA, denA);
  intra_mfma<<<dim3(NCH, NBH), 256, 0, stream>>>(Qp, Kp, Vpr, numA, denA, ctxb);
  gemm_out<<<dim3(16, 32), 256, 0, stream>>>(ctxb, WtB + 3 * (size_t)DMODEL * DMODEL,
                                             bo, (float*)d_out);
}

// Round 10
// 187.050 us; speedup vs baseline: 1.3170x; 1.0443x over previous
//
#include <hip/hip_runtime.h>
#include <hip/hip_bf16.h>

#define BATCH 2
#define SEQ 2048
#define DMODEL 1024
#define NH 16
#define HD 64
#define NRF 266
#define NRFP 288   // padded feature dim (multiple of 32), cols [266,288) are zero
#define CHK 128
#define NCH 16
#define NBH 32
#define NROWS 4096  // BATCH*SEQ

constexpr float SCAL = 0.17677669529663687f;   // DMODEL^-0.25
constexpr float SCAL2 = 0.03125f;              // SCAL^2 = DMODEL^-0.5
constexpr float LN_CNORM = -2.7917480361965505f;   // ln(1/sqrt(266))
constexpr float CKEPS = 6.131393094576169e-6f;     // CNORM*KEPS

typedef short bf16x8 __attribute__((ext_vector_type(8)));
typedef float f32x4 __attribute__((ext_vector_type(4)));

__device__ __forceinline__ short f2bs(float v) {
  __hip_bfloat16 h = __float2bfloat16(v);
  return *reinterpret_cast<short*>(&h);
}
__device__ __forceinline__ float bs2f(short s) {
  __hip_bfloat16 h;
  *reinterpret_cast<short*>(&h) = s;
  return __bfloat162float(h);
}
__device__ __forceinline__ void gload_lds16(const void* g, void* l) {
  __builtin_amdgcn_global_load_lds(
      (const __attribute__((address_space(1))) void*)g,
      (__attribute__((address_space(3))) void*)l, 16, 0, 0);
}
// monotone float<->uint order encoding (for atomicMax over floats)
__device__ __forceinline__ unsigned f2ord(float f) {
  unsigned u = __float_as_uint(f);
  return (u & 0x80000000u) ? ~u : (u | 0x80000000u);
}
__device__ __forceinline__ float ord2f(unsigned e) {
  return (e & 0x80000000u) ? __uint_as_float(e & 0x7fffffffu)
                           : __uint_as_float(~e);
}

// ---------------- fused f32 -> bf16 convert for q,k,v ----------------
__global__ __launch_bounds__(256) void cvt3_kernel(const float* __restrict__ q,
                                                   const float* __restrict__ k,
                                                   const float* __restrict__ v,
                                                   short* __restrict__ out) {
  int z = blockIdx.y;
  const float* x = (z == 0) ? q : (z == 1) ? k : v;
  short* y = out + (size_t)z * NROWS * DMODEL;
  int i = (blockIdx.x * 256 + threadIdx.x) * 8;
  float4 a = *(const float4*)&x[i];
  float4 b = *(const float4*)&x[i + 4];
  bf16x8 o;
  o[0] = f2bs(a.x); o[1] = f2bs(a.y); o[2] = f2bs(a.z); o[3] = f2bs(a.w);
  o[4] = f2bs(b.x); o[5] = f2bs(b.y); o[6] = f2bs(b.z); o[7] = f2bs(b.w);
  *(bf16x8*)&y[i] = o;
}

// ---------------- rf pad + SCAL fold; also zero the kstab atomic slot ----------------
__global__ __launch_bounds__(256) void rf_pad_bf16(const float* __restrict__ rf,
                                                   short* __restrict__ rfb,
                                                   unsigned* __restrict__ kord) {
  int idx = blockIdx.x * 256 + threadIdx.x;  // grid 72*256 = 18432 exact
  rfb[idx] = (idx < NRF * HD) ? f2bs(rf[idx] * SCAL) : (short)0;
  if (idx == 0) *kord = 0u;
}

// ---------------- fused W transposes: W[K][N] f32 -> Wt[N][K] bf16, 4 weights ----------------
__global__ __launch_bounds__(256) void transpose4_bf16(
    const float* __restrict__ Wq, const float* __restrict__ Wk,
    const float* __restrict__ Wv, const float* __restrict__ Wo,
    short* __restrict__ WtBase) {
  __shared__ float t[32][33];
  int z = blockIdx.z;
  const float* W = (z == 0) ? Wq : (z == 1) ? Wk : (z == 2) ? Wv : Wo;
  short* Wt = WtBase + (size_t)z * DMODEL * DMODEL;
  int k0 = blockIdx.y << 5, n0 = blockIdx.x << 5;
  int tx = threadIdx.x & 31, ty = threadIdx.x >> 5;
#pragma unroll
  for (int rr = 0; rr < 4; ++rr) {
    int r = ty + (rr << 3);
    t[r][tx] = W[(size_t)(k0 + r) * DMODEL + n0 + tx];
  }
  __syncthreads();
#pragma unroll
  for (int rr = 0; rr < 4; ++rr) {
    int r = ty + (rr << 3);
    Wt[(size_t)(n0 + r) * DMODEL + k0 + tx] = f2bs(t[tx][r]);
  }
}

// ---------------- MFMA GEMM core 128x128, BK=64, 4 waves (2x2, 64x64 each) ----------------
template <bool OUTBF>
__device__ __forceinline__ void gemm_core128(const short* __restrict__ A,
                                             const short* __restrict__ Bt,
                                             const float* __restrict__ bias,
                                             void* __restrict__ C, int bm, int bn) {
  __shared__ short As[128 * 64];
  __shared__ short Bs[128 * 64];
  int tid = threadIdx.x;
  int lane = tid & 63, wid = tid >> 6;
  int wr = wid >> 1, wc = wid & 1;
  int cl = lane & 15, rq = lane >> 4;
  f32x4 acc[4][4];
#pragma unroll
  for (int m = 0; m < 4; ++m)
#pragma unroll
    for (int n = 0; n < 4; ++n) acc[m][n] = f32x4{0.f, 0.f, 0.f, 0.f};

  for (int k0 = 0; k0 < DMODEL; k0 += 64) {
    __syncthreads();
#pragma unroll
    for (int i = 0; i < 4; ++i) {
      int e = tid * 8 + i * 2048;
      int row = e >> 6;
      int k = (e & 63) ^ ((row & 7) << 3);
      gload_lds16(A + (size_t)(bm + row) * DMODEL + k0 + k,
                  &As[wid * 512 + i * 2048]);
    }
#pragma unroll
    for (int i = 0; i < 4; ++i) {
      int e = tid * 8 + i * 2048;
      int row = e >> 6;
      int k = (e & 63) ^ ((row & 7) << 3);
      gload_lds16(Bt + (size_t)(bn + row) * DMODEL + k0 + k,
                  &Bs[wid * 512 + i * 2048]);
    }
    __syncthreads();
#pragma unroll
    for (int ks = 0; ks < 2; ++ks) {
      int kb = ks * 32 + (rq << 3);
      bf16x8 af[4], bfv[4];
#pragma unroll
      for (int mf = 0; mf < 4; ++mf) {
        int row = wr * 64 + mf * 16 + cl;
        af[mf] = *(const bf16x8*)&As[row * 64 + (kb ^ ((row & 7) << 3))];
      }
#pragma unroll
      for (int nf = 0; nf < 4; ++nf) {
        int row = wc * 64 + nf * 16 + cl;
        bfv[nf] = *(const bf16x8*)&Bs[row * 64 + (kb ^ ((row & 7) << 3))];
      }
#pragma unroll
      for (int mf = 0; mf < 4; ++mf)
#pragma unroll
        for (int nf = 0; nf < 4; ++nf)
          acc[mf][nf] = __builtin_amdgcn_mfma_f32_16x16x32_bf16(af[mf], bfv[nf],
                                                                acc[mf][nf], 0, 0, 0);
    }
  }
  int rbase = bm + wr * 64 + (rq << 2);
  int cbase = bn + wc * 64 + cl;
#pragma unroll
  for (int nf = 0; nf < 4; ++nf) {
    int col = cbase + nf * 16;
    float bv = bias[col];
#pragma unroll
    for (int mf = 0; mf < 4; ++mf)
#pragma unroll
      for (int r = 0; r < 4; ++r) {
        int row = rbase + mf * 16 + r;
        float v = acc[mf][nf][r] + bv;
        if (OUTBF)
          ((short*)C)[(size_t)row * DMODEL + col] = f2bs(v);
        else
          ((float*)C)[(size_t)row * DMODEL + col] = v;
      }
  }
}

// ---------------- MFMA GEMM core 128x64, BK=64, 4 waves (2x2) ----------------
template <bool OUTBF>
__device__ __forceinline__ void gemm_core64(const short* __restrict__ A,
                                            const short* __restrict__ Bt,
                                            const float* __restrict__ bias,
                                            void* __restrict__ C, int bm, int bn) {
  __shared__ short As[128 * 64];
  __shared__ short Bs[64 * 64];
  int tid = threadIdx.x;
  int lane = tid & 63, wid = tid >> 6;
  int wr = wid >> 1, wc = wid & 1;
  f32x4 acc[4][2];
#pragma unroll
  for (int m = 0; m < 4; ++m)
#pragma unroll
    for (int n = 0; n < 2; ++n) acc[m][n] = f32x4{0.f, 0.f, 0.f, 0.f};

  for (int k0 = 0; k0 < DMODEL; k0 += 64) {
    __syncthreads();
#pragma unroll
    for (int i = 0; i < 4; ++i) {
      int e = tid * 8 + i * 2048;
      int row = e >> 6;
      int k = (e & 63) ^ ((row & 7) << 3);
      gload_lds16(A + (size_t)(bm + row) * DMODEL + k0 + k,
                  &As[wid * 512 + i * 2048]);
    }
#pragma unroll
    for (int i = 0; i < 2; ++i) {
      int e = tid * 8 + i * 2048;
      int row = e >> 6;
      int k = (e & 63) ^ ((row & 7) << 3);
      gload_lds16(Bt + (size_t)(bn + row) * DMODEL + k0 + k,
                  &Bs[wid * 512 + i * 2048]);
    }
    __syncthreads();
#pragma unroll
    for (int ks = 0; ks < 2; ++ks) {
      int kb = ks * 32 + ((lane >> 4) << 3);
      bf16x8 af[4], bfv[2];
#pragma unroll
      for (int mf = 0; mf < 4; ++mf) {
        int row = wr * 64 + mf * 16 + (lane & 15);
        af[mf] = *(const bf16x8*)&As[row * 64 + (kb ^ ((row & 7) << 3))];
      }
#pragma unroll
      for (int nf = 0; nf < 2; ++nf) {
        int row = wc * 32 + nf * 16 + (lane & 15);
        bfv[nf] = *(const bf16x8*)&Bs[row * 64 + (kb ^ ((row & 7) << 3))];
      }
#pragma unroll
      for (int mf = 0; mf < 4; ++mf)
#pragma unroll
        for (int nf = 0; nf < 2; ++nf)
          acc[mf][nf] = __builtin_amdgcn_mfma_f32_16x16x32_bf16(af[mf], bfv[nf],
                                                                acc[mf][nf], 0, 0, 0);
    }
  }
  int rbase = bm + wr * 64 + ((lane >> 4) << 2);
  int cbase = bn + wc * 32 + (lane & 15);
#pragma unroll
  for (int nf = 0; nf < 2; ++nf) {
    int col = cbase + nf * 16;
    float bv = bias[col];
#pragma unroll
    for (int mf = 0; mf < 4; ++mf)
#pragma unroll
      for (int r = 0; r < 4; ++r) {
        int row = rbase + mf * 16 + r;
        float v = acc[mf][nf][r] + bv;
        if (OUTBF)
          ((short*)C)[(size_t)row * DMODEL + col] = f2bs(v);
        else
          ((float*)C)[(size_t)row * DMODEL + col] = v;
      }
  }
}

// fused QKV projection: grid (8, 32, 3), 128x128 tile, XCD-swizzled
__global__ __launch_bounds__(256) void gemm_qkv3(
    const short* __restrict__ Abase, const short* __restrict__ WtBase,
    const float* __restrict__ bq, const float* __restrict__ bk,
    const float* __restrict__ bv, short* __restrict__ OutBase) {
  int z = blockIdx.z;
  const short* A = Abase + (size_t)z * NROWS * DMODEL;
  const short* Bt = WtBase + (size_t)z * DMODEL * DMODEL;
  const float* bias = (z == 0) ? bq : (z == 1) ? bk : bv;
  short* C = OutBase + (size_t)z * NROWS * DMODEL;
  int bid = blockIdx.x + (blockIdx.y << 3);
  int swz = ((bid & 7) << 5) + (bid >> 3);
  int bn = (swz & 7) << 7;
  int bm = (swz >> 3) << 7;
  gemm_core128<true>(A, Bt, bias, C, bm, bn);
}

// output projection: grid (16, 32), 128x64 tile, XCD-swizzled
__global__ __launch_bounds__(256) void gemm_out(const short* __restrict__ A,
                                                const short* __restrict__ Bt,
                                                const float* __restrict__ bias,
                                                float* __restrict__ C) {
  int bid = blockIdx.x + (blockIdx.y << 4);  // nwg=512
  int swz = ((bid & 7) << 6) + (bid >> 3);
  int bn = (swz & 15) << 6;
  int bm = (swz >> 4) << 7;
  gemm_core64<false>(A, Bt, bias, C, bm, bn);
}

// ---------------- h_k: 256 blocks x 256 thr; thread = one (row,head); 1 atomic/block ----------------
__global__ __launch_bounds__(256) void hk_kernel(const short* __restrict__ Kb,
                                                 float* __restrict__ hkbuf,
                                                 unsigned* __restrict__ kord) {
  int tid = threadIdx.x;
  int rloc = tid >> 4, h = tid & 15;
  int n = blockIdx.x * 16 + rloc;
  const short* p = Kb + (size_t)n * DMODEL + h * HD;
  float ss = 0.f;
#pragma unroll
  for (int g = 0; g < 8; ++g) {
    bf16x8 v = *(const bf16x8*)(p + g * 8);
#pragma unroll
    for (int e = 0; e < 8; ++e) {
      float x = bs2f(v[e]);
      ss += x * x;
    }
  }
  float hkv = -0.5f * SCAL2 * ss;
  int b = n >> 11, l = n & (SEQ - 1);
  hkbuf[((size_t)(b * NH + h)) * SEQ + l] = hkv;
  __shared__ float red[256];
  red[tid] = hkv;
  __syncthreads();
  for (int s = 128; s > 0; s >>= 1) {
    if (tid < s) red[tid] = fmaxf(red[tid], red[tid + s]);
    __syncthreads();
  }
  if (tid == 0) atomicMax(kord, f2ord(red[0]));
}

// ---------------- feature map via MFMA (fast-exp epilogue) ----------------
__global__ __launch_bounds__(256, 1) void featmap_mfma(
    const short* __restrict__ Qproj, const short* __restrict__ Kproj,
    const short* __restrict__ rfb, const float* __restrict__ hkbuf,
    const unsigned* __restrict__ kord, short* __restrict__ Qp,
    short* __restrict__ Kp) {
  __shared__ short smem[26624];  // A:8192 | B:18432 ; epilogue reuses as P[128][152]
  __shared__ float hks[128];
  short* As = smem;
  short* Bs = smem + 8192;
  int isK = blockIdx.z;
  const short* X = isK ? Kproj : Qproj;
  short* O = isK ? Kp : Qp;
  int bh = blockIdx.y, b = bh >> 4, h = bh & 15;
  int l0 = blockIdx.x << 7;
  int tid = threadIdx.x, lane = tid & 63, wid = tid >> 6;
  int cl = lane & 15, rq = lane >> 4;

#pragma unroll
  for (int i = 0; i < 4; ++i) {
    int e = tid * 8 + i * 2048;
    int row = e >> 6;
    int k = (e & 63) ^ ((row & 7) << 3);
    gload_lds16(X + ((size_t)b * SEQ + l0 + row) * DMODEL + h * HD + k,
                &As[wid * 512 + i * 2048]);
  }
#pragma unroll
  for (int i = 0; i < 9; ++i) {
    int e = tid * 8 + i * 2048;
    int row = e >> 6;
    int k = (e & 63) ^ ((row & 7) << 3);
    gload_lds16(rfb + row * HD + k, &Bs[wid * 512 + i * 2048]);
  }
  if (isK) {
    float ksv = ord2f(*kord);
    if (tid < 128)
      hks[tid] = hkbuf[(size_t)bh * SEQ + l0 + tid] - ksv + LN_CNORM;
  }
  __syncthreads();

  int i0 = wid * 32;
  f32x4 acc[2][18];
#pragma unroll
  for (int m = 0; m < 2; ++m)
#pragma unroll
    for (int n = 0; n < 18; ++n) acc[m][n] = f32x4{0.f, 0.f, 0.f, 0.f};
#pragma unroll
  for (int ks = 0; ks < 2; ++ks) {
    int kb = ks * 32 + (rq << 3);
    int swz = (cl & 7) << 3;
    bf16x8 af[2];
#pragma unroll
    for (int mf = 0; mf < 2; ++mf) {
      int row = i0 + mf * 16 + cl;
      af[mf] = *(const bf16x8*)&As[row * 64 + (kb ^ swz)];
    }
#pragma unroll
    for (int nf = 0; nf < 18; ++nf) {
      int brow = nf * 16 + cl;
      bf16x8 bv = *(const bf16x8*)&Bs[brow * 64 + (kb ^ swz)];
#pragma unroll
      for (int mf = 0; mf < 2; ++mf)
        acc[mf][nf] = __builtin_amdgcn_mfma_f32_16x16x32_bf16(af[mf], bv,
                                                              acc[mf][nf], 0, 0, 0);
    }
  }

  short* Ps = smem;  // [128][152]
#pragma unroll
  for (int hf = 0; hf < 2; ++hf) {
    __syncthreads();
#pragma unroll
    for (int mf = 0; mf < 2; ++mf)
#pragma unroll
      for (int r = 0; r < 4; ++r) {
        int rl = i0 + mf * 16 + (rq << 2) + r;
        float addk = isK ? hks[rl] : LN_CNORM;
#pragma unroll
        for (int nf2 = 0; nf2 < 9; ++nf2) {
          int m = hf * 144 + nf2 * 16 + cl;
          float v = acc[mf][hf * 9 + nf2][r] + addk;
          float o = (m < NRF) ? (__expf(v) + CKEPS) : 0.f;
          Ps[rl * 152 + nf2 * 16 + cl] = f2bs(o);
        }
      }
    __syncthreads();
#pragma unroll
    for (int it = 0; it < 9; ++it) {
      int idx = tid + it * 256;
      int row = idx / 18, ch = idx - row * 18;
      bf16x8 val = *(const bf16x8*)&Ps[row * 152 + ch * 8];
      *(bf16x8*)&O[((size_t)bh * SEQ + l0 + row) * NRFP + hf * 144 + ch * 8] = val;
    }
  }
}

// ---------------- per-chunk sums via MFMA ----------------
__global__ __launch_bounds__(256) void chunksum_mfma(
    const short* __restrict__ Kp, const short* __restrict__ Vb,
    short* __restrict__ Schunk, float* __restrict__ ksum) {
  constexpr int ST = 70;
  __shared__ short KT[NRFP * ST];  // [m][i_loc]
  __shared__ short VT[HD * ST];    // [d][i_loc]
  int c = blockIdx.x, bh = blockIdx.y;
  int b = bh >> 4, h = bh & 15;
  int tid = threadIdx.x, lane = tid & 63, wv = tid >> 6;
  int cl = lane & 15, rq = lane >> 4;
  int irow = tid >> 2;
  int mq = tid & 3;
  size_t rowb = (size_t)bh * SEQ + (size_t)c * CHK;

  f32x4 acc[18];
#pragma unroll
  for (int m = 0; m < 18; ++m) acc[m] = f32x4{0.f, 0.f, 0.f, 0.f};
  float k1 = 0.f, k2 = 0.f;

  for (int hf = 0; hf < 2; ++hf) {
    __syncthreads();
    const short* Krow = Kp + (rowb + hf * 64 + irow) * NRFP;
#pragma unroll
    for (int cg = 0; cg < 9; ++cg) {
      int m0 = cg * 32 + mq * 8;
      bf16x8 v = *(const bf16x8*)(Krow + m0);
#pragma unroll
      for (int e = 0; e < 8; ++e) KT[(m0 + e) * ST + irow] = v[e];
    }
    const short* Vrow =
        Vb + ((size_t)b * SEQ + (size_t)c * CHK + hf * 64 + irow) * DMODEL + h * HD;
    {
      int d0 = mq * 16;
      bf16x8 v0 = *(const bf16x8*)(Vrow + d0);
      bf16x8 v1 = *(const bf16x8*)(Vrow + d0 + 8);
#pragma unroll
      for (int e = 0; e < 8; ++e) VT[(d0 + e) * ST + irow] = v0[e];
#pragma unroll
      for (int e = 0; e < 8; ++e) VT[(d0 + 8 + e) * ST + irow] = v1[e];
    }
    __syncthreads();
#pragma unroll
    for (int ks = 0; ks < 2; ++ks) {
      int kb = ks * 32 + rq * 8;
      bf16x8 bv = *(const bf16x8*)&VT[(wv * 16 + cl) * ST + kb];
#pragma unroll
      for (int mf = 0; mf < 18; ++mf) {
        bf16x8 av = *(const bf16x8*)&KT[(mf * 16 + cl) * ST + kb];
        acc[mf] = __builtin_amdgcn_mfma_f32_16x16x32_bf16(av, bv, acc[mf], 0, 0, 0);
      }
    }
    {
      const short* r1 = &KT[tid * ST];
#pragma unroll
      for (int g = 0; g < 8; ++g) {
        bf16x8 v = *(const bf16x8*)(r1 + g * 8);
#pragma unroll
        for (int e = 0; e < 8; ++e) k1 += bs2f(v[e]);
      }
      if (tid < 10) {
        const short* r2 = &KT[(256 + tid) * ST];
#pragma unroll
        for (int g = 0; g < 8; ++g) {
          bf16x8 v = *(const bf16x8*)(r2 + g * 8);
#pragma unroll
          for (int e = 0; e < 8; ++e) k2 += bs2f(v[e]);
        }
      }
    }
  }
  size_t sbase = ((size_t)bh * NCH + c) * (size_t)(NRFP * HD);
  size_t kbase = ((size_t)bh * NCH + c) * (size_t)NRF;
#pragma unroll
  for (int mf = 0; mf < 18; ++mf)
#pragma unroll
    for (int r = 0; r < 4; ++r) {
      int m = mf * 16 + rq * 4 + r;
      Schunk[sbase + (size_t)m * HD + wv * 16 + cl] = f2bs(acc[mf][r]);
    }
  if (tid < NRF) ksum[kbase + tid] = k1;
  if (tid < 10) ksum[kbase + 256 + tid] = k2;
}

// ---------------- fused exclusive prefixes: S (x<72) and ksum (x==72) ----------------
__global__ __launch_bounds__(256) void prefix_all(const short* __restrict__ Sc,
                                                  short* __restrict__ Sp,
                                                  float* __restrict__ ksum) {
  int bh = blockIdx.y;
  if (blockIdx.x == 72) {
    for (int m = threadIdx.x; m < NRF; m += 256) {
      size_t base = (size_t)bh * NCH * NRF + m;
      float a = 0.f;
#pragma unroll
      for (int c = 0; c < NCH; ++c) {
        size_t idx = base + (size_t)c * NRF;
        float v = ksum[idx];
        ksum[idx] = a;
        a += v;
      }
    }
    return;
  }
  int e = blockIdx.x * 256 + threadIdx.x;
  size_t base = (size_t)bh * NCH * (NRFP * HD) + e;
  float a = 0.f;
#pragma unroll
  for (int c = 0; c < NCH; ++c) {
    size_t idx = base + (size_t)c * (NRFP * HD);
    float v = bs2f(Sc[idx]);
    Sp[idx] = f2bs(a);
    a += v;
  }
}

// ---------------- FUSED inter+intra: out = (Q'@Sprev + mask(Q'K'^T)@V) / (Q'.ksum + rowsum)
// grid (NCH, NBH), 256 thr = 4 waves; wave owns 32 rows of the 128-row chunk.
__global__ __launch_bounds__(256) void attn_mfma(
    const short* __restrict__ Qp, const short* __restrict__ Kp,
    const short* __restrict__ Vb, const short* __restrict__ Sp,
    const float* __restrict__ ksum, short* __restrict__ ctxb) {
  constexpr int PST = 136;  // Vt / Pl row stride (shorts)
  constexpr int BST = 290;  // Sp^T row stride (shorts): odd dword stride -> conflict-free
  __shared__ short Vt[64 * PST];     // V^T [d][j]           17408 B
  __shared__ short BsPl[64 * BST];   // Sp^T [d][m] -> later P [4][32][PST]   37120 B
  __shared__ float ks[272];
  __shared__ float den[128];
  int c = blockIdx.x, bh = blockIdx.y;
  int b = bh >> 4, h = bh & 15;
  int tid = threadIdx.x, lane = tid & 63, wid = tid >> 6;
  int cl = lane & 15, rq = lane >> 4;
  size_t rowb = (size_t)bh * SEQ + (size_t)c * CHK;

  // stage V^T: Vt[d][j] = V[c*CHK+j][h*HD+d]
  {
    int jj = tid >> 3, d0 = (tid & 7) << 3;
#pragma unroll
    for (int jt = 0; jt < 4; ++jt) {
      int j = jj + jt * 32;
      bf16x8 v = *(const bf16x8*)(Vb + ((size_t)b * SEQ + (size_t)c * CHK + j) * DMODEL +
                                  h * HD + d0);
#pragma unroll
      for (int e = 0; e < 8; ++e) Vt[(d0 + e) * PST + j] = v[e];
    }
  }
  // stage Sp^T: BsPl[d*BST + m] = Sp[m*HD + d]
  const short* Spb = Sp + ((size_t)bh * NCH + c) * (size_t)(NRFP * HD);
  for (int idx = tid; idx < NRFP * HD; idx += 256) {
    int m = idx >> 6, d = idx & 63;
    BsPl[d * BST + m] = Spb[idx];
  }
  const float* ksb = ksum + ((size_t)bh * NCH + c) * (size_t)NRF;
  for (int idx = tid; idx < NRF; idx += 256) ks[idx] = ksb[idx];
  __syncthreads();

  int i0 = wid * 32;
  const short* Arow = Qp + (rowb + i0) * NRFP;
  const short* Krow = Kp + rowb * NRFP;
  f32x4 accI[2][4];  // inter numerator (Q' @ Sprev), kept in registers
  f32x4 accP[2][8];  // P = Q'K'^T
#pragma unroll
  for (int m = 0; m < 2; ++m) {
#pragma unroll
    for (int n = 0; n < 4; ++n) accI[m][n] = f32x4{0.f, 0.f, 0.f, 0.f};
#pragma unroll
    for (int n = 0; n < 8; ++n) accP[m][n] = f32x4{0.f, 0.f, 0.f, 0.f};
  }
#pragma unroll
  for (int k9 = 0; k9 < 9; ++k9) {
    int kb = k9 * 32 + (rq << 3);
    bf16x8 af[2];
#pragma unroll
    for (int mf = 0; mf < 2; ++mf)
      af[mf] = *(const bf16x8*)(Arow + (size_t)(mf * 16 + cl) * NRFP + kb);
    // inter: vs Sp^T in LDS
#pragma unroll
    for (int nf = 0; nf < 4; ++nf) {
      bf16x8 bv = *(const bf16x8*)&BsPl[(nf * 16 + cl) * BST + kb];
#pragma unroll
      for (int mf = 0; mf < 2; ++mf)
        accI[mf][nf] = __builtin_amdgcn_mfma_f32_16x16x32_bf16(af[mf], bv,
                                                               accI[mf][nf], 0, 0, 0);
    }
    // intra P: vs K' rows from global
#pragma unroll
    for (int nf = 0; nf < 8; ++nf) {
      bf16x8 bv = *(const bf16x8*)(Krow + (size_t)(nf * 16 + cl) * NRFP + kb);
#pragma unroll
      for (int mf = 0; mf < 2; ++mf)
        accP[mf][nf] = __builtin_amdgcn_mfma_f32_16x16x32_bf16(af[mf], bv,
                                                               accP[mf][nf], 0, 0, 0);
    }
  }
  // inter denominator: den[r] = q'_r . ksum_prefix  (2 threads per row)
  {
    int r = tid >> 1, half = tid & 1;
    const short* qr = Qp + (rowb + r) * NRFP;
    float s = 0.f;
    int m0 = half * 133;
    for (int m = m0; m < m0 + 133; ++m) s += bs2f(qr[m]) * ks[m];
    s += __shfl_xor(s, 1);
    if (!half) den[r] = s;
  }
  __syncthreads();  // all waves done reading BsPl (Sp^T); den[] written

  // mask, rowsum (+= den), write P into BsPl (now P region)
#pragma unroll
  for (int mf = 0; mf < 2; ++mf)
#pragma unroll
    for (int r = 0; r < 4; ++r) {
      int rl = mf * 16 + (rq << 2) + r;
      int row = i0 + rl;
      float dsum = 0.f;
#pragma unroll
      for (int nf = 0; nf < 8; ++nf) {
        int col = nf * 16 + cl;
        float v = (col > row) ? 0.f : accP[mf][nf][r];
        dsum += v;
        BsPl[wid * 32 * PST + rl * PST + col] = f2bs(v);
      }
      dsum += __shfl_xor(dsum, 1);
      dsum += __shfl_xor(dsum, 2);
      dsum += __shfl_xor(dsum, 4);
      dsum += __shfl_xor(dsum, 8);
      if (cl == 0) den[row] += dsum;
    }
  __syncthreads();  // P tiles + den complete

  // PV phase
  f32x4 pacc[2][4];
#pragma unroll
  for (int m = 0; m < 2; ++m)
#pragma unroll
    for (int n = 0; n < 4; ++n) pacc[m][n] = f32x4{0.f, 0.f, 0.f, 0.f};
#pragma unroll
  for (int kk = 0; kk < 4; ++kk) {
    int kb = kk * 32 + (rq << 3);
    bf16x8 paf[2];
#pragma unroll
    for (int mf = 0; mf < 2; ++mf)
      paf[mf] = *(const bf16x8*)&BsPl[wid * 32 * PST + (mf * 16 + cl) * PST + kb];
#pragma unroll
    for (int nf = 0; nf < 4; ++nf) {
      bf16x8 bv = *(const bf16x8*)&Vt[(nf * 16 + cl) * PST + kb];
#pragma unroll
      for (int mf = 0; mf < 2; ++mf)
        pacc[mf][nf] = __builtin_amdgcn_mfma_f32_16x16x32_bf16(paf[mf], bv,
                                                               pacc[mf][nf], 0, 0, 0);
    }
  }
  // finalize: (accI + pacc) / den  -- identical C-layouts, pure register add
#pragma unroll
  for (int mf = 0; mf < 2; ++mf)
#pragma unroll
    for (int r = 0; r < 4; ++r) {
      int row = i0 + mf * 16 + (rq << 2) + r;
      float inv = 1.0f / den[row];
      size_t ob = ((size_t)b * SEQ + (size_t)c * CHK + row) * DMODEL + h * HD;
#pragma unroll
      for (int nf = 0; nf < 4; ++nf) {
        int d = nf * 16 + cl;
        float v = (accI[mf][nf][r] + pacc[mf][nf][r]) * inv;
        ctxb[ob + d] = f2bs(v);
      }
    }
}

// ---------------- launch ----------------
extern "C" void kernel_launch(void* const* d_in, const int* in_sizes, int n_in,
                              void* d_out, int out_size, void* d_ws, size_t ws_size,
                              hipStream_t stream) {
  (void)in_sizes; (void)n_in; (void)out_size;
  const float* query = (const float*)d_in[0];
  const float* key_  = (const float*)d_in[1];
  const float* value = (const float*)d_in[2];
  const float* Wq = (const float*)d_in[3];
  const float* bq = (const float*)d_in[4];
  const float* Wk = (const float*)d_in[5];
  const float* bk = (const float*)d_in[6];
  const float* Wv = (const float*)d_in[7];
  const float* bv = (const float*)d_in[8];
  const float* Wo = (const float*)d_in[9];
  const float* bo = (const float*)d_in[10];
  const float* rf = (const float*)d_in[11];

  constexpr size_t SZ_INBF = (size_t)NROWS * DMODEL * 2;
  constexpr size_t SZ_QP   = (size_t)NBH * SEQ * NRFP * 2;
  constexpr size_t SZ_WT   = (size_t)DMODEL * DMODEL * 2;
  constexpr size_t SZ_SCH  = (size_t)NBH * NCH * NRFP * HD * 2;
  constexpr size_t SZ_KS   = (size_t)NBH * NCH * NRF * 4;
  constexpr size_t SZ_HK   = (size_t)NBH * SEQ * 4;
  constexpr size_t SZ_RFB  = (size_t)NRFP * HD * 2;

  constexpr size_t O_QP   = 0;
  constexpr size_t O_KP   = O_QP + SZ_QP;
  constexpr size_t O_WT   = O_KP + SZ_QP;
  constexpr size_t O_QPR  = O_WT + 4 * SZ_WT;
  constexpr size_t O_SCH  = O_QPR + 3 * SZ_INBF;
  constexpr size_t O_SPR  = O_SCH + SZ_SCH;
  constexpr size_t O_KSUM = O_SPR + SZ_SCH;
  constexpr size_t O_HK   = O_KSUM + SZ_KS;
  constexpr size_t O_KST  = O_HK + SZ_HK;
  constexpr size_t O_CTXB = O_KST + 256;
  constexpr size_t O_RFB  = O_CTXB + SZ_INBF;
  constexpr size_t O_END  = O_RFB + SZ_RFB;
  if (ws_size < O_END) return;

  char* w = (char*)d_ws;
  short* Qbf  = (short*)(w + O_QP);
  short* Qp   = (short*)(w + O_QP);
  short* Kp   = (short*)(w + O_KP);
  short* WtB  = (short*)(w + O_WT);
  short* QprB = (short*)(w + O_QPR);
  short* Kpr  = (short*)(w + O_QPR + SZ_INBF);
  short* Vpr  = (short*)(w + O_QPR + 2 * SZ_INBF);
  short* Sch  = (short*)(w + O_SCH);
  short* Spr  = (short*)(w + O_SPR);
  float* ksum = (float*)(w + O_KSUM);
  float* hkbuf = (float*)(w + O_HK);
  unsigned* kord = (unsigned*)(w + O_KST);
  short* ctxb = (short*)(w + O_CTXB);
  short* rfb  = (short*)(w + O_RFB);

  constexpr int NEL = NROWS * DMODEL;
  cvt3_kernel<<<dim3(NEL / 2048, 3), 256, 0, stream>>>(query, key_, value, Qbf);
  transpose4_bf16<<<dim3(32, 32, 4), 256, 0, stream>>>(Wq, Wk, Wv, Wo, WtB);
  rf_pad_bf16<<<(NRFP * HD) / 256, 256, 0, stream>>>(rf, rfb, kord);
  gemm_qkv3<<<dim3(8, 32, 3), 256, 0, stream>>>(Qbf, WtB, bq, bk, bv, QprB);
  hk_kernel<<<256, 256, 0, stream>>>(Kpr, hkbuf, kord);
  featmap_mfma<<<dim3(SEQ / 128, NBH, 2), 256, 0, stream>>>(QprB, Kpr, rfb, hkbuf,
                                                            kord, Qp, Kp);
  chunksum_mfma<<<dim3(NCH, NBH), 256, 0, stream>>>(Kp, Vpr, Sch, ksum);
  prefix_all<<<dim3(73, NBH), 256, 0, stream>>>(Sch, Spr, ksum);
  attn_mfma<<<dim3(NCH, NBH), 256, 0, stream>>>(Qp, Kp, Vpr, Spr, ksum, ctxb);
  gemm_out<<<dim3(16, 32), 256, 0, stream>>>(ctxb, WtB + 3 * (size_t)DMODEL * DMODEL,
                                             bo, (float*)d_out);
}

// Round 11
// 184.673 us; speedup vs baseline: 1.3339x; 1.0129x over previous
//
#include <hip/hip_runtime.h>
#include <hip/hip_bf16.h>

#define BATCH 2
#define SEQ 2048
#define DMODEL 1024
#define NH 16
#define HD 64
#define NRF 266
#define NRFP 288   // padded feature dim (multiple of 32), cols [266,288) are zero
#define CHK 128
#define NCH 16
#define NBH 32
#define NROWS 4096  // BATCH*SEQ

constexpr float SCAL = 0.17677669529663687f;   // DMODEL^-0.25
constexpr float SCAL2 = 0.03125f;              // SCAL^2 = DMODEL^-0.5
constexpr float LN_CNORM = -2.7917480361965505f;   // ln(1/sqrt(266))
constexpr float CKEPS = 6.131393094576169e-6f;     // CNORM*KEPS

typedef short bf16x8 __attribute__((ext_vector_type(8)));
typedef float f32x4 __attribute__((ext_vector_type(4)));

__device__ __forceinline__ short f2bs(float v) {
  __hip_bfloat16 h = __float2bfloat16(v);
  return *reinterpret_cast<short*>(&h);
}
__device__ __forceinline__ float bs2f(short s) {
  __hip_bfloat16 h;
  *reinterpret_cast<short*>(&h) = s;
  return __bfloat162float(h);
}
__device__ __forceinline__ void gload_lds16(const void* g, void* l) {
  __builtin_amdgcn_global_load_lds(
      (const __attribute__((address_space(1))) void*)g,
      (__attribute__((address_space(3))) void*)l, 16, 0, 0);
}
// monotone float<->uint order encoding (for atomicMax over floats)
__device__ __forceinline__ unsigned f2ord(float f) {
  unsigned u = __float_as_uint(f);
  return (u & 0x80000000u) ? ~u : (u | 0x80000000u);
}
__device__ __forceinline__ float ord2f(unsigned e) {
  return (e & 0x80000000u) ? __uint_as_float(e & 0x7fffffffu)
                           : __uint_as_float(~e);
}

// ---------------- fused f32 -> bf16 convert for q,k,v ----------------
__global__ __launch_bounds__(256) void cvt3_kernel(const float* __restrict__ q,
                                                   const float* __restrict__ k,
                                                   const float* __restrict__ v,
                                                   short* __restrict__ out) {
  int z = blockIdx.y;
  const float* x = (z == 0) ? q : (z == 1) ? k : v;
  short* y = out + (size_t)z * NROWS * DMODEL;
  int i = (blockIdx.x * 256 + threadIdx.x) * 8;
  float4 a = *(const float4*)&x[i];
  float4 b = *(const float4*)&x[i + 4];
  bf16x8 o;
  o[0] = f2bs(a.x); o[1] = f2bs(a.y); o[2] = f2bs(a.z); o[3] = f2bs(a.w);
  o[4] = f2bs(b.x); o[5] = f2bs(b.y); o[6] = f2bs(b.z); o[7] = f2bs(b.w);
  *(bf16x8*)&y[i] = o;
}

// ---------------- rf pad + SCAL fold; also zero the kstab atomic slot ----------------
__global__ __launch_bounds__(256) void rf_pad_bf16(const float* __restrict__ rf,
                                                   short* __restrict__ rfb,
                                                   unsigned* __restrict__ kord) {
  int idx = blockIdx.x * 256 + threadIdx.x;  // grid 72*256 = 18432 exact
  rfb[idx] = (idx < NRF * HD) ? f2bs(rf[idx] * SCAL) : (short)0;
  if (idx == 0) *kord = 0u;
}

// ---------------- fused W transposes: W[K][N] f32 -> Wt[N][K] bf16, 4 weights ----------------
__global__ __launch_bounds__(256) void transpose4_bf16(
    const float* __restrict__ Wq, const float* __restrict__ Wk,
    const float* __restrict__ Wv, const float* __restrict__ Wo,
    short* __restrict__ WtBase) {
  __shared__ float t[32][33];
  int z = blockIdx.z;
  const float* W = (z == 0) ? Wq : (z == 1) ? Wk : (z == 2) ? Wv : Wo;
  short* Wt = WtBase + (size_t)z * DMODEL * DMODEL;
  int k0 = blockIdx.y << 5, n0 = blockIdx.x << 5;
  int tx = threadIdx.x & 31, ty = threadIdx.x >> 5;
#pragma unroll
  for (int rr = 0; rr < 4; ++rr) {
    int r = ty + (rr << 3);
    t[r][tx] = W[(size_t)(k0 + r) * DMODEL + n0 + tx];
  }
  __syncthreads();
#pragma unroll
  for (int rr = 0; rr < 4; ++rr) {
    int r = ty + (rr << 3);
    Wt[(size_t)(n0 + r) * DMODEL + k0 + tx] = f2bs(t[tx][r]);
  }
}

// ---------------- MFMA GEMM core 128x128, BK=64, dbuf + counted vmcnt ----------------
template <bool OUTBF>
__device__ __forceinline__ void gemm_core128(const short* __restrict__ A,
                                             const short* __restrict__ Bt,
                                             const float* __restrict__ bias,
                                             void* __restrict__ C, int bm, int bn) {
  __shared__ short As[2][128 * 64];
  __shared__ short Bs[2][128 * 64];
  int tid = threadIdx.x;
  int lane = tid & 63, wid = tid >> 6;
  int wr = wid >> 1, wc = wid & 1;
  int cl = lane & 15, rq = lane >> 4;
  f32x4 acc[4][4];
#pragma unroll
  for (int m = 0; m < 4; ++m)
#pragma unroll
    for (int n = 0; n < 4; ++n) acc[m][n] = f32x4{0.f, 0.f, 0.f, 0.f};

  auto stage = [&](int buf, int k0) {
#pragma unroll
    for (int i = 0; i < 4; ++i) {
      int e = tid * 8 + i * 2048;
      int row = e >> 6;
      int k = (e & 63) ^ ((row & 7) << 3);
      gload_lds16(A + (size_t)(bm + row) * DMODEL + k0 + k,
                  &As[buf][wid * 512 + i * 2048]);
    }
#pragma unroll
    for (int i = 0; i < 4; ++i) {
      int e = tid * 8 + i * 2048;
      int row = e >> 6;
      int k = (e & 63) ^ ((row & 7) << 3);
      gload_lds16(Bt + (size_t)(bn + row) * DMODEL + k0 + k,
                  &Bs[buf][wid * 512 + i * 2048]);
    }
  };

  stage(0, 0);  // 8 loads/thread in flight
#pragma unroll 2
  for (int t = 0; t < 16; ++t) {
    int cur = t & 1;
    if (t < 15) {
      stage(cur ^ 1, (t + 1) * 64);  // 16 in flight
      asm volatile("s_waitcnt vmcnt(8)" ::: "memory");  // drain tile t, keep t+1
    } else {
      asm volatile("s_waitcnt vmcnt(0)" ::: "memory");
    }
    __builtin_amdgcn_s_barrier();
    asm volatile("" ::: "memory");
    const short* curA = &As[cur][0];
    const short* curB = &Bs[cur][0];
#pragma unroll
    for (int ks = 0; ks < 2; ++ks) {
      int kb = ks * 32 + (rq << 3);
      bf16x8 af[4], bfv[4];
#pragma unroll
      for (int mf = 0; mf < 4; ++mf) {
        int row = wr * 64 + mf * 16 + cl;
        af[mf] = *(const bf16x8*)&curA[row * 64 + (kb ^ ((row & 7) << 3))];
      }
#pragma unroll
      for (int nf = 0; nf < 4; ++nf) {
        int row = wc * 64 + nf * 16 + cl;
        bfv[nf] = *(const bf16x8*)&curB[row * 64 + (kb ^ ((row & 7) << 3))];
      }
#pragma unroll
      for (int mf = 0; mf < 4; ++mf)
#pragma unroll
        for (int nf = 0; nf < 4; ++nf)
          acc[mf][nf] = __builtin_amdgcn_mfma_f32_16x16x32_bf16(af[mf], bfv[nf],
                                                                acc[mf][nf], 0, 0, 0);
    }
    __builtin_amdgcn_s_barrier();  // frees buf cur for staging at t+1
    asm volatile("" ::: "memory");
  }
  int rbase = bm + wr * 64 + (rq << 2);
  int cbase = bn + wc * 64 + cl;
#pragma unroll
  for (int nf = 0; nf < 4; ++nf) {
    int col = cbase + nf * 16;
    float bv = bias[col];
#pragma unroll
    for (int mf = 0; mf < 4; ++mf)
#pragma unroll
      for (int r = 0; r < 4; ++r) {
        int row = rbase + mf * 16 + r;
        float v = acc[mf][nf][r] + bv;
        if (OUTBF)
          ((short*)C)[(size_t)row * DMODEL + col] = f2bs(v);
        else
          ((float*)C)[(size_t)row * DMODEL + col] = v;
      }
  }
}

// ---------------- MFMA GEMM core 128x64, BK=64, dbuf + counted vmcnt ----------------
template <bool OUTBF>
__device__ __forceinline__ void gemm_core64(const short* __restrict__ A,
                                            const short* __restrict__ Bt,
                                            const float* __restrict__ bias,
                                            void* __restrict__ C, int bm, int bn) {
  __shared__ short As[2][128 * 64];
  __shared__ short Bs[2][64 * 64];
  int tid = threadIdx.x;
  int lane = tid & 63, wid = tid >> 6;
  int wr = wid >> 1, wc = wid & 1;
  f32x4 acc[4][2];
#pragma unroll
  for (int m = 0; m < 4; ++m)
#pragma unroll
    for (int n = 0; n < 2; ++n) acc[m][n] = f32x4{0.f, 0.f, 0.f, 0.f};

  auto stage = [&](int buf, int k0) {
#pragma unroll
    for (int i = 0; i < 4; ++i) {
      int e = tid * 8 + i * 2048;
      int row = e >> 6;
      int k = (e & 63) ^ ((row & 7) << 3);
      gload_lds16(A + (size_t)(bm + row) * DMODEL + k0 + k,
                  &As[buf][wid * 512 + i * 2048]);
    }
#pragma unroll
    for (int i = 0; i < 2; ++i) {
      int e = tid * 8 + i * 2048;
      int row = e >> 6;
      int k = (e & 63) ^ ((row & 7) << 3);
      gload_lds16(Bt + (size_t)(bn + row) * DMODEL + k0 + k,
                  &Bs[buf][wid * 512 + i * 2048]);
    }
  };

  stage(0, 0);  // 6 loads/thread in flight
#pragma unroll 2
  for (int t = 0; t < 16; ++t) {
    int cur = t & 1;
    if (t < 15) {
      stage(cur ^ 1, (t + 1) * 64);  // 12 in flight
      asm volatile("s_waitcnt vmcnt(6)" ::: "memory");
    } else {
      asm volatile("s_waitcnt vmcnt(0)" ::: "memory");
    }
    __builtin_amdgcn_s_barrier();
    asm volatile("" ::: "memory");
    const short* curA = &As[cur][0];
    const short* curB = &Bs[cur][0];
#pragma unroll
    for (int ks = 0; ks < 2; ++ks) {
      int kb = ks * 32 + ((lane >> 4) << 3);
      bf16x8 af[4], bfv[2];
#pragma unroll
      for (int mf = 0; mf < 4; ++mf) {
        int row = wr * 64 + mf * 16 + (lane & 15);
        af[mf] = *(const bf16x8*)&curA[row * 64 + (kb ^ ((row & 7) << 3))];
      }
#pragma unroll
      for (int nf = 0; nf < 2; ++nf) {
        int row = wc * 32 + nf * 16 + (lane & 15);
        bfv[nf] = *(const bf16x8*)&curB[row * 64 + (kb ^ ((row & 7) << 3))];
      }
#pragma unroll
      for (int mf = 0; mf < 4; ++mf)
#pragma unroll
        for (int nf = 0; nf < 2; ++nf)
          acc[mf][nf] = __builtin_amdgcn_mfma_f32_16x16x32_bf16(af[mf], bfv[nf],
                                                                acc[mf][nf], 0, 0, 0);
    }
    __builtin_amdgcn_s_barrier();
    asm volatile("" ::: "memory");
  }
  int rbase = bm + wr * 64 + ((lane >> 4) << 2);
  int cbase = bn + wc * 32 + (lane & 15);
#pragma unroll
  for (int nf = 0; nf < 2; ++nf) {
    int col = cbase + nf * 16;
    float bv = bias[col];
#pragma unroll
    for (int mf = 0; mf < 4; ++mf)
#pragma unroll
      for (int r = 0; r < 4; ++r) {
        int row = rbase + mf * 16 + r;
        float v = acc[mf][nf][r] + bv;
        if (OUTBF)
          ((short*)C)[(size_t)row * DMODEL + col] = f2bs(v);
        else
          ((float*)C)[(size_t)row * DMODEL + col] = v;
      }
  }
}

// fused QKV projection: grid (8, 32, 3), 128x128 tile, XCD-swizzled
__global__ __launch_bounds__(256) void gemm_qkv3(
    const short* __restrict__ Abase, const short* __restrict__ WtBase,
    const float* __restrict__ bq, const float* __restrict__ bk,
    const float* __restrict__ bv, short* __restrict__ OutBase) {
  int z = blockIdx.z;
  const short* A = Abase + (size_t)z * NROWS * DMODEL;
  const short* Bt = WtBase + (size_t)z * DMODEL * DMODEL;
  const float* bias = (z == 0) ? bq : (z == 1) ? bk : bv;
  short* C = OutBase + (size_t)z * NROWS * DMODEL;
  int bid = blockIdx.x + (blockIdx.y << 3);
  int swz = ((bid & 7) << 5) + (bid >> 3);
  int bn = (swz & 7) << 7;
  int bm = (swz >> 3) << 7;
  gemm_core128<true>(A, Bt, bias, C, bm, bn);
}

// output projection: grid (16, 32), 128x64 tile, XCD-swizzled
__global__ __launch_bounds__(256) void gemm_out(const short* __restrict__ A,
                                                const short* __restrict__ Bt,
                                                const float* __restrict__ bias,
                                                float* __restrict__ C) {
  int bid = blockIdx.x + (blockIdx.y << 4);  // nwg=512
  int swz = ((bid & 7) << 6) + (bid >> 3);
  int bn = (swz & 15) << 6;
  int bm = (swz >> 4) << 7;
  gemm_core64<false>(A, Bt, bias, C, bm, bn);
}

// ---------------- h_k: 256 blocks x 256 thr; thread = one (row,head); 1 atomic/block ----------------
__global__ __launch_bounds__(256) void hk_kernel(const short* __restrict__ Kb,
                                                 float* __restrict__ hkbuf,
                                                 unsigned* __restrict__ kord) {
  int tid = threadIdx.x;
  int rloc = tid >> 4, h = tid & 15;
  int n = blockIdx.x * 16 + rloc;
  const short* p = Kb + (size_t)n * DMODEL + h * HD;
  float ss = 0.f;
#pragma unroll
  for (int g = 0; g < 8; ++g) {
    bf16x8 v = *(const bf16x8*)(p + g * 8);
#pragma unroll
    for (int e = 0; e < 8; ++e) {
      float x = bs2f(v[e]);
      ss += x * x;
    }
  }
  float hkv = -0.5f * SCAL2 * ss;
  int b = n >> 11, l = n & (SEQ - 1);
  hkbuf[((size_t)(b * NH + h)) * SEQ + l] = hkv;
  __shared__ float red[256];
  red[tid] = hkv;
  __syncthreads();
  for (int s = 128; s > 0; s >>= 1) {
    if (tid < s) red[tid] = fmaxf(red[tid], red[tid + s]);
    __syncthreads();
  }
  if (tid == 0) atomicMax(kord, f2ord(red[0]));
}

// ---------------- feature map via MFMA (fast-exp epilogue) ----------------
__global__ __launch_bounds__(256, 1) void featmap_mfma(
    const short* __restrict__ Qproj, const short* __restrict__ Kproj,
    const short* __restrict__ rfb, const float* __restrict__ hkbuf,
    const unsigned* __restrict__ kord, short* __restrict__ Qp,
    short* __restrict__ Kp) {
  __shared__ short smem[26624];  // A:8192 | B:18432 ; epilogue reuses as P[128][152]
  __shared__ float hks[128];
  short* As = smem;
  short* Bs = smem + 8192;
  int isK = blockIdx.z;
  const short* X = isK ? Kproj : Qproj;
  short* O = isK ? Kp : Qp;
  int bh = blockIdx.y, b = bh >> 4, h = bh & 15;
  int l0 = blockIdx.x << 7;
  int tid = threadIdx.x, lane = tid & 63, wid = tid >> 6;
  int cl = lane & 15, rq = lane >> 4;

#pragma unroll
  for (int i = 0; i < 4; ++i) {
    int e = tid * 8 + i * 2048;
    int row = e >> 6;
    int k = (e & 63) ^ ((row & 7) << 3);
    gload_lds16(X + ((size_t)b * SEQ + l0 + row) * DMODEL + h * HD + k,
                &As[wid * 512 + i * 2048]);
  }
#pragma unroll
  for (int i = 0; i < 9; ++i) {
    int e = tid * 8 + i * 2048;
    int row = e >> 6;
    int k = (e & 63) ^ ((row & 7) << 3);
    gload_lds16(rfb + row * HD + k, &Bs[wid * 512 + i * 2048]);
  }
  if (isK) {
    float ksv = ord2f(*kord);
    if (tid < 128)
      hks[tid] = hkbuf[(size_t)bh * SEQ + l0 + tid] - ksv + LN_CNORM;
  }
  __syncthreads();

  int i0 = wid * 32;
  f32x4 acc[2][18];
#pragma unroll
  for (int m = 0; m < 2; ++m)
#pragma unroll
    for (int n = 0; n < 18; ++n) acc[m][n] = f32x4{0.f, 0.f, 0.f, 0.f};
#pragma unroll
  for (int ks = 0; ks < 2; ++ks) {
    int kb = ks * 32 + (rq << 3);
    int swz = (cl & 7) << 3;
    bf16x8 af[2];
#pragma unroll
    for (int mf = 0; mf < 2; ++mf) {
      int row = i0 + mf * 16 + cl;
      af[mf] = *(const bf16x8*)&As[row * 64 + (kb ^ swz)];
    }
#pragma unroll
    for (int nf = 0; nf < 18; ++nf) {
      int brow = nf * 16 + cl;
      bf16x8 bv = *(const bf16x8*)&Bs[brow * 64 + (kb ^ swz)];
#pragma unroll
      for (int mf = 0; mf < 2; ++mf)
        acc[mf][nf] = __builtin_amdgcn_mfma_f32_16x16x32_bf16(af[mf], bv,
                                                              acc[mf][nf], 0, 0, 0);
    }
  }

  short* Ps = smem;  // [128][152]
#pragma unroll
  for (int hf = 0; hf < 2; ++hf) {
    __syncthreads();
#pragma unroll
    for (int mf = 0; mf < 2; ++mf)
#pragma unroll
      for (int r = 0; r < 4; ++r) {
        int rl = i0 + mf * 16 + (rq << 2) + r;
        float addk = isK ? hks[rl] : LN_CNORM;
#pragma unroll
        for (int nf2 = 0; nf2 < 9; ++nf2) {
          int m = hf * 144 + nf2 * 16 + cl;
          float v = acc[mf][hf * 9 + nf2][r] + addk;
          float o = (m < NRF) ? (__expf(v) + CKEPS) : 0.f;
          Ps[rl * 152 + nf2 * 16 + cl] = f2bs(o);
        }
      }
    __syncthreads();
#pragma unroll
    for (int it = 0; it < 9; ++it) {
      int idx = tid + it * 256;
      int row = idx / 18, ch = idx - row * 18;
      bf16x8 val = *(const bf16x8*)&Ps[row * 152 + ch * 8];
      *(bf16x8*)&O[((size_t)bh * SEQ + l0 + row) * NRFP + hf * 144 + ch * 8] = val;
    }
  }
}

// ---------------- per-chunk sums via MFMA ----------------
__global__ __launch_bounds__(256) void chunksum_mfma(
    const short* __restrict__ Kp, const short* __restrict__ Vb,
    short* __restrict__ Schunk, float* __restrict__ ksum) {
  constexpr int ST = 70;
  __shared__ short KT[NRFP * ST];  // [m][i_loc]
  __shared__ short VT[HD * ST];    // [d][i_loc]
  int c = blockIdx.x, bh = blockIdx.y;
  int b = bh >> 4, h = bh & 15;
  int tid = threadIdx.x, lane = tid & 63, wv = tid >> 6;
  int cl = lane & 15, rq = lane >> 4;
  int irow = tid >> 2;
  int mq = tid & 3;
  size_t rowb = (size_t)bh * SEQ + (size_t)c * CHK;

  f32x4 acc[18];
#pragma unroll
  for (int m = 0; m < 18; ++m) acc[m] = f32x4{0.f, 0.f, 0.f, 0.f};
  float k1 = 0.f, k2 = 0.f;

  for (int hf = 0; hf < 2; ++hf) {
    __syncthreads();
    const short* Krow = Kp + (rowb + hf * 64 + irow) * NRFP;
#pragma unroll
    for (int cg = 0; cg < 9; ++cg) {
      int m0 = cg * 32 + mq * 8;
      bf16x8 v = *(const bf16x8*)(Krow + m0);
#pragma unroll
      for (int e = 0; e < 8; ++e) KT[(m0 + e) * ST + irow] = v[e];
    }
    const short* Vrow =
        Vb + ((size_t)b * SEQ + (size_t)c * CHK + hf * 64 + irow) * DMODEL + h * HD;
    {
      int d0 = mq * 16;
      bf16x8 v0 = *(const bf16x8*)(Vrow + d0);
      bf16x8 v1 = *(const bf16x8*)(Vrow + d0 + 8);
#pragma unroll
      for (int e = 0; e < 8; ++e) VT[(d0 + e) * ST + irow] = v0[e];
#pragma unroll
      for (int e = 0; e < 8; ++e) VT[(d0 + 8 + e) * ST + irow] = v1[e];
    }
    __syncthreads();
#pragma unroll
    for (int ks = 0; ks < 2; ++ks) {
      int kb = ks * 32 + rq * 8;
      bf16x8 bv = *(const bf16x8*)&VT[(wv * 16 + cl) * ST + kb];
#pragma unroll
      for (int mf = 0; mf < 18; ++mf) {
        bf16x8 av = *(const bf16x8*)&KT[(mf * 16 + cl) * ST + kb];
        acc[mf] = __builtin_amdgcn_mfma_f32_16x16x32_bf16(av, bv, acc[mf], 0, 0, 0);
      }
    }
    {
      const short* r1 = &KT[tid * ST];
#pragma unroll
      for (int g = 0; g < 8; ++g) {
        bf16x8 v = *(const bf16x8*)(r1 + g * 8);
#pragma unroll
        for (int e = 0; e < 8; ++e) k1 += bs2f(v[e]);
      }
      if (tid < 10) {
        const short* r2 = &KT[(256 + tid) * ST];
#pragma unroll
        for (int g = 0; g < 8; ++g) {
          bf16x8 v = *(const bf16x8*)(r2 + g * 8);
#pragma unroll
          for (int e = 0; e < 8; ++e) k2 += bs2f(v[e]);
        }
      }
    }
  }
  size_t sbase = ((size_t)bh * NCH + c) * (size_t)(NRFP * HD);
  size_t kbase = ((size_t)bh * NCH + c) * (size_t)NRF;
#pragma unroll
  for (int mf = 0; mf < 18; ++mf)
#pragma unroll
    for (int r = 0; r < 4; ++r) {
      int m = mf * 16 + rq * 4 + r;
      Schunk[sbase + (size_t)m * HD + wv * 16 + cl] = f2bs(acc[mf][r]);
    }
  if (tid < NRF) ksum[kbase + tid] = k1;
  if (tid < 10) ksum[kbase + 256 + tid] = k2;
}

// ---------------- fused exclusive prefixes: S (x<72) and ksum (x==72) ----------------
__global__ __launch_bounds__(256) void prefix_all(const short* __restrict__ Sc,
                                                  short* __restrict__ Sp,
                                                  float* __restrict__ ksum) {
  int bh = blockIdx.y;
  if (blockIdx.x == 72) {
    for (int m = threadIdx.x; m < NRF; m += 256) {
      size_t base = (size_t)bh * NCH * NRF + m;
      float a = 0.f;
#pragma unroll
      for (int c = 0; c < NCH; ++c) {
        size_t idx = base + (size_t)c * NRF;
        float v = ksum[idx];
        ksum[idx] = a;
        a += v;
      }
    }
    return;
  }
  int e = blockIdx.x * 256 + threadIdx.x;
  size_t base = (size_t)bh * NCH * (NRFP * HD) + e;
  float a = 0.f;
#pragma unroll
  for (int c = 0; c < NCH; ++c) {
    size_t idx = base + (size_t)c * (NRFP * HD);
    float v = bs2f(Sc[idx]);
    Sp[idx] = f2bs(a);
    a += v;
  }
}

// ---------------- FUSED inter+intra ----------------
__global__ __launch_bounds__(256) void attn_mfma(
    const short* __restrict__ Qp, const short* __restrict__ Kp,
    const short* __restrict__ Vb, const short* __restrict__ Sp,
    const float* __restrict__ ksum, short* __restrict__ ctxb) {
  constexpr int PST = 136;
  constexpr int BST = 290;
  __shared__ short Vt[64 * PST];
  __shared__ short BsPl[64 * BST];
  __shared__ float ks[272];
  __shared__ float den[128];
  int c = blockIdx.x, bh = blockIdx.y;
  int b = bh >> 4, h = bh & 15;
  int tid = threadIdx.x, lane = tid & 63, wid = tid >> 6;
  int cl = lane & 15, rq = lane >> 4;
  size_t rowb = (size_t)bh * SEQ + (size_t)c * CHK;

  {
    int jj = tid >> 3, d0 = (tid & 7) << 3;
#pragma unroll
    for (int jt = 0; jt < 4; ++jt) {
      int j = jj + jt * 32;
      bf16x8 v = *(const bf16x8*)(Vb + ((size_t)b * SEQ + (size_t)c * CHK + j) * DMODEL +
                                  h * HD + d0);
#pragma unroll
      for (int e = 0; e < 8; ++e) Vt[(d0 + e) * PST + j] = v[e];
    }
  }
  const short* Spb = Sp + ((size_t)bh * NCH + c) * (size_t)(NRFP * HD);
  for (int idx = tid; idx < NRFP * HD; idx += 256) {
    int m = idx >> 6, d = idx & 63;
    BsPl[d * BST + m] = Spb[idx];
  }
  const float* ksb = ksum + ((size_t)bh * NCH + c) * (size_t)NRF;
  for (int idx = tid; idx < NRF; idx += 256) ks[idx] = ksb[idx];
  __syncthreads();

  int i0 = wid * 32;
  const short* Arow = Qp + (rowb + i0) * NRFP;
  const short* Krow = Kp + rowb * NRFP;
  f32x4 accI[2][4];
  f32x4 accP[2][8];
#pragma unroll
  for (int m = 0; m < 2; ++m) {
#pragma unroll
    for (int n = 0; n < 4; ++n) accI[m][n] = f32x4{0.f, 0.f, 0.f, 0.f};
#pragma unroll
    for (int n = 0; n < 8; ++n) accP[m][n] = f32x4{0.f, 0.f, 0.f, 0.f};
  }
#pragma unroll
  for (int k9 = 0; k9 < 9; ++k9) {
    int kb = k9 * 32 + (rq << 3);
    bf16x8 af[2];
#pragma unroll
    for (int mf = 0; mf < 2; ++mf)
      af[mf] = *(const bf16x8*)(Arow + (size_t)(mf * 16 + cl) * NRFP + kb);
#pragma unroll
    for (int nf = 0; nf < 4; ++nf) {
      bf16x8 bv = *(const bf16x8*)&BsPl[(nf * 16 + cl) * BST + kb];
#pragma unroll
      for (int mf = 0; mf < 2; ++mf)
        accI[mf][nf] = __builtin_amdgcn_mfma_f32_16x16x32_bf16(af[mf], bv,
                                                               accI[mf][nf], 0, 0, 0);
    }
#pragma unroll
    for (int nf = 0; nf < 8; ++nf) {
      bf16x8 bv = *(const bf16x8*)(Krow + (size_t)(nf * 16 + cl) * NRFP + kb);
#pragma unroll
      for (int mf = 0; mf < 2; ++mf)
        accP[mf][nf] = __builtin_amdgcn_mfma_f32_16x16x32_bf16(af[mf], bv,
                                                               accP[mf][nf], 0, 0, 0);
    }
  }
  {
    int r = tid >> 1, half = tid & 1;
    const short* qr = Qp + (rowb + r) * NRFP;
    float s = 0.f;
    int m0 = half * 133;
    for (int m = m0; m < m0 + 133; ++m) s += bs2f(qr[m]) * ks[m];
    s += __shfl_xor(s, 1);
    if (!half) den[r] = s;
  }
  __syncthreads();

#pragma unroll
  for (int mf = 0; mf < 2; ++mf)
#pragma unroll
    for (int r = 0; r < 4; ++r) {
      int rl = mf * 16 + (rq << 2) + r;
      int row = i0 + rl;
      float dsum = 0.f;
#pragma unroll
      for (int nf = 0; nf < 8; ++nf) {
        int col = nf * 16 + cl;
        float v = (col > row) ? 0.f : accP[mf][nf][r];
        dsum += v;
        BsPl[wid * 32 * PST + rl * PST + col] = f2bs(v);
      }
      dsum += __shfl_xor(dsum, 1);
      dsum += __shfl_xor(dsum, 2);
      dsum += __shfl_xor(dsum, 4);
      dsum += __shfl_xor(dsum, 8);
      if (cl == 0) den[row] += dsum;
    }
  __syncthreads();

  f32x4 pacc[2][4];
#pragma unroll
  for (int m = 0; m < 2; ++m)
#pragma unroll
    for (int n = 0; n < 4; ++n) pacc[m][n] = f32x4{0.f, 0.f, 0.f, 0.f};
#pragma unroll
  for (int kk = 0; kk < 4; ++kk) {
    int kb = kk * 32 + (rq << 3);
    bf16x8 paf[2];
#pragma unroll
    for (int mf = 0; mf < 2; ++mf)
      paf[mf] = *(const bf16x8*)&BsPl[wid * 32 * PST + (mf * 16 + cl) * PST + kb];
#pragma unroll
    for (int nf = 0; nf < 4; ++nf) {
      bf16x8 bv = *(const bf16x8*)&Vt[(nf * 16 + cl) * PST + kb];
#pragma unroll
      for (int mf = 0; mf < 2; ++mf)
        pacc[mf][nf] = __builtin_amdgcn_mfma_f32_16x16x32_bf16(paf[mf], bv,
                                                               pacc[mf][nf], 0, 0, 0);
    }
  }
#pragma unroll
  for (int mf = 0; mf < 2; ++mf)
#pragma unroll
    for (int r = 0; r < 4; ++r) {
      int row = i0 + mf * 16 + (rq << 2) + r;
      float inv = 1.0f / den[row];
      size_t ob = ((size_t)b * SEQ + (size_t)c * CHK + row) * DMODEL + h * HD;
#pragma unroll
      for (int nf = 0; nf < 4; ++nf) {
        int d = nf * 16 + cl;
        float v = (accI[mf][nf][r] + pacc[mf][nf][r]) * inv;
        ctxb[ob + d] = f2bs(v);
      }
    }
}

// ---------------- launch ----------------
extern "C" void kernel_launch(void* const* d_in, const int* in_sizes, int n_in,
                              void* d_out, int out_size, void* d_ws, size_t ws_size,
                              hipStream_t stream) {
  (void)in_sizes; (void)n_in; (void)out_size;
  const float* query = (const float*)d_in[0];
  const float* key_  = (const float*)d_in[1];
  const float* value = (const float*)d_in[2];
  const float* Wq = (const float*)d_in[3];
  const float* bq = (const float*)d_in[4];
  const float* Wk = (const float*)d_in[5];
  const float* bk = (const float*)d_in[6];
  const float* Wv = (const float*)d_in[7];
  const float* bv = (const float*)d_in[8];
  const float* Wo = (const float*)d_in[9];
  const float* bo = (const float*)d_in[10];
  const float* rf = (const float*)d_in[11];

  constexpr size_t SZ_INBF = (size_t)NROWS * DMODEL * 2;
  constexpr size_t SZ_QP   = (size_t)NBH * SEQ * NRFP * 2;
  constexpr size_t SZ_WT   = (size_t)DMODEL * DMODEL * 2;
  constexpr size_t SZ_SCH  = (size_t)NBH * NCH * NRFP * HD * 2;
  constexpr size_t SZ_KS   = (size_t)NBH * NCH * NRF * 4;
  constexpr size_t SZ_HK   = (size_t)NBH * SEQ * 4;
  constexpr size_t SZ_RFB  = (size_t)NRFP * HD * 2;

  constexpr size_t O_QP   = 0;
  constexpr size_t O_KP   = O_QP + SZ_QP;
  constexpr size_t O_WT   = O_KP + SZ_QP;
  constexpr size_t O_QPR  = O_WT + 4 * SZ_WT;
  constexpr size_t O_SCH  = O_QPR + 3 * SZ_INBF;
  constexpr size_t O_SPR  = O_SCH + SZ_SCH;
  constexpr size_t O_KSUM = O_SPR + SZ_SCH;
  constexpr size_t O_HK   = O_KSUM + SZ_KS;
  constexpr size_t O_KST  = O_HK + SZ_HK;
  constexpr size_t O_CTXB = O_KST + 256;
  constexpr size_t O_RFB  = O_CTXB + SZ_INBF;
  constexpr size_t O_END  = O_RFB + SZ_RFB;
  if (ws_size < O_END) return;

  char* w = (char*)d_ws;
  short* Qbf  = (short*)(w + O_QP);
  short* Qp   = (short*)(w + O_QP);
  short* Kp   = (short*)(w + O_KP);
  short* WtB  = (short*)(w + O_WT);
  short* QprB = (short*)(w + O_QPR);
  short* Kpr  = (short*)(w + O_QPR + SZ_INBF);
  short* Vpr  = (short*)(w + O_QPR + 2 * SZ_INBF);
  short* Sch  = (short*)(w + O_SCH);
  short* Spr  = (short*)(w + O_SPR);
  float* ksum = (float*)(w + O_KSUM);
  float* hkbuf = (float*)(w + O_HK);
  unsigned* kord = (unsigned*)(w + O_KST);
  short* ctxb = (short*)(w + O_CTXB);
  short* rfb  = (short*)(w + O_RFB);

  constexpr int NEL = NROWS * DMODEL;
  cvt3_kernel<<<dim3(NEL / 2048, 3), 256, 0, stream>>>(query, key_, value, Qbf);
  transpose4_bf16<<<dim3(32, 32, 4), 256, 0, stream>>>(Wq, Wk, Wv, Wo, WtB);
  rf_pad_bf16<<<(NRFP * HD) / 256, 256, 0, stream>>>(rf, rfb, kord);
  gemm_qkv3<<<dim3(8, 32, 3), 256, 0, stream>>>(Qbf, WtB, bq, bk, bv, QprB);
  hk_kernel<<<256, 256, 0, stream>>>(Kpr, hkbuf, kord);
  featmap_mfma<<<dim3(SEQ / 128, NBH, 2), 256, 0, stream>>>(QprB, Kpr, rfb, hkbuf,
                                                            kord, Qp, Kp);
  chunksum_mfma<<<dim3(NCH, NBH), 256, 0, stream>>>(Kp, Vpr, Sch, ksum);
  prefix_all<<<dim3(73, NBH), 256, 0, stream>>>(Sch, Spr, ksum);
  attn_mfma<<<dim3(NCH, NBH), 256, 0, stream>>>(Qp, Kp, Vpr, Spr, ksum, ctxb);
  gemm_out<<<dim3(16, 32), 256, 0, stream>>>(ctxb, WtB + 3 * (size_t)DMODEL * DMODEL,
                                             bo, (float*)d_out);
}

// Round 13
// 184.060 us; speedup vs baseline: 1.3384x; 1.0033x over previous
//
#include <hip/hip_runtime.h>
#include <hip/hip_bf16.h>

#define BATCH 2
#define SEQ 2048
#define DMODEL 1024
#define NH 16
#define HD 64
#define NRF 266
#define NRFP 288   // padded feature dim (multiple of 32), cols [266,288) are zero
#define SROW 320   // transposed-S row stride: 5 full 64-blocks so XOR swizzle is closed
#define CHK 128
#define NCH 16
#define NBH 32
#define NROWS 4096  // BATCH*SEQ

constexpr float SCAL = 0.17677669529663687f;   // DMODEL^-0.25
constexpr float SCAL2 = 0.03125f;              // SCAL^2 = DMODEL^-0.5
constexpr float LN_CNORM = -2.7917480361965505f;   // ln(1/sqrt(266))
constexpr float CKEPS = 6.131393094576169e-6f;     // CNORM*KEPS

typedef short bf16x8 __attribute__((ext_vector_type(8)));
typedef float f32x4 __attribute__((ext_vector_type(4)));

__device__ __forceinline__ short f2bs(float v) {
  __hip_bfloat16 h = __float2bfloat16(v);
  return *reinterpret_cast<short*>(&h);
}
__device__ __forceinline__ float bs2f(short s) {
  __hip_bfloat16 h;
  *reinterpret_cast<short*>(&h) = s;
  return __bfloat162float(h);
}
__device__ __forceinline__ void gload_lds16(const void* g, void* l) {
  __builtin_amdgcn_global_load_lds(
      (const __attribute__((address_space(1))) void*)g,
      (__attribute__((address_space(3))) void*)l, 16, 0, 0);
}
// monotone float<->uint order encoding (for atomicMax over floats)
__device__ __forceinline__ unsigned f2ord(float f) {
  unsigned u = __float_as_uint(f);
  return (u & 0x80000000u) ? ~u : (u | 0x80000000u);
}
__device__ __forceinline__ float ord2f(unsigned e) {
  return (e & 0x80000000u) ? __uint_as_float(e & 0x7fffffffu)
                           : __uint_as_float(~e);
}

// ---------------- fused f32 -> bf16 convert for q,k,v ----------------
__global__ __launch_bounds__(256) void cvt3_kernel(const float* __restrict__ q,
                                                   const float* __restrict__ k,
                                                   const float* __restrict__ v,
                                                   short* __restrict__ out) {
  int z = blockIdx.y;
  const float* x = (z == 0) ? q : (z == 1) ? k : v;
  short* y = out + (size_t)z * NROWS * DMODEL;
  int i = (blockIdx.x * 256 + threadIdx.x) * 8;
  float4 a = *(const float4*)&x[i];
  float4 b = *(const float4*)&x[i + 4];
  bf16x8 o;
  o[0] = f2bs(a.x); o[1] = f2bs(a.y); o[2] = f2bs(a.z); o[3] = f2bs(a.w);
  o[4] = f2bs(b.x); o[5] = f2bs(b.y); o[6] = f2bs(b.z); o[7] = f2bs(b.w);
  *(bf16x8*)&y[i] = o;
}

// ---------------- rf pad + SCAL fold; also zero the kstab atomic slot ----------------
__global__ __launch_bounds__(256) void rf_pad_bf16(const float* __restrict__ rf,
                                                   short* __restrict__ rfb,
                                                   unsigned* __restrict__ kord) {
  int idx = blockIdx.x * 256 + threadIdx.x;  // grid 72*256 = 18432 exact
  rfb[idx] = (idx < NRF * HD) ? f2bs(rf[idx] * SCAL) : (short)0;
  if (idx == 0) *kord = 0u;
}

// ---------------- fused W transposes: W[K][N] f32 -> Wt[N][K] bf16, 4 weights ----------------
__global__ __launch_bounds__(256) void transpose4_bf16(
    const float* __restrict__ Wq, const float* __restrict__ Wk,
    const float* __restrict__ Wv, const float* __restrict__ Wo,
    short* __restrict__ WtBase) {
  __shared__ float t[32][33];
  int z = blockIdx.z;
  const float* W = (z == 0) ? Wq : (z == 1) ? Wk : (z == 2) ? Wv : Wo;
  short* Wt = WtBase + (size_t)z * DMODEL * DMODEL;
  int k0 = blockIdx.y << 5, n0 = blockIdx.x << 5;
  int tx = threadIdx.x & 31, ty = threadIdx.x >> 5;
#pragma unroll
  for (int rr = 0; rr < 4; ++rr) {
    int r = ty + (rr << 3);
    t[r][tx] = W[(size_t)(k0 + r) * DMODEL + n0 + tx];
  }
  __syncthreads();
#pragma unroll
  for (int rr = 0; rr < 4; ++rr) {
    int r = ty + (rr << 3);
    Wt[(size_t)(n0 + r) * DMODEL + k0 + tx] = f2bs(t[tx][r]);
  }
}

// ---------------- MFMA GEMM core 128x128, BK=64, dbuf + counted vmcnt ----------------
template <bool OUTBF>
__device__ __forceinline__ void gemm_core128(const short* __restrict__ A,
                                             const short* __restrict__ Bt,
                                             const float* __restrict__ bias,
                                             void* __restrict__ C, int bm, int bn) {
  __shared__ short As[2][128 * 64];
  __shared__ short Bs[2][128 * 64];
  int tid = threadIdx.x;
  int lane = tid & 63, wid = tid >> 6;
  int wr = wid >> 1, wc = wid & 1;
  int cl = lane & 15, rq = lane >> 4;
  f32x4 acc[4][4];
#pragma unroll
  for (int m = 0; m < 4; ++m)
#pragma unroll
    for (int n = 0; n < 4; ++n) acc[m][n] = f32x4{0.f, 0.f, 0.f, 0.f};

  auto stage = [&](int buf, int k0) {
#pragma unroll
    for (int i = 0; i < 4; ++i) {
      int e = tid * 8 + i * 2048;
      int row = e >> 6;
      int k = (e & 63) ^ ((row & 7) << 3);
      gload_lds16(A + (size_t)(bm + row) * DMODEL + k0 + k,
                  &As[buf][wid * 512 + i * 2048]);
    }
#pragma unroll
    for (int i = 0; i < 4; ++i) {
      int e = tid * 8 + i * 2048;
      int row = e >> 6;
      int k = (e & 63) ^ ((row & 7) << 3);
      gload_lds16(Bt + (size_t)(bn + row) * DMODEL + k0 + k,
                  &Bs[buf][wid * 512 + i * 2048]);
    }
  };

  stage(0, 0);
#pragma unroll 2
  for (int t = 0; t < 16; ++t) {
    int cur = t & 1;
    if (t < 15) {
      stage(cur ^ 1, (t + 1) * 64);
      asm volatile("s_waitcnt vmcnt(8)" ::: "memory");
    } else {
      asm volatile("s_waitcnt vmcnt(0)" ::: "memory");
    }
    __builtin_amdgcn_s_barrier();
    asm volatile("" ::: "memory");
    const short* curA = &As[cur][0];
    const short* curB = &Bs[cur][0];
#pragma unroll
    for (int ks = 0; ks < 2; ++ks) {
      int kb = ks * 32 + (rq << 3);
      bf16x8 af[4], bfv[4];
#pragma unroll
      for (int mf = 0; mf < 4; ++mf) {
        int row = wr * 64 + mf * 16 + cl;
        af[mf] = *(const bf16x8*)&curA[row * 64 + (kb ^ ((row & 7) << 3))];
      }
#pragma unroll
      for (int nf = 0; nf < 4; ++nf) {
        int row = wc * 64 + nf * 16 + cl;
        bfv[nf] = *(const bf16x8*)&curB[row * 64 + (kb ^ ((row & 7) << 3))];
      }
#pragma unroll
      for (int mf = 0; mf < 4; ++mf)
#pragma unroll
        for (int nf = 0; nf < 4; ++nf)
          acc[mf][nf] = __builtin_amdgcn_mfma_f32_16x16x32_bf16(af[mf], bfv[nf],
                                                                acc[mf][nf], 0, 0, 0);
    }
    __builtin_amdgcn_s_barrier();
    asm volatile("" ::: "memory");
  }
  int rbase = bm + wr * 64 + (rq << 2);
  int cbase = bn + wc * 64 + cl;
#pragma unroll
  for (int nf = 0; nf < 4; ++nf) {
    int col = cbase + nf * 16;
    float bv = bias[col];
#pragma unroll
    for (int mf = 0; mf < 4; ++mf)
#pragma unroll
      for (int r = 0; r < 4; ++r) {
        int row = rbase + mf * 16 + r;
        float v = acc[mf][nf][r] + bv;
        if (OUTBF)
          ((short*)C)[(size_t)row * DMODEL + col] = f2bs(v);
        else
          ((float*)C)[(size_t)row * DMODEL + col] = v;
      }
  }
}

// ---------------- MFMA GEMM core 128x64, BK=64, dbuf + counted vmcnt ----------------
template <bool OUTBF>
__device__ __forceinline__ void gemm_core64(const short* __restrict__ A,
                                            const short* __restrict__ Bt,
                                            const float* __restrict__ bias,
                                            void* __restrict__ C, int bm, int bn) {
  __shared__ short As[2][128 * 64];
  __shared__ short Bs[2][64 * 64];
  int tid = threadIdx.x;
  int lane = tid & 63, wid = tid >> 6;
  int wr = wid >> 1, wc = wid & 1;
  f32x4 acc[4][2];
#pragma unroll
  for (int m = 0; m < 4; ++m)
#pragma unroll
    for (int n = 0; n < 2; ++n) acc[m][n] = f32x4{0.f, 0.f, 0.f, 0.f};

  auto stage = [&](int buf, int k0) {
#pragma unroll
    for (int i = 0; i < 4; ++i) {
      int e = tid * 8 + i * 2048;
      int row = e >> 6;
      int k = (e & 63) ^ ((row & 7) << 3);
      gload_lds16(A + (size_t)(bm + row) * DMODEL + k0 + k,
                  &As[buf][wid * 512 + i * 2048]);
    }
#pragma unroll
    for (int i = 0; i < 2; ++i) {
      int e = tid * 8 + i * 2048;
      int row = e >> 6;
      int k = (e & 63) ^ ((row & 7) << 3);
      gload_lds16(Bt + (size_t)(bn + row) * DMODEL + k0 + k,
                  &Bs[buf][wid * 512 + i * 2048]);
    }
  };

  stage(0, 0);
#pragma unroll 2
  for (int t = 0; t < 16; ++t) {
    int cur = t & 1;
    if (t < 15) {
      stage(cur ^ 1, (t + 1) * 64);
      asm volatile("s_waitcnt vmcnt(6)" ::: "memory");
    } else {
      asm volatile("s_waitcnt vmcnt(0)" ::: "memory");
    }
    __builtin_amdgcn_s_barrier();
    asm volatile("" ::: "memory");
    const short* curA = &As[cur][0];
    const short* curB = &Bs[cur][0];
#pragma unroll
    for (int ks = 0; ks < 2; ++ks) {
      int kb = ks * 32 + ((lane >> 4) << 3);
      bf16x8 af[4], bfv[2];
#pragma unroll
      for (int mf = 0; mf < 4; ++mf) {
        int row = wr * 64 + mf * 16 + (lane & 15);
        af[mf] = *(const bf16x8*)&curA[row * 64 + (kb ^ ((row & 7) << 3))];
      }
#pragma unroll
      for (int nf = 0; nf < 2; ++nf) {
        int row = wc * 32 + nf * 16 + (lane & 15);
        bfv[nf] = *(const bf16x8*)&curB[row * 64 + (kb ^ ((row & 7) << 3))];
      }
#pragma unroll
      for (int mf = 0; mf < 4; ++mf)
#pragma unroll
        for (int nf = 0; nf < 2; ++nf)
          acc[mf][nf] = __builtin_amdgcn_mfma_f32_16x16x32_bf16(af[mf], bfv[nf],
                                                                acc[mf][nf], 0, 0, 0);
    }
    __builtin_amdgcn_s_barrier();
    asm volatile("" ::: "memory");
  }
  int rbase = bm + wr * 64 + ((lane >> 4) << 2);
  int cbase = bn + wc * 32 + (lane & 15);
#pragma unroll
  for (int nf = 0; nf < 2; ++nf) {
    int col = cbase + nf * 16;
    float bv = bias[col];
#pragma unroll
    for (int mf = 0; mf < 4; ++mf)
#pragma unroll
      for (int r = 0; r < 4; ++r) {
        int row = rbase + mf * 16 + r;
        float v = acc[mf][nf][r] + bv;
        if (OUTBF)
          ((short*)C)[(size_t)row * DMODEL + col] = f2bs(v);
        else
          ((float*)C)[(size_t)row * DMODEL + col] = v;
      }
  }
}

// fused QKV projection: grid (8, 32, 3), 128x128 tile, XCD-swizzled
__global__ __launch_bounds__(256) void gemm_qkv3(
    const short* __restrict__ Abase, const short* __restrict__ WtBase,
    const float* __restrict__ bq, const float* __restrict__ bk,
    const float* __restrict__ bv, short* __restrict__ OutBase) {
  int z = blockIdx.z;
  const short* A = Abase + (size_t)z * NROWS * DMODEL;
  const short* Bt = WtBase + (size_t)z * DMODEL * DMODEL;
  const float* bias = (z == 0) ? bq : (z == 1) ? bk : bv;
  short* C = OutBase + (size_t)z * NROWS * DMODEL;
  int bid = blockIdx.x + (blockIdx.y << 3);
  int swz = ((bid & 7) << 5) + (bid >> 3);
  int bn = (swz & 7) << 7;
  int bm = (swz >> 3) << 7;
  gemm_core128<true>(A, Bt, bias, C, bm, bn);
}

// output projection: grid (16, 32), 128x64 tile, XCD-swizzled
__global__ __launch_bounds__(256) void gemm_out(const short* __restrict__ A,
                                                const short* __restrict__ Bt,
                                                const float* __restrict__ bias,
                                                float* __restrict__ C) {
  int bid = blockIdx.x + (blockIdx.y << 4);  // nwg=512
  int swz = ((bid & 7) << 6) + (bid >> 3);
  int bn = (swz & 15) << 6;
  int bm = (swz >> 4) << 7;
  gemm_core64<false>(A, Bt, bias, C, bm, bn);
}

// ---------------- h_k: 256 blocks x 256 thr; thread = one (row,head); 1 atomic/block ----------------
__global__ __launch_bounds__(256) void hk_kernel(const short* __restrict__ Kb,
                                                 float* __restrict__ hkbuf,
                                                 unsigned* __restrict__ kord) {
  int tid = threadIdx.x;
  int rloc = tid >> 4, h = tid & 15;
  int n = blockIdx.x * 16 + rloc;
  const short* p = Kb + (size_t)n * DMODEL + h * HD;
  float ss = 0.f;
#pragma unroll
  for (int g = 0; g < 8; ++g) {
    bf16x8 v = *(const bf16x8*)(p + g * 8);
#pragma unroll
    for (int e = 0; e < 8; ++e) {
      float x = bs2f(v[e]);
      ss += x * x;
    }
  }
  float hkv = -0.5f * SCAL2 * ss;
  int b = n >> 11, l = n & (SEQ - 1);
  hkbuf[((size_t)(b * NH + h)) * SEQ + l] = hkv;
  __shared__ float red[256];
  red[tid] = hkv;
  __syncthreads();
  for (int s = 128; s > 0; s >>= 1) {
    if (tid < s) red[tid] = fmaxf(red[tid], red[tid + s]);
    __syncthreads();
  }
  if (tid == 0) atomicMax(kord, f2ord(red[0]));
}

// ---------------- feature map via MFMA (fast-exp epilogue) ----------------
__global__ __launch_bounds__(256, 1) void featmap_mfma(
    const short* __restrict__ Qproj, const short* __restrict__ Kproj,
    const short* __restrict__ rfb, const float* __restrict__ hkbuf,
    const unsigned* __restrict__ kord, short* __restrict__ Qp,
    short* __restrict__ Kp) {
  __shared__ short smem[26624];  // A:8192 | B:18432 ; epilogue reuses as P[128][152]
  __shared__ float hks[128];
  short* As = smem;
  short* Bs = smem + 8192;
  int isK = blockIdx.z;
  const short* X = isK ? Kproj : Qproj;
  short* O = isK ? Kp : Qp;
  int bh = blockIdx.y, b = bh >> 4, h = bh & 15;
  int l0 = blockIdx.x << 7;
  int tid = threadIdx.x, lane = tid & 63, wid = tid >> 6;
  int cl = lane & 15, rq = lane >> 4;

#pragma unroll
  for (int i = 0; i < 4; ++i) {
    int e = tid * 8 + i * 2048;
    int row = e >> 6;
    int k = (e & 63) ^ ((row & 7) << 3);
    gload_lds16(X + ((size_t)b * SEQ + l0 + row) * DMODEL + h * HD + k,
                &As[wid * 512 + i * 2048]);
  }
#pragma unroll
  for (int i = 0; i < 9; ++i) {
    int e = tid * 8 + i * 2048;
    int row = e >> 6;
    int k = (e & 63) ^ ((row & 7) << 3);
    gload_lds16(rfb + row * HD + k, &Bs[wid * 512 + i * 2048]);
  }
  if (isK) {
    float ksv = ord2f(*kord);
    if (tid < 128)
      hks[tid] = hkbuf[(size_t)bh * SEQ + l0 + tid] - ksv + LN_CNORM;
  }
  __syncthreads();

  int i0 = wid * 32;
  f32x4 acc[2][18];
#pragma unroll
  for (int m = 0; m < 2; ++m)
#pragma unroll
    for (int n = 0; n < 18; ++n) acc[m][n] = f32x4{0.f, 0.f, 0.f, 0.f};
#pragma unroll
  for (int ks = 0; ks < 2; ++ks) {
    int kb = ks * 32 + (rq << 3);
    int swz = (cl & 7) << 3;
    bf16x8 af[2];
#pragma unroll
    for (int mf = 0; mf < 2; ++mf) {
      int row = i0 + mf * 16 + cl;
      af[mf] = *(const bf16x8*)&As[row * 64 + (kb ^ swz)];
    }
#pragma unroll
    for (int nf = 0; nf < 18; ++nf) {
      int brow = nf * 16 + cl;
      bf16x8 bv = *(const bf16x8*)&Bs[brow * 64 + (kb ^ swz)];
#pragma unroll
      for (int mf = 0; mf < 2; ++mf)
        acc[mf][nf] = __builtin_amdgcn_mfma_f32_16x16x32_bf16(af[mf], bv,
                                                              acc[mf][nf], 0, 0, 0);
    }
  }

  short* Ps = smem;  // [128][152]
#pragma unroll
  for (int hf = 0; hf < 2; ++hf) {
    __syncthreads();
#pragma unroll
    for (int mf = 0; mf < 2; ++mf)
#pragma unroll
      for (int r = 0; r < 4; ++r) {
        int rl = i0 + mf * 16 + (rq << 2) + r;
        float addk = isK ? hks[rl] : LN_CNORM;
#pragma unroll
        for (int nf2 = 0; nf2 < 9; ++nf2) {
          int m = hf * 144 + nf2 * 16 + cl;
          float v = acc[mf][hf * 9 + nf2][r] + addk;
          float o = (m < NRF) ? (__expf(v) + CKEPS) : 0.f;
          Ps[rl * 152 + nf2 * 16 + cl] = f2bs(o);
        }
      }
    __syncthreads();
#pragma unroll
    for (int it = 0; it < 9; ++it) {
      int idx = tid + it * 256;
      int row = idx / 18, ch = idx - row * 18;
      bf16x8 val = *(const bf16x8*)&Ps[row * 152 + ch * 8];
      *(bf16x8*)&O[((size_t)bh * SEQ + l0 + row) * NRFP + hf * 144 + ch * 8] = val;
    }
  }
}

// ---------------- per-chunk sums via MFMA -> Sct TRANSPOSED [bh][c][d][SROW] bf16 ----------------
__global__ __launch_bounds__(256) void chunksum_mfma(
    const short* __restrict__ Kp, const short* __restrict__ Vb,
    short* __restrict__ Sct, float* __restrict__ ksum) {
  constexpr int ST = 70;
  __shared__ short KT[NRFP * ST];  // [m][i_loc]
  __shared__ short VT[HD * ST];    // [d][i_loc]
  int c = blockIdx.x, bh = blockIdx.y;
  int b = bh >> 4, h = bh & 15;
  int tid = threadIdx.x, lane = tid & 63, wv = tid >> 6;
  int cl = lane & 15, rq = lane >> 4;
  int irow = tid >> 2;
  int mq = tid & 3;
  size_t rowb = (size_t)bh * SEQ + (size_t)c * CHK;

  f32x4 acc[18];
#pragma unroll
  for (int m = 0; m < 18; ++m) acc[m] = f32x4{0.f, 0.f, 0.f, 0.f};
  float k1 = 0.f, k2 = 0.f;

  for (int hf = 0; hf < 2; ++hf) {
    __syncthreads();
    const short* Krow = Kp + (rowb + hf * 64 + irow) * NRFP;
#pragma unroll
    for (int cg = 0; cg < 9; ++cg) {
      int m0 = cg * 32 + mq * 8;
      bf16x8 v = *(const bf16x8*)(Krow + m0);
#pragma unroll
      for (int e = 0; e < 8; ++e) KT[(m0 + e) * ST + irow] = v[e];
    }
    const short* Vrow =
        Vb + ((size_t)b * SEQ + (size_t)c * CHK + hf * 64 + irow) * DMODEL + h * HD;
    {
      int d0 = mq * 16;
      bf16x8 v0 = *(const bf16x8*)(Vrow + d0);
      bf16x8 v1 = *(const bf16x8*)(Vrow + d0 + 8);
#pragma unroll
      for (int e = 0; e < 8; ++e) VT[(d0 + e) * ST + irow] = v0[e];
#pragma unroll
      for (int e = 0; e < 8; ++e) VT[(d0 + 8 + e) * ST + irow] = v1[e];
    }
    __syncthreads();
#pragma unroll
    for (int ks = 0; ks < 2; ++ks) {
      int kb = ks * 32 + rq * 8;
      bf16x8 bv = *(const bf16x8*)&VT[(wv * 16 + cl) * ST + kb];
#pragma unroll
      for (int mf = 0; mf < 18; ++mf) {
        bf16x8 av = *(const bf16x8*)&KT[(mf * 16 + cl) * ST + kb];
        acc[mf] = __builtin_amdgcn_mfma_f32_16x16x32_bf16(av, bv, acc[mf], 0, 0, 0);
      }
    }
    {
      const short* r1 = &KT[tid * ST];
#pragma unroll
      for (int g = 0; g < 8; ++g) {
        bf16x8 v = *(const bf16x8*)(r1 + g * 8);
#pragma unroll
        for (int e = 0; e < 8; ++e) k1 += bs2f(v[e]);
      }
      if (tid < 10) {
        const short* r2 = &KT[(256 + tid) * ST];
#pragma unroll
        for (int g = 0; g < 8; ++g) {
          bf16x8 v = *(const bf16x8*)(r2 + g * 8);
#pragma unroll
          for (int e = 0; e < 8; ++e) k2 += bs2f(v[e]);
        }
      }
    }
  }
  // transposed store: Sct[(bh,c)][d][m], d = wv*16+cl, m = mf*16 + rq*4 + r; stride SROW
  size_t sbase = ((size_t)bh * NCH + c) * (size_t)(HD * SROW);
  int d = wv * 16 + cl;
#pragma unroll
  for (int mf = 0; mf < 18; ++mf) {
    short4 o4 = make_short4(f2bs(acc[mf][0]), f2bs(acc[mf][1]),
                            f2bs(acc[mf][2]), f2bs(acc[mf][3]));
    *(short4*)&Sct[sbase + (size_t)d * SROW + mf * 16 + rq * 4] = o4;
  }
  // zero pad columns [288, 320): 64 rows x 32 = 2048 shorts, 256 threads x 1 bf16x8
  {
    int dz = tid >> 2, off = NRFP + ((tid & 3) << 3);
    bf16x8 z = {0, 0, 0, 0, 0, 0, 0, 0};
    *(bf16x8*)&Sct[sbase + (size_t)dz * SROW + off] = z;
  }
  size_t kbase = ((size_t)bh * NCH + c) * (size_t)NRF;
  if (tid < NRF) ksum[kbase + tid] = k1;
  if (tid < 10) ksum[kbase + 256 + tid] = k2;
}

// ---------------- fused exclusive prefixes over chunks ----------------
// x<80: transposed S (64*SROW elems) ; x==80: ksum -> bf16 ksb rows
__global__ __launch_bounds__(256) void prefix_all(const short* __restrict__ Sct,
                                                  short* __restrict__ Spt,
                                                  const float* __restrict__ ksum,
                                                  short* __restrict__ ksb) {
  int bh = blockIdx.y;
  if (blockIdx.x == 80) {
    for (int m = threadIdx.x; m < NRFP; m += 256) {
      if (m < NRF) {
        size_t base = (size_t)bh * NCH * NRF + m;
        float a = 0.f;
#pragma unroll
        for (int c = 0; c < NCH; ++c) {
          float v = ksum[base + (size_t)c * NRF];
          ksb[((size_t)bh * NCH + c) * NRFP + m] = f2bs(a);
          a += v;
        }
      } else {
#pragma unroll
        for (int c = 0; c < NCH; ++c)
          ksb[((size_t)bh * NCH + c) * NRFP + m] = 0;
      }
    }
    return;
  }
  int e = blockIdx.x * 256 + threadIdx.x;  // over 64*SROW = 20480 (80 blocks exact)
  float a = 0.f;
#pragma unroll
  for (int c = 0; c < NCH; ++c) {
    size_t idx = ((size_t)bh * NCH + c) * (size_t)(HD * SROW) + e;
    float v = bs2f(Sct[idx]);
    Spt[idx] = f2bs(a);
    a += v;
  }
}

// ---------------- FUSED inter+intra, register den via MFMA, gload_lds Sp^T ----------------
__global__ __launch_bounds__(256) void attn_mfma(
    const short* __restrict__ Qp, const short* __restrict__ Kp,
    const short* __restrict__ Vb, const short* __restrict__ Spt,
    const short* __restrict__ ksb, short* __restrict__ ctxb) {
  constexpr int PST = 136;
  __shared__ short Vt[64 * PST];   // V^T [d][j]
  __shared__ short SP[64 * SROW];  // Sp^T [d][m] (XOR-swizzled) -> later P region
  int c = blockIdx.x, bh = blockIdx.y;
  int b = bh >> 4, h = bh & 15;
  int tid = threadIdx.x, lane = tid & 63, wid = tid >> 6;
  int cl = lane & 15, rq = lane >> 4;
  size_t rowb = (size_t)bh * SEQ + (size_t)c * CHK;

  // stage Sp^T via gload_lds, XOR-swizzled source: SP[d][x] = g[d][x ^ ((d&7)<<3)]
  // SROW=320 is 5 full 64-blocks -> involution closed within every row.
  const short* sg = Spt + ((size_t)bh * NCH + c) * (size_t)(HD * SROW);
#pragma unroll
  for (int i = 0; i < 10; ++i) {
    int o = tid * 8 + i * 2048;
    int d = o / SROW;
    int m = o - d * SROW;
    int ms = m ^ ((d & 7) << 3);
    gload_lds16(sg + (size_t)d * SROW + ms, &SP[wid * 512 + i * 2048]);
  }
  // stage V^T (register path)
  {
    int jj = tid >> 3, d0 = (tid & 7) << 3;
#pragma unroll
    for (int jt = 0; jt < 4; ++jt) {
      int j = jj + jt * 32;
      bf16x8 v = *(const bf16x8*)(Vb + ((size_t)b * SEQ + (size_t)c * CHK + j) * DMODEL +
                                  h * HD + d0);
#pragma unroll
      for (int e = 0; e < 8; ++e) Vt[(d0 + e) * PST + j] = v[e];
    }
  }
  __syncthreads();

  int i0 = wid * 32;
  const short* Arow = Qp + (rowb + i0) * NRFP;
  const short* Krow = Kp + rowb * NRFP;
  const short* krow = ksb + ((size_t)bh * NCH + c) * NRFP;
  f32x4 accI[2][4];  // inter numerator
  f32x4 accD[2];     // inter denominator (col-0 trick; valid on cl==0 lanes)
  f32x4 accP[2][8];  // P = Q'K'^T
#pragma unroll
  for (int m = 0; m < 2; ++m) {
#pragma unroll
    for (int n = 0; n < 4; ++n) accI[m][n] = f32x4{0.f, 0.f, 0.f, 0.f};
    accD[m] = f32x4{0.f, 0.f, 0.f, 0.f};
#pragma unroll
    for (int n = 0; n < 8; ++n) accP[m][n] = f32x4{0.f, 0.f, 0.f, 0.f};
  }
#pragma unroll
  for (int k9 = 0; k9 < 9; ++k9) {
    int kb = k9 * 32 + (rq << 3);
    bf16x8 af[2];
#pragma unroll
    for (int mf = 0; mf < 2; ++mf)
      af[mf] = *(const bf16x8*)(Arow + (size_t)(mf * 16 + cl) * NRFP + kb);
    // den fragment: only col 0 (cl==0) carries ksum
    bf16x8 bvD = {0, 0, 0, 0, 0, 0, 0, 0};
    if (cl == 0) bvD = *(const bf16x8*)(krow + kb);
#pragma unroll
    for (int mf = 0; mf < 2; ++mf)
      accD[mf] = __builtin_amdgcn_mfma_f32_16x16x32_bf16(af[mf], bvD, accD[mf], 0, 0, 0);
    // inter: Sp^T from LDS (swizzled, stride SROW)
#pragma unroll
    for (int nf = 0; nf < 4; ++nf) {
      int row = nf * 16 + cl;
      bf16x8 bv = *(const bf16x8*)&SP[row * SROW + (kb ^ ((cl & 7) << 3))];
#pragma unroll
      for (int mf = 0; mf < 2; ++mf)
        accI[mf][nf] = __builtin_amdgcn_mfma_f32_16x16x32_bf16(af[mf], bv,
                                                               accI[mf][nf], 0, 0, 0);
    }
    // intra P: K' rows from global (L2-hot)
#pragma unroll
    for (int nf = 0; nf < 8; ++nf) {
      bf16x8 bv = *(const bf16x8*)(Krow + (size_t)(nf * 16 + cl) * NRFP + kb);
#pragma unroll
      for (int mf = 0; mf < 2; ++mf)
        accP[mf][nf] = __builtin_amdgcn_mfma_f32_16x16x32_bf16(af[mf], bv,
                                                               accP[mf][nf], 0, 0, 0);
    }
  }
  __syncthreads();  // all waves done reading SP; region becomes P

  // mask, rowsum, den (registers); write P to LDS
  float dtot[2][4];
#pragma unroll
  for (int mf = 0; mf < 2; ++mf)
#pragma unroll
    for (int r = 0; r < 4; ++r) {
      int rl = mf * 16 + (rq << 2) + r;
      int row = i0 + rl;
      float dsum = 0.f;
#pragma unroll
      for (int nf = 0; nf < 8; ++nf) {
        int col = nf * 16 + cl;
        float v = (col > row) ? 0.f : accP[mf][nf][r];
        dsum += v;
        SP[wid * 32 * PST + rl * PST + col] = f2bs(v);
      }
      dsum += __shfl_xor(dsum, 1);
      dsum += __shfl_xor(dsum, 2);
      dsum += __shfl_xor(dsum, 4);
      dsum += __shfl_xor(dsum, 8);
      float dden = __shfl(accD[mf][r], lane & 48);  // broadcast from cl==0 of same rq
      dtot[mf][r] = dden + dsum;
    }
  __syncthreads();  // P tiles complete

  // PV phase
  f32x4 pacc[2][4];
#pragma unroll
  for (int m = 0; m < 2; ++m)
#pragma unroll
    for (int n = 0; n < 4; ++n) pacc[m][n] = f32x4{0.f, 0.f, 0.f, 0.f};
#pragma unroll
  for (int kk = 0; kk < 4; ++kk) {
    int kb = kk * 32 + (rq << 3);
    bf16x8 paf[2];
#pragma unroll
    for (int mf = 0; mf < 2; ++mf)
      paf[mf] = *(const bf16x8*)&SP[wid * 32 * PST + (mf * 16 + cl) * PST + kb];
#pragma unroll
    for (int nf = 0; nf < 4; ++nf) {
      bf16x8 bv = *(const bf16x8*)&Vt[(nf * 16 + cl) * PST + kb];
#pragma unroll
      for (int mf = 0; mf < 2; ++mf)
        pacc[mf][nf] = __builtin_amdgcn_mfma_f32_16x16x32_bf16(paf[mf], bv,
                                                               pacc[mf][nf], 0, 0, 0);
    }
  }
  // finalize: (accI + pacc) / dtot
#pragma unroll
  for (int mf = 0; mf < 2; ++mf)
#pragma unroll
    for (int r = 0; r < 4; ++r) {
      int row = i0 + mf * 16 + (rq << 2) + r;
      float inv = 1.0f / dtot[mf][r];
      size_t ob = ((size_t)b * SEQ + (size_t)c * CHK + row) * DMODEL + h * HD;
#pragma unroll
      for (int nf = 0; nf < 4; ++nf) {
        int d = nf * 16 + cl;
        float v = (accI[mf][nf][r] + pacc[mf][nf][r]) * inv;
        ctxb[ob + d] = f2bs(v);
      }
    }
}

// ---------------- launch ----------------
extern "C" void kernel_launch(void* const* d_in, const int* in_sizes, int n_in,
                              void* d_out, int out_size, void* d_ws, size_t ws_size,
                              hipStream_t stream) {
  (void)in_sizes; (void)n_in; (void)out_size;
  const float* query = (const float*)d_in[0];
  const float* key_  = (const float*)d_in[1];
  const float* value = (const float*)d_in[2];
  const float* Wq = (const float*)d_in[3];
  const float* bq = (const float*)d_in[4];
  const float* Wk = (const float*)d_in[5];
  const float* bk = (const float*)d_in[6];
  const float* Wv = (const float*)d_in[7];
  const float* bv = (const float*)d_in[8];
  const float* Wo = (const float*)d_in[9];
  const float* bo = (const float*)d_in[10];
  const float* rf = (const float*)d_in[11];

  constexpr size_t SZ_INBF = (size_t)NROWS * DMODEL * 2;
  constexpr size_t SZ_QP   = (size_t)NBH * SEQ * NRFP * 2;
  constexpr size_t SZ_WT   = (size_t)DMODEL * DMODEL * 2;
  constexpr size_t SZ_SCH  = (size_t)NBH * NCH * HD * SROW * 2;  // 20.97 MB
  constexpr size_t SZ_KS   = (size_t)NBH * NCH * NRF * 4;
  constexpr size_t SZ_KSB  = (size_t)NBH * NCH * NRFP * 2;
  constexpr size_t SZ_HK   = (size_t)NBH * SEQ * 4;
  constexpr size_t SZ_RFB  = (size_t)NRFP * HD * 2;

  constexpr size_t O_QP   = 0;
  constexpr size_t O_KP   = O_QP + SZ_QP;
  constexpr size_t O_WT   = O_KP + SZ_QP;
  constexpr size_t O_QPR  = O_WT + 4 * SZ_WT;
  constexpr size_t O_SCH  = O_QPR + 3 * SZ_INBF;
  constexpr size_t O_SPR  = O_SCH + SZ_SCH;
  constexpr size_t O_KSUM = O_SPR + SZ_SCH;
  constexpr size_t O_KSB  = O_KSUM + SZ_KS;
  constexpr size_t O_HK   = O_KSB + SZ_KSB;
  constexpr size_t O_KST  = O_HK + SZ_HK;
  constexpr size_t O_CTXB = O_KST + 256;
  constexpr size_t O_RFB  = O_CTXB + SZ_INBF;
  constexpr size_t O_END  = O_RFB + SZ_RFB;
  if (ws_size < O_END) return;

  char* w = (char*)d_ws;
  short* Qbf  = (short*)(w + O_QP);
  short* Qp   = (short*)(w + O_QP);
  short* Kp   = (short*)(w + O_KP);
  short* WtB  = (short*)(w + O_WT);
  short* QprB = (short*)(w + O_QPR);
  short* Kpr  = (short*)(w + O_QPR + SZ_INBF);
  short* Vpr  = (short*)(w + O_QPR + 2 * SZ_INBF);
  short* Sct  = (short*)(w + O_SCH);
  short* Spt  = (short*)(w + O_SPR);
  float* ksum = (float*)(w + O_KSUM);
  short* ksb  = (short*)(w + O_KSB);
  float* hkbuf = (float*)(w + O_HK);
  unsigned* kord = (unsigned*)(w + O_KST);
  short* ctxb = (short*)(w + O_CTXB);
  short* rfb  = (short*)(w + O_RFB);

  constexpr int NEL = NROWS * DMODEL;
  cvt3_kernel<<<dim3(NEL / 2048, 3), 256, 0, stream>>>(query, key_, value, Qbf);
  transpose4_bf16<<<dim3(32, 32, 4), 256, 0, stream>>>(Wq, Wk, Wv, Wo, WtB);
  rf_pad_bf16<<<(NRFP * HD) / 256, 256, 0, stream>>>(rf, rfb, kord);
  gemm_qkv3<<<dim3(8, 32, 3), 256, 0, stream>>>(Qbf, WtB, bq, bk, bv, QprB);
  hk_kernel<<<256, 256, 0, stream>>>(Kpr, hkbuf, kord);
  featmap_mfma<<<dim3(SEQ / 128, NBH, 2), 256, 0, stream>>>(QprB, Kpr, rfb, hkbuf,
                                                            kord, Qp, Kp);
  chunksum_mfma<<<dim3(NCH, NBH), 256, 0, stream>>>(Kp, Vpr, Sct, ksum);
  prefix_all<<<dim3(81, NBH), 256, 0, stream>>>(Sct, Spt, ksum, ksb);
  attn_mfma<<<dim3(NCH, NBH), 256, 0, stream>>>(Qp, Kp, Vpr, Spt, ksb, ctxb);
  gemm_out<<<dim3(16, 32), 256, 0, stream>>>(ctxb, WtB + 3 * (size_t)DMODEL * DMODEL,
                                             bo, (float*)d_out);
}